// Round 2
// baseline (7658.398 us; speedup 1.0000x reference)
//
#include <hip/hip_runtime.h>
#include <hip/hip_bf16.h>
#include <cstdint>

// Problem dims
#define BB   32
#define CINX 256
#define HH   56
#define WW   56
#define HWX  (HH*WW)      // 3136
#define CO   512
#define PL   128
#define HP   28
#define WP   28
#define HWP  (HP*WP)      // 784
#define NG   4
#define MSZ  7

// ---------------- avgpool 3x3 stride2 pad1 on x (f32) ----------------
__global__ __launch_bounds__(256) void k_avgpool_x(const float* __restrict__ x, float* __restrict__ out){
  int idx = blockIdx.x*256 + threadIdx.x;
  if (idx >= BB*CINX*HWP) return;
  int p = idx % HWP; int bc = idx / HWP;
  int ox = p % WP, oy = p / WP;
  const float* src = x + (size_t)bc*HWX;
  float s = 0.f;
  #pragma unroll
  for (int dy=0; dy<3; dy++){
    int yy = 2*oy-1+dy;
    if ((unsigned)yy >= HH) continue;
    #pragma unroll
    for (int dx=0; dx<3; dx++){
      int xx = 2*ox-1+dx;
      if ((unsigned)xx >= WW) continue;
      s += src[yy*WW + xx];
    }
  }
  out[idx] = s * (1.f/9.f);
}

// ---------------- 1x1 conv + BN + optional ReLU, 8 couts/thread ----------------
template<int CIN_T, bool RELU>
__global__ __launch_bounds__(256) void k_conv1x1(const float* __restrict__ in, const float* __restrict__ w,
                const float* __restrict__ gam, const float* __restrict__ bet,
                float* __restrict__ out, int hw, int cout){
  __shared__ float wsh[8*CIN_T];
  __shared__ float gsh[8], bsh[8];
  int tid = threadIdx.x;
  int co = blockIdx.y*8;
  for (int i = tid; i < 8*CIN_T; i += 256)
    wsh[i] = w[(size_t)co*CIN_T + i];
  if (tid < 8){ gsh[tid]=gam[co+tid]; bsh[tid]=bet[co+tid]; }
  __syncthreads();
  int pos = blockIdx.x*256 + tid;
  if (pos >= BB*hw) return;
  int b = pos / hw, p = pos % hw;
  const float* src = in + (size_t)b*CIN_T*hw + p;
  float acc[8] = {0,0,0,0,0,0,0,0};
  #pragma unroll 4
  for (int c=0;c<CIN_T;c++){
    float v = src[(size_t)c*hw];
    #pragma unroll
    for (int j=0;j<8;j++) acc[j] += v * wsh[j*CIN_T + c];
  }
  #pragma unroll
  for (int j=0;j<8;j++){
    float r = acc[j]*gsh[j] + bsh[j];
    if (RELU) r = fmaxf(r, 0.f);
    out[((size_t)b*cout + co + j)*hw + p] = r;
  }
}

// ---------------- 3x3 conv (Cin=Cout=128) + BN + ReLU, 4 couts/thread ----------------
template<int STRIDE>
__global__ __launch_bounds__(256) void k_conv3x3(const float* __restrict__ in, const float* __restrict__ w,
                const float* __restrict__ gam, const float* __restrict__ bet,
                float* __restrict__ out, int hi, int wi, int ho, int wo){
  __shared__ float wsh[4*PL*9];
  __shared__ float gsh[4], bsh[4];
  int tid = threadIdx.x;
  int co = blockIdx.y*4;
  for (int i=tid; i<4*PL*9; i+=256)
    wsh[i] = w[(size_t)co*PL*9 + i];
  if (tid<4){ gsh[tid]=gam[co+tid]; bsh[tid]=bet[co+tid]; }
  __syncthreads();
  int hwo = ho*wo;
  int pos = blockIdx.x*256 + tid;
  if (pos >= BB*hwo) return;
  int b = pos/hwo, p = pos%hwo;
  int oy = p/wo, ox = p%wo;
  const float* src = in + (size_t)b*PL*hi*wi;
  int iy0 = oy*STRIDE-1, ix0 = ox*STRIDE-1;
  float a[4] = {0,0,0,0};
  bool interior = (iy0>=0) && (ix0>=0) && (iy0+2<hi) && (ix0+2<wi);
  if (interior){
    const float* s0 = src + (size_t)iy0*wi + ix0;
    for (int c=0;c<PL;c++){
      const float* sc = s0 + (size_t)c*hi*wi;
      float v00=sc[0],    v01=sc[1],      v02=sc[2];
      float v10=sc[wi],   v11=sc[wi+1],   v12=sc[wi+2];
      float v20=sc[2*wi], v21=sc[2*wi+1], v22=sc[2*wi+2];
      int wb = c*9;
      #pragma unroll
      for (int j=0;j<4;j++){
        const float* wj = &wsh[j*PL*9 + wb];
        a[j] += v00*wj[0]+v01*wj[1]+v02*wj[2]
              + v10*wj[3]+v11*wj[4]+v12*wj[5]
              + v20*wj[6]+v21*wj[7]+v22*wj[8];
      }
    }
  } else {
    for (int c=0;c<PL;c++){
      const float* sc = src + (size_t)c*hi*wi;
      int wb = c*9;
      #pragma unroll
      for (int dy=0;dy<3;dy++){
        int yy=iy0+dy; if((unsigned)yy>=(unsigned)hi) continue;
        #pragma unroll
        for (int dx=0;dx<3;dx++){
          int xx=ix0+dx; if((unsigned)xx>=(unsigned)wi) continue;
          float v = sc[yy*wi+xx];
          #pragma unroll
          for (int j=0;j<4;j++) a[j] += v*wsh[j*PL*9 + wb + dy*3+dx];
        }
      }
    }
  }
  #pragma unroll
  for (int j=0;j<4;j++){
    float r = a[j]*gsh[j] + bsh[j];
    out[((size_t)b*PL + co + j)*hwo + p] = fmaxf(r, 0.f);
  }
}

// ---------------- x_base = bn(conv1x1(t2,w3)) + bn(conv1x1(pooled,dw)) ----------------
__global__ __launch_bounds__(256) void k_xbase(const float* __restrict__ t2, const float* __restrict__ pooled,
    const float* __restrict__ w3, const float* __restrict__ g3, const float* __restrict__ b3,
    const float* __restrict__ dw, const float* __restrict__ dg, const float* __restrict__ db,
    float* __restrict__ xbase){
  __shared__ float w3s[8*PL], dws[8*CINX];
  __shared__ float g3s[8], dgs[8], bias[8];
  int tid = threadIdx.x; int co = blockIdx.y*8;
  for (int i=tid;i<8*PL;i+=256)   w3s[i]=w3[(size_t)co*PL+i];
  for (int i=tid;i<8*CINX;i+=256) dws[i]=dw[(size_t)co*CINX+i];
  if (tid<8){
    g3s[tid]=g3[co+tid];
    dgs[tid]=dg[co+tid];
    bias[tid]=b3[co+tid] + db[co+tid];
  }
  __syncthreads();
  int pos = blockIdx.x*256 + tid;
  if (pos >= BB*HWP) return;
  int b = pos/HWP, p = pos%HWP;
  const float* s1 = t2 + (size_t)b*PL*HWP + p;
  const float* s2 = pooled + (size_t)b*CINX*HWP + p;
  float a[8]={0,0,0,0,0,0,0,0}, d[8]={0,0,0,0,0,0,0,0};
  #pragma unroll 4
  for (int c=0;c<PL;c++){
    float v = s1[(size_t)c*HWP];
    #pragma unroll
    for (int j=0;j<8;j++) a[j]+=v*w3s[j*PL+c];
  }
  #pragma unroll 4
  for (int c=0;c<CINX;c++){
    float v = s2[(size_t)c*HWP];
    #pragma unroll
    for (int j=0;j<8;j++) d[j]+=v*dws[j*CINX+c];
  }
  #pragma unroll
  for (int j=0;j<8;j++)
    xbase[((size_t)b*CO + co + j)*HWP + p] = a[j]*g3s[j] + d[j]*dgs[j] + bias[j];
}

// ---------------- grouped 3x3 conv on xbase -> gmap (B,16,28,28), relu ----------------
__global__ __launch_bounds__(256) void k_gmap(const float* __restrict__ xbase, const float* __restrict__ mw,
    const float* __restrict__ mg, const float* __restrict__ mb, float* __restrict__ gmap){
  __shared__ float wsh[PL*9];
  int tid = threadIdx.x;
  int oc = blockIdx.y; int b = blockIdx.x;
  for (int i=tid;i<PL*9;i+=256) wsh[i]=mw[(size_t)oc*PL*9+i];
  __syncthreads();
  float gg=mg[oc], bb2=mb[oc];
  int grp = oc >> 2;
  const float* src = xbase + ((size_t)b*CO + grp*PL)*HWP;
  for (int p=tid; p<HWP; p+=256){
    int oy=p/WP, ox=p%WP;
    float a = 0.f;
    for (int c=0;c<PL;c++){
      const float* sc = src + (size_t)c*HWP;
      #pragma unroll
      for (int dy=0;dy<3;dy++){
        int yy=oy-1+dy; if((unsigned)yy>=HP) continue;
        #pragma unroll
        for (int dx=0;dx<3;dx++){
          int xx=ox-1+dx; if((unsigned)xx>=WP) continue;
          a += sc[yy*WP+xx]*wsh[c*9+dy*3+dx];
        }
      }
    }
    gmap[((size_t)b*16+oc)*HWP + p] = fmaxf(a*gg+bb2, 0.f);
  }
}

// ---------------- gpool: mean over 4x4 blocks -> (B,16,7,7) ----------------
__global__ __launch_bounds__(256) void k_gpool(const float* __restrict__ gmap, float* __restrict__ gpool){
  int idx = blockIdx.x*256 + threadIdx.x;
  if (idx >= BB*16*49) return;
  int q = idx % 49; int t = idx / 49; int ch = t % 16; int b = t / 16;
  int my = q/7, mx = q%7;
  const float* src = gmap + ((size_t)b*16 + ch)*HWP;
  float s = 0.f;
  #pragma unroll
  for (int yb=0;yb<4;yb++)
    #pragma unroll
    for (int xb=0;xb<4;xb++)
      s += src[(my*4+yb)*WP + (mx*4+xb)];
  gpool[idx] = s * (1.f/16.f);
}

// ---------------- mask: grouped 1x1 fc + gumbel argmax -> {0,1} ----------------
// logits reshape(B,2,G): class cls, group g -> conv channel c = cls*4+g, conv-group c>>1
__global__ __launch_bounds__(256) void k_mask(const float* __restrict__ gpool, const float* __restrict__ fcw,
    const float* __restrict__ fcb, const float* __restrict__ gum,
    float* __restrict__ maskf, float* __restrict__ mout){
  int idx = blockIdx.x*256 + threadIdx.x;
  if (idx >= BB*NG*49) return;
  int q = idx % 49; int t = idx / 49; int g = t % NG; int b = t / NG;
  float l[2];
  #pragma unroll
  for (int cls=0; cls<2; cls++){
    int c = cls*NG + g;
    int gc = c >> 1;               // conv group of channel c
    float s = fcb[c];
    #pragma unroll
    for (int k=0;k<4;k++)
      s += fcw[c*4+k] * gpool[((size_t)b*16 + gc*4 + k)*49 + q];
    s += gum[(((size_t)b*2 + cls)*NG + g)*49 + q];
    l[cls] = s;
  }
  // argmax picks first max on ties -> class 0 wins ties -> mask=1 iff l1 > l0 strictly
  float m = (l[1] > l[0]) ? 1.f : 0.f;
  maskf[idx] = m;
  mout[idx] = m;
}

// ---------------- fused = relu(up(xbase) + bn(conv1x1(r2,rw3))*mask + bn(conv1x1(x,rdw))) ----------------
__global__ __launch_bounds__(256) void k_fuse(const float* __restrict__ r2, const float* __restrict__ x,
    const float* __restrict__ rw3, const float* __restrict__ rg3, const float* __restrict__ rb3,
    const float* __restrict__ rdw, const float* __restrict__ rdg, const float* __restrict__ rdb,
    const float* __restrict__ xbase, const float* __restrict__ maskf, float* __restrict__ fused){
  __shared__ float w1s[8*PL], w2s[8*CINX];
  __shared__ float g1s[8], b1s[8], g2s[8], b2s[8];
  int tid = threadIdx.x; int co = blockIdx.y*8;
  for (int i=tid;i<8*PL;i+=256)   w1s[i]=rw3[(size_t)co*PL+i];
  for (int i=tid;i<8*CINX;i+=256) w2s[i]=rdw[(size_t)co*CINX+i];
  if (tid<8){
    g1s[tid]=rg3[co+tid]; b1s[tid]=rb3[co+tid];
    g2s[tid]=rdg[co+tid]; b2s[tid]=rdb[co+tid];
  }
  __syncthreads();
  int pos = blockIdx.x*256 + tid;
  if (pos >= BB*HWX) return;
  int b = pos/HWX, p = pos%HWX;
  int y = p/WW, xx = p%WW;
  float a[8]={0,0,0,0,0,0,0,0}, d[8]={0,0,0,0,0,0,0,0};
  const float* s1 = r2 + (size_t)b*PL*HWX + p;
  #pragma unroll 4
  for (int c=0;c<PL;c++){
    float v = s1[(size_t)c*HWX];
    #pragma unroll
    for (int j=0;j<8;j++) a[j]+=v*w1s[j*PL+c];
  }
  const float* s2 = x + (size_t)b*CINX*HWX + p;
  #pragma unroll 4
  for (int c=0;c<CINX;c++){
    float v = s2[(size_t)c*HWX];
    #pragma unroll
    for (int j=0;j<8;j++) d[j]+=v*w2s[j*CINX+c];
  }
  // bilinear 2x (half-pixel, edge-renormalized == clamp)
  int iy = y>>1, ix = xx>>1;
  int yA,yB,xA,xB; float wyA,wyB,wxA,wxB;
  if (y & 1){ yA=iy; wyA=0.75f; yB=(iy+1<HP)?iy+1:HP-1; wyB=0.25f; }
  else      { yA=(iy>0)?iy-1:0; wyA=0.25f; yB=iy; wyB=0.75f; }
  if (xx & 1){ xA=ix; wxA=0.75f; xB=(ix+1<WP)?ix+1:WP-1; wxB=0.25f; }
  else       { xA=(ix>0)?ix-1:0; wxA=0.25f; xB=ix; wxB=0.75f; }
  int grp = co >> 7;   // co/(CO/NG) = co/128
  float m = maskf[(((size_t)b*NG + grp)*MSZ + (y>>3))*MSZ + (xx>>3)];
  #pragma unroll
  for (int j=0;j<8;j++){
    const float* xb = xbase + ((size_t)b*CO + co + j)*HWP;
    float up = wyA*(wxA*xb[yA*WP+xA] + wxB*xb[yA*WP+xB])
             + wyB*(wxA*xb[yB*WP+xA] + wxB*xb[yB*WP+xB]);
    float rv = a[j]*g1s[j] + b1s[j];
    float dv = d[j]*g2s[j] + b2s[j];
    float f = up + rv*m + dv;
    fused[((size_t)b*CO + co + j)*HWX + p] = fmaxf(f, 0.f);
  }
}

// ---------------- out = relu(bn(conv1x1(f2,fw3)) + avgpool3s2(fused)) ----------------
__global__ __launch_bounds__(256) void k_final(const float* __restrict__ f2, const float* __restrict__ fw3,
    const float* __restrict__ fg3, const float* __restrict__ fb3,
    const float* __restrict__ fused, float* __restrict__ outp){
  __shared__ float wsh[8*PL];
  __shared__ float gsh[8], bsh[8];
  int tid = threadIdx.x; int co = blockIdx.y*8;
  for (int i=tid;i<8*PL;i+=256) wsh[i]=fw3[(size_t)co*PL+i];
  if (tid<8){ gsh[tid]=fg3[co+tid]; bsh[tid]=fb3[co+tid]; }
  __syncthreads();
  int pos = blockIdx.x*256 + tid;
  if (pos >= BB*HWP) return;
  int b = pos/HWP, p = pos%HWP;
  int oy = p/WP, ox = p%WP;
  const float* s1 = f2 + (size_t)b*PL*HWP + p;
  float a[8]={0,0,0,0,0,0,0,0};
  #pragma unroll 4
  for (int c=0;c<PL;c++){
    float v = s1[(size_t)c*HWP];
    #pragma unroll
    for (int j=0;j<8;j++) a[j]+=v*wsh[j*PL+c];
  }
  #pragma unroll
  for (int j=0;j<8;j++){
    const float* fs = fused + ((size_t)b*CO + co + j)*HWX;
    float s = 0.f;
    #pragma unroll
    for (int dy=0;dy<3;dy++){
      int yy = 2*oy-1+dy; if ((unsigned)yy>=HH) continue;
      #pragma unroll
      for (int dx=0;dx<3;dx++){
        int xxp = 2*ox-1+dx; if ((unsigned)xxp>=WW) continue;
        s += fs[yy*WW+xxp];
      }
    }
    float r = a[j]*gsh[j] + bsh[j] + s*(1.f/9.f);
    outp[((size_t)b*CO + co + j)*HWP + p] = fmaxf(r, 0.f);
  }
}

extern "C" void kernel_launch(void* const* d_in, const int* in_sizes, int n_in,
                              void* d_out, int out_size, void* d_ws, size_t ws_size,
                              hipStream_t stream){
  const float* x    = (const float*)d_in[0];
  const float* gum  = (const float*)d_in[1];
  const float* b_w1 = (const float*)d_in[2];
  const float* b_g1 = (const float*)d_in[3];
  const float* b_b1 = (const float*)d_in[4];
  const float* b_w2 = (const float*)d_in[5];
  const float* b_g2 = (const float*)d_in[6];
  const float* b_b2 = (const float*)d_in[7];
  const float* b_w3 = (const float*)d_in[8];
  const float* b_g3 = (const float*)d_in[9];
  const float* b_b3 = (const float*)d_in[10];
  const float* b_dw = (const float*)d_in[11];
  const float* b_dg = (const float*)d_in[12];
  const float* b_db = (const float*)d_in[13];
  const float* r_w1 = (const float*)d_in[14];
  const float* r_g1 = (const float*)d_in[15];
  const float* r_b1 = (const float*)d_in[16];
  const float* r_w2 = (const float*)d_in[17];
  const float* r_g2 = (const float*)d_in[18];
  const float* r_b2 = (const float*)d_in[19];
  const float* r_w3 = (const float*)d_in[20];
  const float* r_g3 = (const float*)d_in[21];
  const float* r_b3 = (const float*)d_in[22];
  const float* r_dw = (const float*)d_in[23];
  const float* r_dg = (const float*)d_in[24];
  const float* r_db = (const float*)d_in[25];
  const float* m_w  = (const float*)d_in[26];
  const float* m_g  = (const float*)d_in[27];
  const float* m_b  = (const float*)d_in[28];
  const float* m_fcw= (const float*)d_in[29];
  const float* m_fcb= (const float*)d_in[30];
  const float* f_w1 = (const float*)d_in[31];
  const float* f_g1 = (const float*)d_in[32];
  const float* f_b1 = (const float*)d_in[33];
  const float* f_w2 = (const float*)d_in[34];
  const float* f_g2 = (const float*)d_in[35];
  const float* f_b2 = (const float*)d_in[36];
  const float* f_w3 = (const float*)d_in[37];
  const float* f_g3 = (const float*)d_in[38];
  const float* f_b3 = (const float*)d_in[39];

  char* ws = (char*)d_ws;
  // All-fp32 intermediates. Offsets (bytes):
  float* pooled = (float*)(ws + 0);              //  25,690,112
  float* t1     = (float*)(ws + 25690112);       //  51,380,224  (b1/r1/f1 reuse)
  float* t2     = (float*)(ws + 77070336);       //  12,845,056  (b2/f2 reuse)
  float* xbase  = (float*)(ws + 89915392);       //  51,380,224
  float* gmap   = (float*)(ws + 141295616);      //   1,605,632
  float* gpool  = (float*)(ws + 142901248);      //     100,352
  float* maskf  = (float*)(ws + 143001600);      //      25,088
  float* r2     = (float*)(ws + 143026688);      //  51,380,224
  float* fused  = (float*)(ws + 194406912);      // 205,520,896  -> total 399,927,808 B
  (void)ws_size;

  float* outp = (float*)d_out;
  float* mout = outp + (size_t)BB*CO*HWP;        // mask tail at 12,845,056 floats

  dim3 blk(256);
  // 1) pooled = avgpool3s2(x)
  k_avgpool_x<<<dim3((BB*CINX*HWP+255)/256), blk, 0, stream>>>(x, pooled);
  // 2) t1 = relu(bn(conv1x1(x, b_w1)))
  k_conv1x1<CINX,true><<<dim3((BB*HWX+255)/256, PL/8), blk, 0, stream>>>(x, b_w1, b_g1, b_b1, t1, HWX, PL);
  // 3) t2 = relu(bn(conv3x3s2(t1, b_w2)))
  k_conv3x3<2><<<dim3((BB*HWP+255)/256, PL/4), blk, 0, stream>>>(t1, b_w2, b_g2, b_b2, t2, HH, WW, HP, WP);
  // 4) x_base
  k_xbase<<<dim3((BB*HWP+255)/256, CO/8), blk, 0, stream>>>(t2, pooled, b_w3,b_g3,b_b3, b_dw,b_dg,b_db, xbase);
  // 5) gmap = relu(bn(gconv3x3(x_base, m_w)))
  k_gmap<<<dim3(BB, 16), blk, 0, stream>>>(xbase, m_w, m_g, m_b, gmap);
  // 6) gpool + mask
  k_gpool<<<dim3((BB*16*49+255)/256), blk, 0, stream>>>(gmap, gpool);
  k_mask<<<dim3((BB*NG*49+255)/256), blk, 0, stream>>>(gpool, m_fcw, m_fcb, gum, maskf, mout);
  // 7) r1 = relu(bn(conv1x1(x, r_w1)))  (reuse t1)
  k_conv1x1<CINX,true><<<dim3((BB*HWX+255)/256, PL/8), blk, 0, stream>>>(x, r_w1, r_g1, r_b1, t1, HWX, PL);
  // 8) r2 = relu(bn(conv3x3(r1, r_w2, pad=1)))
  k_conv3x3<1><<<dim3((BB*HWX+255)/256, PL/4), blk, 0, stream>>>(t1, r_w2, r_g2, r_b2, r2, HH, WW, HH, WW);
  // 9) fused
  k_fuse<<<dim3((BB*HWX+255)/256, CO/8), blk, 0, stream>>>(r2, x, r_w3,r_g3,r_b3, r_dw,r_dg,r_db, xbase, maskf, fused);
  // 10) f1 = relu(bn(conv1x1(fused, f_w1)))  (reuse t1)
  k_conv1x1<CO,true><<<dim3((BB*HWX+255)/256, PL/8), blk, 0, stream>>>(fused, f_w1, f_g1, f_b1, t1, HWX, PL);
  // 11) f2 = relu(bn(conv3x3s2(f1, f_w2)))  (reuse t2)
  k_conv3x3<2><<<dim3((BB*HWP+255)/256, PL/4), blk, 0, stream>>>(t1, f_w2, f_g2, f_b2, t2, HH, WW, HP, WP);
  // 12) out = relu(bn(conv1x1(f2, f_w3)) + avgpool3s2(fused))
  k_final<<<dim3((BB*HWP+255)/256, CO/8), blk, 0, stream>>>(t2, f_w3, f_g3, f_b3, fused, outp);
}

// Round 4
// 2157.634 us; speedup vs baseline: 3.5494x; 3.5494x over previous
//
#include <hip/hip_runtime.h>
#include <cstdint>

// dims
#define BB   32
#define CINX 256
#define HH   56
#define WW   56
#define HWX  3136
#define CO   512
#define PL   128
#define HP   28
#define WP   28
#define HWP  784
#define NG   4
#define MSZ  7

typedef unsigned short ushortT;
typedef unsigned int   uint32;
typedef __attribute__((ext_vector_type(8))) short short8;
typedef __attribute__((ext_vector_type(4))) float f32x4;

__device__ __forceinline__ ushortT f2bf(float f){
  uint32 u = __float_as_uint(f);
  u = (u + 0x7fffu + ((u >> 16) & 1u)) >> 16;   // RNE
  return (ushortT)u;
}
__device__ __forceinline__ float bf2f(ushortT u){
  return __uint_as_float(((uint32)u) << 16);
}
__device__ __forceinline__ void split2(float v, ushortT& h, ushortT& lo){
  h = f2bf(v);
  lo = f2bf(v - bf2f(h));
}
__device__ __forceinline__ uint32 packu(ushortT a, ushortT b){
  return (uint32)a | ((uint32)b << 16);
}

// ============ weight prep: [m][Ktot] taps-major / K-concat, gamma-folded, hi/lo split ============
__device__ __forceinline__ void wsplit(float v, ushortT* dh, ushortT* dl, size_t i){
  ushortT h, lo; split2(v, h, lo); dh[i] = h; dl[i] = lo;
}

__global__ __launch_bounds__(256) void prep_w(
  const float* __restrict__ b_w1, const float* __restrict__ b_g1,
  const float* __restrict__ b_w2, const float* __restrict__ b_g2,
  const float* __restrict__ b_w3, const float* __restrict__ b_g3,
  const float* __restrict__ b_dw, const float* __restrict__ b_dg,
  const float* __restrict__ r_w1, const float* __restrict__ r_g1,
  const float* __restrict__ r_w2, const float* __restrict__ r_g2,
  const float* __restrict__ r_w3, const float* __restrict__ r_g3,
  const float* __restrict__ r_dw, const float* __restrict__ r_dg,
  const float* __restrict__ f_w1, const float* __restrict__ f_g1,
  const float* __restrict__ f_w2, const float* __restrict__ f_g2,
  const float* __restrict__ f_w3, const float* __restrict__ f_g3,
  ushortT* __restrict__ dh, ushortT* __restrict__ dl)
{
  const int idx = blockIdx.x*256 + threadIdx.x;
  switch (blockIdx.y){
    case 0: { // b1 [128][256]
      if (idx >= 32768) return; int m = idx >> 8;
      wsplit(b_w1[idx]*b_g1[m], dh, dl, (size_t)0 + idx); } break;
    case 1: { // b2 [128][1152] k = tap*128+c
      if (idx >= 147456) return; int m = idx / 1152; int k = idx - m*1152;
      int tap = k >> 7, c = k & 127;
      wsplit(b_w2[((size_t)(m*128 + c))*9 + tap]*b_g2[m], dh, dl, 32768 + (size_t)idx); } break;
    case 2: { // xbase dual [512][384]
      if (idx >= 196608) return; int m = idx / 384; int k = idx - m*384;
      float v = (k < 128) ? b_w3[m*128 + k]*b_g3[m] : b_dw[m*256 + (k-128)]*b_dg[m];
      wsplit(v, dh, dl, 180224 + (size_t)idx); } break;
    case 3: { // r1 [128][256]
      if (idx >= 32768) return; int m = idx >> 8;
      wsplit(r_w1[idx]*r_g1[m], dh, dl, 376832 + (size_t)idx); } break;
    case 4: { // r2 [128][1152]
      if (idx >= 147456) return; int m = idx / 1152; int k = idx - m*1152;
      int tap = k >> 7, c = k & 127;
      wsplit(r_w2[((size_t)(m*128 + c))*9 + tap]*r_g2[m], dh, dl, 409600 + (size_t)idx); } break;
    case 5: { // fuse dual [512][384]
      if (idx >= 196608) return; int m = idx / 384; int k = idx - m*384;
      float v = (k < 128) ? r_w3[m*128 + k]*r_g3[m] : r_dw[m*256 + (k-128)]*r_dg[m];
      wsplit(v, dh, dl, 557056 + (size_t)idx); } break;
    case 6: { // f1 [128][512]
      if (idx >= 65536) return; int m = idx >> 9;
      wsplit(f_w1[idx]*f_g1[m], dh, dl, 753664 + (size_t)idx); } break;
    case 7: { // f2 [128][1152]
      if (idx >= 147456) return; int m = idx / 1152; int k = idx - m*1152;
      int tap = k >> 7, c = k & 127;
      wsplit(f_w2[((size_t)(m*128 + c))*9 + tap]*f_g2[m], dh, dl, 819200 + (size_t)idx); } break;
    case 8: { // final [512][128]
      if (idx >= 65536) return; int m = idx >> 7;
      wsplit(f_w3[idx]*f_g3[m], dh, dl, 966656 + (size_t)idx); } break;
  }
}

// ============ avgpool 3x3 s2 p1 on x, f32 NCHW -> f32 NCHW temp ============
__global__ __launch_bounds__(256) void k_avgpool_x(const float* __restrict__ x, float* __restrict__ out){
  int idx = blockIdx.x*256 + threadIdx.x;
  if (idx >= BB*CINX*HWP) return;
  int p = idx % HWP; int bc = idx / HWP;
  int ox = p % WP, oy = p / WP;
  const float* src = x + (size_t)bc*HWX;
  float s = 0.f;
  #pragma unroll
  for (int dy=0; dy<3; dy++){
    int yy = 2*oy-1+dy;
    if ((unsigned)yy >= HH) continue;
    #pragma unroll
    for (int dx=0; dx<3; dx++){
      int xx = 2*ox-1+dx;
      if ((unsigned)xx >= WW) continue;
      s += src[yy*WW + xx];
    }
  }
  out[idx] = s * (1.f/9.f);
}

// ============ pooled f32 NCHW -> NHWC hi/lo (16x16 LDS transpose) ============
__global__ __launch_bounds__(256) void prep_p(const float* __restrict__ t,
    ushortT* __restrict__ ph_, ushortT* __restrict__ pl_){
  __shared__ float s[16][17];
  const int p0 = blockIdx.x*16, c0 = blockIdx.y*16, bz = blockIdx.z;
  const int ci = threadIdx.x >> 4, pi = threadIdx.x & 15;
  s[ci][pi] = t[((size_t)bz*CINX + c0 + ci)*HWP + p0 + pi];
  __syncthreads();
  const int pr = threadIdx.x >> 4, cj = threadIdx.x & 15;
  float v = s[cj][pr];
  ushortT h, lo; split2(v, h, lo);
  size_t o = ((size_t)bz*HWP + p0 + pr)*CINX + c0 + cj;
  ph_[o] = h; pl_[o] = lo;
}

// ============ unified bf16x3-split MFMA implicit-GEMM ============
// KIND: 0=1x1, 1=3x3, 2=dual K-concat, 3=dual K-concat with mask on src1
// S1F/S2F: 0 = pre-split NHWC hi/lo pair, 1 = f32 NCHW gather (x), split on the fly
// EPI:  0=bias+relu->hi/lo NHWC, 1=bias1+bias2->f32 NCHW,
//       2=fuse(bilinear+mask+relu->hi/lo), 3=final(+avgpool(fused)+relu->f32 NCHW)
template<int KIND,int EPI,int S1F,int S2F,int STRIDE,int PAD,int HIN,int WIN,
         int WOUT,int NOUT,int C1,int C2,int MTOT,int KTOT>
__global__ __launch_bounds__(256)
void gemm_bf3(const ushortT* __restrict__ wph, const ushortT* __restrict__ wpl,
              const ushortT* __restrict__ s1h, const ushortT* __restrict__ s1l,
              const ushortT* __restrict__ s2h, const ushortT* __restrict__ s2l,
              const float* __restrict__ xf32,
              const float* __restrict__ bias1, const float* __restrict__ bias2,
              const float* __restrict__ maskf, const float* __restrict__ xbase,
              ushortT* __restrict__ oh, ushortT* __restrict__ ol,
              float* __restrict__ of32,
              const ushortT* __restrict__ fzh, const ushortT* __restrict__ fzl)
{
  __shared__ ushortT smem[16384];           // 32 KiB: A_hi A_lo B_hi B_lo
  ushortT* AH  = smem;
  ushortT* AL  = smem + 4096;
  ushortT* BHs = smem + 8192;
  ushortT* BLs = smem + 12288;

  const int tid = threadIdx.x;
  const int nt = blockIdx.x, mt = blockIdx.y, bz = blockIdx.z;
  const int l  = tid & 63, w = tid >> 6;
  const int wm = w >> 1, wn = w & 1;

  // staging: row sr (0..127), 16-elem half hp; swizzled 16B slots:
  // elem (row,k): off = row*32 + (slot ^ ((row>>1)&3))*8 + (k&7), slot=k>>3
  const int sr = tid >> 1;
  const int hp = tid & 1;
  const int swz = (sr >> 1) & 3;
  const int lws0 = sr*32 + ((2*hp) ^ swz)*8;
  const int lws1 = sr*32 + ((2*hp + 1) ^ swz)*8;

  const size_t arow = (size_t)(mt*128 + sr)*KTOT + hp*16;

  const int ng = nt*128 + sr;               // staging output position
  int oyS = 0, oxS = 0;
  if (KIND == 1){ oyS = ng / WOUT; oxS = ng - (ng / WOUT)*WOUT; }

  float mvstage = 1.f;
  if (KIND == 3){
    if (ng < NOUT){
      int yy = ng / WOUT, xx = ng - (ng / WOUT)*WOUT;
      mvstage = maskf[((size_t)(bz*NG + mt)*MSZ + (yy>>3))*MSZ + (xx>>3)];
    } else mvstage = 0.f;
  }

  f32x4 acc[4][4];
  f32x4 zf = {0.f,0.f,0.f,0.f};
  #pragma unroll
  for (int i=0;i<4;i++)
    #pragma unroll
    for (int j=0;j<4;j++) acc[i][j] = zf;

  const int NK = KTOT / 32;
  for (int ks=0; ks<NK; ks++){
    const int k0 = ks*32;
    // A stage
    uint4 a0 = *(const uint4*)(wph + arow + k0);
    uint4 a1 = *(const uint4*)(wph + arow + k0 + 8);
    uint4 a2 = *(const uint4*)(wpl + arow + k0);
    uint4 a3 = *(const uint4*)(wpl + arow + k0 + 8);
    // B stage
    uint4 b0 = make_uint4(0,0,0,0), b1v = b0, b2v = b0, b3v = b0;
    bool valid = false;
    bool usef = false;
    size_t brow = 0, fbase = 0;
    const ushortT* psh = s1h; const ushortT* psl = s1l;
    if (KIND == 0){
      valid = (ng < NOUT);
      if (S1F == 1){
        usef = true;
        fbase = ((size_t)bz*C1 + k0 + hp*16)*(size_t)NOUT + ng;
      } else {
        brow = ((size_t)bz*NOUT + ng)*C1 + k0 + hp*16;
      }
    } else if (KIND == 1){
      const int tap = k0 / C1;
      const int c   = k0 - tap*C1;
      const int dy = tap/3, dx = tap - 3*(tap/3);
      const int iy = oyS*STRIDE + dy - PAD;
      const int ix = oxS*STRIDE + dx - PAD;
      valid = (ng < NOUT) && (iy >= 0) && (iy < HIN) && (ix >= 0) && (ix < WIN);
      brow = ((size_t)bz*(HIN*WIN) + (size_t)(iy*WIN + ix))*C1 + c + hp*16;
    } else {
      valid = (ng < NOUT);
      if (k0 < C1){
        if (KIND == 3 && mvstage == 0.f) valid = false;   // exact {0,1} mask
        brow = ((size_t)bz*NOUT + ng)*C1 + k0 + hp*16;
      } else {
        if (S2F == 1){
          usef = true;
          fbase = ((size_t)bz*C2 + (k0 - C1) + hp*16)*(size_t)NOUT + ng;
        } else {
          psh = s2h; psl = s2l;
          brow = ((size_t)bz*NOUT + ng)*C2 + (k0 - C1) + hp*16;
        }
      }
    }
    if (valid){
      if (usef){
        ushortT h[16], lo[16];
        #pragma unroll
        for (int e=0;e<16;e++){
          float v = xf32[fbase + (size_t)e*NOUT];
          split2(v, h[e], lo[e]);
        }
        b0  = make_uint4(packu(h[0],h[1]),  packu(h[2],h[3]),  packu(h[4],h[5]),  packu(h[6],h[7]));
        b1v = make_uint4(packu(h[8],h[9]),  packu(h[10],h[11]),packu(h[12],h[13]),packu(h[14],h[15]));
        b2v = make_uint4(packu(lo[0],lo[1]),packu(lo[2],lo[3]),packu(lo[4],lo[5]),packu(lo[6],lo[7]));
        b3v = make_uint4(packu(lo[8],lo[9]),packu(lo[10],lo[11]),packu(lo[12],lo[13]),packu(lo[14],lo[15]));
      } else {
        b0  = *(const uint4*)(psh + brow);
        b1v = *(const uint4*)(psh + brow + 8);
        b2v = *(const uint4*)(psl + brow);
        b3v = *(const uint4*)(psl + brow + 8);
      }
    }
    *(uint4*)(AH  + lws0) = a0;  *(uint4*)(AH  + lws1) = a1;
    *(uint4*)(AL  + lws0) = a2;  *(uint4*)(AL  + lws1) = a3;
    *(uint4*)(BHs + lws0) = b0;  *(uint4*)(BHs + lws1) = b1v;
    *(uint4*)(BLs + lws0) = b2v; *(uint4*)(BLs + lws1) = b3v;
    __syncthreads();

    short8 bh[4], bl[4];
    #pragma unroll
    for (int nf=0; nf<4; nf++){
      const int rr = wn*64 + nf*16 + (l & 15);
      const int ph = (l >> 4) ^ ((rr >> 1) & 3);
      bh[nf] = *(const short8*)(BHs + rr*32 + ph*8);
      bl[nf] = *(const short8*)(BLs + rr*32 + ph*8);
    }
    #pragma unroll
    for (int mf=0; mf<4; mf++){
      const int rr = wm*64 + mf*16 + (l & 15);
      const int ph = (l >> 4) ^ ((rr >> 1) & 3);
      short8 ah = *(const short8*)(AH + rr*32 + ph*8);
      short8 al = *(const short8*)(AL + rr*32 + ph*8);
      #pragma unroll
      for (int nf=0; nf<4; nf++)
        acc[mf][nf] = __builtin_amdgcn_mfma_f32_16x16x32_bf16(ah, bh[nf], acc[mf][nf], 0,0,0);
      #pragma unroll
      for (int nf=0; nf<4; nf++)
        acc[mf][nf] = __builtin_amdgcn_mfma_f32_16x16x32_bf16(ah, bl[nf], acc[mf][nf], 0,0,0);
      #pragma unroll
      for (int nf=0; nf<4; nf++)
        acc[mf][nf] = __builtin_amdgcn_mfma_f32_16x16x32_bf16(al, bh[nf], acc[mf][nf], 0,0,0);
    }
    __syncthreads();
  }

  // epilogue: C/D frag: col n = l&15, row m = (l>>4)*4 + r
  const int mb0 = mt*128 + wm*64;
  const int nb0 = nt*128 + wn*64;

  #pragma unroll
  for (int nf=0; nf<4; nf++){
    const int n = nb0 + nf*16 + (l & 15);
    if (n >= NOUT) continue;
    if constexpr (EPI == 0){
      const size_t ob = ((size_t)bz*NOUT + n)*MTOT;
      #pragma unroll
      for (int mf=0; mf<4; mf++){
        const int m0 = mb0 + mf*16 + (l>>4)*4;
        ushort4 hq, lq; ushortT h0, l0; float v;
        v = fmaxf(acc[mf][nf][0] + bias1[m0+0], 0.f); split2(v,h0,l0); hq.x=h0; lq.x=l0;
        v = fmaxf(acc[mf][nf][1] + bias1[m0+1], 0.f); split2(v,h0,l0); hq.y=h0; lq.y=l0;
        v = fmaxf(acc[mf][nf][2] + bias1[m0+2], 0.f); split2(v,h0,l0); hq.z=h0; lq.z=l0;
        v = fmaxf(acc[mf][nf][3] + bias1[m0+3], 0.f); split2(v,h0,l0); hq.w=h0; lq.w=l0;
        *(ushort4*)(oh + ob + m0) = hq;
        *(ushort4*)(ol + ob + m0) = lq;
      }
    } else if constexpr (EPI == 1){
      #pragma unroll
      for (int mf=0; mf<4; mf++){
        const int m0 = mb0 + mf*16 + (l>>4)*4;
        #pragma unroll
        for (int r=0;r<4;r++){
          const int m = m0 + r;
          of32[((size_t)bz*MTOT + m)*NOUT + n] = acc[mf][nf][r] + bias1[m] + bias2[m];
        }
      }
    } else if constexpr (EPI == 2){
      const int y = n / WOUT, x = n - (n / WOUT)*WOUT;
      const float mvv = maskf[((size_t)(bz*NG + mt)*MSZ + (y>>3))*MSZ + (x>>3)];
      const int iy = y >> 1, ix = x >> 1;
      int yA,yB,xA,xB; float wyA,wyB,wxA,wxB;
      if (y & 1){ yA=iy; wyA=0.75f; yB=(iy+1<HP)?iy+1:HP-1; wyB=0.25f; }
      else      { yA=(iy>0)?iy-1:0; wyA=0.25f; yB=iy; wyB=0.75f; }
      if (x & 1){ xA=ix; wxA=0.75f; xB=(ix+1<WP)?ix+1:WP-1; wxB=0.25f; }
      else      { xA=(ix>0)?ix-1:0; wxA=0.25f; xB=ix; wxB=0.75f; }
      const size_t ob = ((size_t)bz*NOUT + n)*MTOT;
      #pragma unroll
      for (int mf=0; mf<4; mf++){
        const int m0 = mb0 + mf*16 + (l>>4)*4;
        ushort4 hq, lq;
        #pragma unroll
        for (int r=0;r<4;r++){
          const int m = m0 + r;
          const float* xb = xbase + ((size_t)bz*MTOT + m)*HWP;
          float up = wyA*(wxA*xb[yA*WP+xA] + wxB*xb[yA*WP+xB])
                   + wyB*(wxA*xb[yB*WP+xA] + wxB*xb[yB*WP+xB]);
          float v = fmaxf(acc[mf][nf][r] + up + mvv*bias1[m] + bias2[m], 0.f);
          ushortT h0, l0; split2(v, h0, l0);
          if      (r==0){hq.x=h0;lq.x=l0;}
          else if (r==1){hq.y=h0;lq.y=l0;}
          else if (r==2){hq.z=h0;lq.z=l0;}
          else          {hq.w=h0;lq.w=l0;}
        }
        *(ushort4*)(oh + ob + m0) = hq;
        *(ushort4*)(ol + ob + m0) = lq;
      }
    } else { // EPI == 3
      const int oy = n / WOUT, ox = n - (n / WOUT)*WOUT;   // 28x28
      #pragma unroll
      for (int mf=0; mf<4; mf++){
        const int m0 = mb0 + mf*16 + (l>>4)*4;
        #pragma unroll
        for (int r=0;r<4;r++){
          const int m = m0 + r;
          float s = 0.f;
          #pragma unroll
          for (int dy=0; dy<3; dy++){
            const int iy = 2*oy - 1 + dy;
            if ((unsigned)iy >= (unsigned)HH) continue;
            #pragma unroll
            for (int dx=0; dx<3; dx++){
              const int ix = 2*ox - 1 + dx;
              if ((unsigned)ix >= (unsigned)WW) continue;
              const size_t fi = ((size_t)bz*HWX + (size_t)(iy*WW + ix))*CO + m;
              s += bf2f(fzh[fi]) + bf2f(fzl[fi]);
            }
          }
          float v = acc[mf][nf][r] + bias1[m] + s*(1.f/9.f);
          of32[((size_t)bz*MTOT + m)*NOUT + n] = fmaxf(v, 0.f);
        }
      }
    }
  }
}

// ============ mask path tail (round-2 proven) ============
__global__ __launch_bounds__(256) void k_gmap(const float* __restrict__ xbase, const float* __restrict__ mw,
    const float* __restrict__ mg, const float* __restrict__ mb, float* __restrict__ gmap){
  __shared__ float wsh[PL*9];
  int tid = threadIdx.x;
  int oc = blockIdx.y; int b = blockIdx.x;
  for (int i=tid;i<PL*9;i+=256) wsh[i]=mw[(size_t)oc*PL*9+i];
  __syncthreads();
  float gg=mg[oc], bb2=mb[oc];
  int grp = oc >> 2;
  const float* src = xbase + ((size_t)b*CO + grp*PL)*HWP;
  for (int p=tid; p<HWP; p+=256){
    int oy=p/WP, ox=p%WP;
    float a = 0.f;
    for (int c=0;c<PL;c++){
      const float* sc = src + (size_t)c*HWP;
      #pragma unroll
      for (int dy=0;dy<3;dy++){
        int yy=oy-1+dy; if((unsigned)yy>=HP) continue;
        #pragma unroll
        for (int dx=0;dx<3;dx++){
          int xx=ox-1+dx; if((unsigned)xx>=WP) continue;
          a += sc[yy*WP+xx]*wsh[c*9+dy*3+dx];
        }
      }
    }
    gmap[((size_t)b*16+oc)*HWP + p] = fmaxf(a*gg+bb2, 0.f);
  }
}

__global__ __launch_bounds__(256) void k_gpool(const float* __restrict__ gmap, float* __restrict__ gpool){
  int idx = blockIdx.x*256 + threadIdx.x;
  if (idx >= BB*16*49) return;
  int q = idx % 49; int t = idx / 49; int ch = t % 16; int b = t / 16;
  int my = q/7, mx = q%7;
  const float* src = gmap + ((size_t)b*16 + ch)*HWP;
  float s = 0.f;
  #pragma unroll
  for (int yb=0;yb<4;yb++)
    #pragma unroll
    for (int xb=0;xb<4;xb++)
      s += src[(my*4+yb)*WP + (mx*4+xb)];
  gpool[idx] = s * (1.f/16.f);
}

__global__ __launch_bounds__(256) void k_mask(const float* __restrict__ gpool, const float* __restrict__ fcw,
    const float* __restrict__ fcb, const float* __restrict__ gum,
    float* __restrict__ maskf, float* __restrict__ mout){
  int idx = blockIdx.x*256 + threadIdx.x;
  if (idx >= BB*NG*49) return;
  int q = idx % 49; int t = idx / 49; int g = t % NG; int b = t / NG;
  float lgt[2];
  #pragma unroll
  for (int cls=0; cls<2; cls++){
    int c = cls*NG + g;
    int gc = c >> 1;
    float s = fcb[c];
    #pragma unroll
    for (int k=0;k<4;k++)
      s += fcw[c*4+k] * gpool[((size_t)b*16 + gc*4 + k)*49 + q];
    s += gum[(((size_t)b*2 + cls)*NG + g)*49 + q];
    lgt[cls] = s;
  }
  float m = (lgt[1] > lgt[0]) ? 1.f : 0.f;
  maskf[idx] = m;
  mout[idx] = m;
}

extern "C" void kernel_launch(void* const* d_in, const int* in_sizes, int n_in,
                              void* d_out, int out_size, void* d_ws, size_t ws_size,
                              hipStream_t stream){
  const float* x    = (const float*)d_in[0];
  const float* gum  = (const float*)d_in[1];
  const float* b_w1 = (const float*)d_in[2];
  const float* b_g1 = (const float*)d_in[3];
  const float* b_b1 = (const float*)d_in[4];
  const float* b_w2 = (const float*)d_in[5];
  const float* b_g2 = (const float*)d_in[6];
  const float* b_b2 = (const float*)d_in[7];
  const float* b_w3 = (const float*)d_in[8];
  const float* b_g3 = (const float*)d_in[9];
  const float* b_b3 = (const float*)d_in[10];
  const float* b_dw = (const float*)d_in[11];
  const float* b_dg = (const float*)d_in[12];
  const float* b_db = (const float*)d_in[13];
  const float* r_w1 = (const float*)d_in[14];
  const float* r_g1 = (const float*)d_in[15];
  const float* r_b1 = (const float*)d_in[16];
  const float* r_w2 = (const float*)d_in[17];
  const float* r_g2 = (const float*)d_in[18];
  const float* r_b2 = (const float*)d_in[19];
  const float* r_w3 = (const float*)d_in[20];
  const float* r_g3 = (const float*)d_in[21];
  const float* r_b3 = (const float*)d_in[22];
  const float* r_dw = (const float*)d_in[23];
  const float* r_dg = (const float*)d_in[24];
  const float* r_db = (const float*)d_in[25];
  const float* m_w  = (const float*)d_in[26];
  const float* m_g  = (const float*)d_in[27];
  const float* m_b  = (const float*)d_in[28];
  const float* m_fcw= (const float*)d_in[29];
  const float* m_fcb= (const float*)d_in[30];
  const float* f_w1 = (const float*)d_in[31];
  const float* f_g1 = (const float*)d_in[32];
  const float* f_b1 = (const float*)d_in[33];
  const float* f_w2 = (const float*)d_in[34];
  const float* f_g2 = (const float*)d_in[35];
  const float* f_b2 = (const float*)d_in[36];
  const float* f_w3 = (const float*)d_in[37];
  const float* f_g3 = (const float*)d_in[38];
  const float* f_b3 = (const float*)d_in[39];

  char* ws = (char*)d_ws;
  // ws layout v2 — total 378,366,464 B (< round-2-proven 399,927,808)
  constexpr size_t O_WPH  = 0;            //  2,064,384
  constexpr size_t O_WPL  = 2064384;      //  2,064,384  -> 4,128,768
  constexpr size_t O_CH   = 4128768;      // 25,690,112  t1/r1/f1 hi
  constexpr size_t O_CL   = 29818880;     // 25,690,112  -> 55,508,992
  constexpr size_t O_DH   = 55508992;     //  6,422,528  t2/f2 hi
  constexpr size_t O_DL   = 61931520;     //  6,422,528  -> 68,354,048
  constexpr size_t O_EH   = 68354048;     // 25,690,112  r2 hi
  constexpr size_t O_EL   = 94044160;     // 25,690,112  -> 119,734,272
  constexpr size_t O_XB   = 119734272;    // 51,380,224  xbase f32 NCHW (first 25.7MB doubles as pooled-NCHW tmp)
  constexpr size_t O_GMAP = 171114496;    //  1,605,632
  constexpr size_t O_GPOOL= 172720128;    //    100,352
  constexpr size_t O_MASK = 172820480;    //     25,088  -> 172,845,568
  constexpr size_t O_FH   = 172845568;    // 102,760,448 fused hi (overlaps PH/PL, dead by then)
  constexpr size_t O_PH   = 172845568;    // 12,845,056  pooled hi (dead after xbase GEMM)
  constexpr size_t O_PL   = 185690624;    // 12,845,056  -> 198,535,680 (inside FH region)
  constexpr size_t O_FL   = 275606016;    // 102,760,448 -> 378,366,464

  ushortT* WPH = (ushortT*)(ws + O_WPH);
  ushortT* WPL = (ushortT*)(ws + O_WPL);
  ushortT* CHp = (ushortT*)(ws + O_CH);
  ushortT* CLp = (ushortT*)(ws + O_CL);
  ushortT* DHp = (ushortT*)(ws + O_DH);
  ushortT* DLp = (ushortT*)(ws + O_DL);
  ushortT* EHp = (ushortT*)(ws + O_EH);
  ushortT* ELp = (ushortT*)(ws + O_EL);
  float*   XB  = (float*)(ws + O_XB);
  float*   PTMP= (float*)(ws + O_XB);     // pooled NCHW tmp, dead before XB written
  ushortT* PHp = (ushortT*)(ws + O_PH);
  ushortT* PLp = (ushortT*)(ws + O_PL);
  ushortT* FHp = (ushortT*)(ws + O_FH);
  ushortT* FLp = (ushortT*)(ws + O_FL);
  float*   GMAP = (float*)(ws + O_GMAP);
  float*   GPOOL= (float*)(ws + O_GPOOL);
  float*   MASKF= (float*)(ws + O_MASK);
  (void)ws_size;

  float* outp = (float*)d_out;
  float* mout = outp + (size_t)BB*CO*HWP;

  dim3 blk(256);
  const ushortT* nu = nullptr; const float* nf_ = nullptr;
  ushortT* nuo = nullptr; float* nfo = nullptr;

  // prep
  prep_w<<<dim3(768, 9), blk, 0, stream>>>(b_w1,b_g1,b_w2,b_g2,b_w3,b_g3,b_dw,b_dg,
      r_w1,r_g1,r_w2,r_g2,r_w3,r_g3,r_dw,r_dg,f_w1,f_g1,f_w2,f_g2,f_w3,f_g3, WPH, WPL);
  k_avgpool_x<<<dim3((BB*CINX*HWP+255)/256), blk, 0, stream>>>(x, PTMP);
  prep_p<<<dim3(49, 16, BB), blk, 0, stream>>>(PTMP, PHp, PLp);

  // base branch
  gemm_bf3<0,0,1,0,1,0,56,56,56,3136,256,0,128,256><<<dim3(25,1,BB), blk, 0, stream>>>(
      WPH+0, WPL+0, nu, nu, nu, nu, x, b_b1, nf_, nf_, nf_, CHp, CLp, nfo, nu, nu);
  gemm_bf3<1,0,0,0,2,1,56,56,28,784,128,0,128,1152><<<dim3(7,1,BB), blk, 0, stream>>>(
      WPH+32768, WPL+32768, CHp, CLp, nu, nu, nf_, b_b2, nf_, nf_, nf_, DHp, DLp, nfo, nu, nu);
  gemm_bf3<2,1,0,0,1,0,28,28,28,784,128,256,512,384><<<dim3(7,4,BB), blk, 0, stream>>>(
      WPH+180224, WPL+180224, DHp, DLp, PHp, PLp, nf_, b_b3, b_db, nf_, nf_, nuo, nuo, XB, nu, nu);

  // mask path
  k_gmap<<<dim3(BB,16), blk, 0, stream>>>(XB, m_w, m_g, m_b, GMAP);
  k_gpool<<<dim3(98), blk, 0, stream>>>(GMAP, GPOOL);
  k_mask<<<dim3(25), blk, 0, stream>>>(GPOOL, m_fcw, m_fcb, gum, MASKF, mout);

  // refine branch
  gemm_bf3<0,0,1,0,1,0,56,56,56,3136,256,0,128,256><<<dim3(25,1,BB), blk, 0, stream>>>(
      WPH+376832, WPL+376832, nu, nu, nu, nu, x, r_b1, nf_, nf_, nf_, CHp, CLp, nfo, nu, nu);
  gemm_bf3<1,0,0,0,1,1,56,56,56,3136,128,0,128,1152><<<dim3(25,1,BB), blk, 0, stream>>>(
      WPH+409600, WPL+409600, CHp, CLp, nu, nu, nf_, r_b2, nf_, nf_, nf_, EHp, ELp, nfo, nu, nu);
  // fused = relu(up(xbase) + mask*(conv(r2)+b3) + conv(x)+db)
  gemm_bf3<3,2,0,1,1,0,56,56,56,3136,128,256,512,384><<<dim3(25,4,BB), blk, 0, stream>>>(
      WPH+557056, WPL+557056, EHp, ELp, nu, nu, x, r_b3, r_db, MASKF, XB, FHp, FLp, nfo, nu, nu);

  // fuse branch
  gemm_bf3<0,0,0,0,1,0,56,56,56,3136,512,0,128,512><<<dim3(25,1,BB), blk, 0, stream>>>(
      WPH+753664, WPL+753664, FHp, FLp, nu, nu, nf_, f_b1, nf_, nf_, nf_, CHp, CLp, nfo, nu, nu);
  gemm_bf3<1,0,0,0,2,1,56,56,28,784,128,0,128,1152><<<dim3(7,1,BB), blk, 0, stream>>>(
      WPH+819200, WPL+819200, CHp, CLp, nu, nu, nf_, f_b2, nf_, nf_, nf_, DHp, DLp, nfo, nu, nu);
  // out = relu(conv(f2)+b3 + avgpool3s2(fused))
  gemm_bf3<0,3,0,0,1,0,28,28,28,784,128,0,512,128><<<dim3(7,4,BB), blk, 0, stream>>>(
      WPH+966656, WPL+966656, DHp, DLp, nu, nu, nf_, f_b3, nf_, nf_, nf_, nuo, nuo, outp, FHp, FLp);
}

// Round 5
// 1474.638 us; speedup vs baseline: 5.1934x; 1.4632x over previous
//
#include <hip/hip_runtime.h>
#include <cstdint>

// dims
#define BB   32
#define CINX 256
#define HH   56
#define WW   56
#define HWX  3136
#define CO   512
#define PL   128
#define HP   28
#define WP   28
#define HWP  784
#define NG   4
#define MSZ  7

typedef unsigned short ushortT;
typedef unsigned int   uint32;
typedef __attribute__((ext_vector_type(8))) short short8;
typedef __attribute__((ext_vector_type(4))) float f32x4;

__device__ __forceinline__ ushortT f2bf(float f){
  uint32 u = __float_as_uint(f);
  u = (u + 0x7fffu + ((u >> 16) & 1u)) >> 16;   // RNE
  return (ushortT)u;
}
__device__ __forceinline__ float bf2f(ushortT u){
  return __uint_as_float(((uint32)u) << 16);
}
__device__ __forceinline__ void split2(float v, ushortT& h, ushortT& lo){
  h = f2bf(v);
  lo = f2bf(v - bf2f(h));
}
__device__ __forceinline__ uint32 packu(ushortT a, ushortT b){
  return (uint32)a | ((uint32)b << 16);
}

// ============ weight prep ============
__device__ __forceinline__ void wsplit(float v, ushortT* dh, ushortT* dl, size_t i){
  ushortT h, lo; split2(v, h, lo); dh[i] = h; dl[i] = lo;
}

__global__ __launch_bounds__(256) void prep_w(
  const float* __restrict__ b_w1, const float* __restrict__ b_g1,
  const float* __restrict__ b_w2, const float* __restrict__ b_g2,
  const float* __restrict__ b_w3, const float* __restrict__ b_g3,
  const float* __restrict__ b_dw, const float* __restrict__ b_dg,
  const float* __restrict__ r_w1, const float* __restrict__ r_g1,
  const float* __restrict__ r_w2, const float* __restrict__ r_g2,
  const float* __restrict__ r_w3, const float* __restrict__ r_g3,
  const float* __restrict__ r_dw, const float* __restrict__ r_dg,
  const float* __restrict__ f_w1, const float* __restrict__ f_g1,
  const float* __restrict__ f_w2, const float* __restrict__ f_g2,
  const float* __restrict__ f_w3, const float* __restrict__ f_g3,
  ushortT* __restrict__ dh, ushortT* __restrict__ dl)
{
  const int idx = blockIdx.x*256 + threadIdx.x;
  switch (blockIdx.y){
    case 0: { // b1 [128][256]
      if (idx >= 32768) return; int m = idx >> 8;
      wsplit(b_w1[idx]*b_g1[m], dh, dl, (size_t)0 + idx); } break;
    case 1: { // b2 [128][1152] k = tap*128+c
      if (idx >= 147456) return; int m = idx / 1152; int k = idx - m*1152;
      int tap = k >> 7, c = k & 127;
      wsplit(b_w2[((size_t)(m*128 + c))*9 + tap]*b_g2[m], dh, dl, 32768 + (size_t)idx); } break;
    case 2: { // xbase dual [512][384]
      if (idx >= 196608) return; int m = idx / 384; int k = idx - m*384;
      float v = (k < 128) ? b_w3[m*128 + k]*b_g3[m] : b_dw[m*256 + (k-128)]*b_dg[m];
      wsplit(v, dh, dl, 180224 + (size_t)idx); } break;
    case 3: { // r1 [128][256]
      if (idx >= 32768) return; int m = idx >> 8;
      wsplit(r_w1[idx]*r_g1[m], dh, dl, 376832 + (size_t)idx); } break;
    case 4: { // r2 [128][1152]
      if (idx >= 147456) return; int m = idx / 1152; int k = idx - m*1152;
      int tap = k >> 7, c = k & 127;
      wsplit(r_w2[((size_t)(m*128 + c))*9 + tap]*r_g2[m], dh, dl, 409600 + (size_t)idx); } break;
    case 5: { // fuse dual [512][384]
      if (idx >= 196608) return; int m = idx / 384; int k = idx - m*384;
      float v = (k < 128) ? r_w3[m*128 + k]*r_g3[m] : r_dw[m*256 + (k-128)]*r_dg[m];
      wsplit(v, dh, dl, 557056 + (size_t)idx); } break;
    case 6: { // f1 [128][512]
      if (idx >= 65536) return; int m = idx >> 9;
      wsplit(f_w1[idx]*f_g1[m], dh, dl, 753664 + (size_t)idx); } break;
    case 7: { // f2 [128][1152]
      if (idx >= 147456) return; int m = idx / 1152; int k = idx - m*1152;
      int tap = k >> 7, c = k & 127;
      wsplit(f_w2[((size_t)(m*128 + c))*9 + tap]*f_g2[m], dh, dl, 819200 + (size_t)idx); } break;
    case 8: { // final [512][128]
      if (idx >= 65536) return; int m = idx >> 7;
      wsplit(f_w3[idx]*f_g3[m], dh, dl, 966656 + (size_t)idx); } break;
  }
}

// ============ avgpool 3x3 s2 p1 on x, f32 NCHW -> f32 NCHW temp ============
__global__ __launch_bounds__(256) void k_avgpool_x(const float* __restrict__ x, float* __restrict__ out){
  int idx = blockIdx.x*256 + threadIdx.x;
  if (idx >= BB*CINX*HWP) return;
  int p = idx % HWP; int bc = idx / HWP;
  int ox = p % WP, oy = p / WP;
  const float* src = x + (size_t)bc*HWX;
  float s = 0.f;
  #pragma unroll
  for (int dy=0; dy<3; dy++){
    int yy = 2*oy-1+dy;
    if ((unsigned)yy >= HH) continue;
    #pragma unroll
    for (int dx=0; dx<3; dx++){
      int xx = 2*ox-1+dx;
      if ((unsigned)xx >= WW) continue;
      s += src[yy*WW + xx];
    }
  }
  out[idx] = s * (1.f/9.f);
}

// ============ pooled f32 NCHW -> NHWC hi/lo (16x16 LDS transpose) ============
__global__ __launch_bounds__(256) void prep_p(const float* __restrict__ t,
    ushortT* __restrict__ ph_, ushortT* __restrict__ pl_){
  __shared__ float s[16][17];
  const int p0 = blockIdx.x*16, c0 = blockIdx.y*16, bz = blockIdx.z;
  const int ci = threadIdx.x >> 4, pi = threadIdx.x & 15;
  s[ci][pi] = t[((size_t)bz*CINX + c0 + ci)*HWP + p0 + pi];
  __syncthreads();
  const int pr = threadIdx.x >> 4, cj = threadIdx.x & 15;
  float v = s[cj][pr];
  ushortT h, lo; split2(v, h, lo);
  size_t o = ((size_t)bz*HWP + p0 + pr)*CINX + c0 + cj;
  ph_[o] = h; pl_[o] = lo;
}

// ============ avgpool 3x3 s2 p1 on fused (NHWC hi/lo) -> f32 NHWC [bz][p][512] ============
__global__ __launch_bounds__(256) void k_poolf(const ushortT* __restrict__ fzh,
    const ushortT* __restrict__ fzl, float* __restrict__ pf){
  const int p = blockIdx.x, bz = blockIdx.y;
  const int oy = p / WP, ox = p - oy*WP;
  for (int c = threadIdx.x; c < CO; c += 256){
    float s = 0.f;
    #pragma unroll
    for (int dy=0; dy<3; dy++){
      const int iy = 2*oy - 1 + dy;
      if ((unsigned)iy >= (unsigned)HH) continue;
      #pragma unroll
      for (int dx=0; dx<3; dx++){
        const int ix = 2*ox - 1 + dx;
        if ((unsigned)ix >= (unsigned)WW) continue;
        const size_t fi = ((size_t)bz*HWX + (size_t)(iy*WW + ix))*CO + c;
        s += bf2f(fzh[fi]) + bf2f(fzl[fi]);
      }
    }
    pf[((size_t)bz*HWP + p)*CO + c] = s * (1.f/9.f);
  }
}

// ============ unified bf16x3-split MFMA implicit-GEMM ============
// KIND: 0=1x1, 1=3x3, 2=dual K-concat, 3=dual K-concat with mask on src1
// S1F/S2F: 0 = pre-split NHWC hi/lo pair, 1 = f32 NCHW gather (x), split on the fly
// EPI:  0=bias+relu->hi/lo NHWC, 1=bias1+bias2->f32 NCHW,
//       2=fuse(bilinear+mask+relu->hi/lo), 3=final(+pooledF NHWC f32 add+relu->f32 NCHW)
template<int KIND,int EPI,int S1F,int S2F,int STRIDE,int PAD,int HIN,int WIN,
         int WOUT,int NOUT,int C1,int C2,int MTOT,int KTOT>
__global__ __launch_bounds__(256)
void gemm_bf3(const ushortT* __restrict__ wph, const ushortT* __restrict__ wpl,
              const ushortT* __restrict__ s1h, const ushortT* __restrict__ s1l,
              const ushortT* __restrict__ s2h, const ushortT* __restrict__ s2l,
              const float* __restrict__ xf32,
              const float* __restrict__ bias1, const float* __restrict__ bias2,
              const float* __restrict__ maskf, const float* __restrict__ xbase,
              ushortT* __restrict__ oh, ushortT* __restrict__ ol,
              float* __restrict__ of32)
{
  __shared__ ushortT smem[16384];           // 32 KiB: A_hi A_lo B_hi B_lo
  ushortT* AH  = smem;
  ushortT* AL  = smem + 4096;
  ushortT* BHs = smem + 8192;
  ushortT* BLs = smem + 12288;

  const int tid = threadIdx.x;
  const int nt = blockIdx.x, mt = blockIdx.y, bz = blockIdx.z;
  const int l  = tid & 63, w = tid >> 6;
  const int wm = w >> 1, wn = w & 1;

  // staging: row sr (0..127), 16-elem half hp; swizzled 16B slots:
  // elem (row,k): off = row*32 + (slot ^ ((row>>1)&3))*8 + (k&7), slot=k>>3
  const int sr = tid >> 1;
  const int hp = tid & 1;
  const int swz = (sr >> 1) & 3;
  const int lws0 = sr*32 + ((2*hp) ^ swz)*8;
  const int lws1 = sr*32 + ((2*hp + 1) ^ swz)*8;

  const size_t arow = (size_t)(mt*128 + sr)*KTOT + hp*16;

  const int ng = nt*128 + sr;               // staging output position
  int oyS = 0, oxS = 0;
  if (KIND == 1){ oyS = ng / WOUT; oxS = ng - (ng / WOUT)*WOUT; }

  float mvstage = 1.f;
  if (KIND == 3){
    if (ng < NOUT){
      int yy = ng / WOUT, xx = ng - (ng / WOUT)*WOUT;
      mvstage = maskf[((size_t)(bz*NG + mt)*MSZ + (yy>>3))*MSZ + (xx>>3)];
    } else mvstage = 0.f;
  }

  f32x4 acc[4][4];
  f32x4 zf = {0.f,0.f,0.f,0.f};
  #pragma unroll
  for (int i=0;i<4;i++)
    #pragma unroll
    for (int j=0;j<4;j++) acc[i][j] = zf;

  const int NK = KTOT / 32;
  for (int ks=0; ks<NK; ks++){
    const int k0 = ks*32;
    // A stage
    uint4 a0 = *(const uint4*)(wph + arow + k0);
    uint4 a1 = *(const uint4*)(wph + arow + k0 + 8);
    uint4 a2 = *(const uint4*)(wpl + arow + k0);
    uint4 a3 = *(const uint4*)(wpl + arow + k0 + 8);
    // B stage
    uint4 b0 = make_uint4(0,0,0,0), b1v = b0, b2v = b0, b3v = b0;
    bool valid = false;
    bool usef = false;
    size_t brow = 0, fbase = 0;
    const ushortT* psh = s1h; const ushortT* psl = s1l;
    if (KIND == 0){
      valid = (ng < NOUT);
      if (S1F == 1){
        usef = true;
        fbase = ((size_t)bz*C1 + k0 + hp*16)*(size_t)NOUT + ng;
      } else {
        brow = ((size_t)bz*NOUT + ng)*C1 + k0 + hp*16;
      }
    } else if (KIND == 1){
      const int tap = k0 / C1;
      const int c   = k0 - tap*C1;
      const int dy = tap/3, dx = tap - 3*(tap/3);
      const int iy = oyS*STRIDE + dy - PAD;
      const int ix = oxS*STRIDE + dx - PAD;
      valid = (ng < NOUT) && (iy >= 0) && (iy < HIN) && (ix >= 0) && (ix < WIN);
      brow = ((size_t)bz*(HIN*WIN) + (size_t)(iy*WIN + ix))*C1 + c + hp*16;
    } else {
      valid = (ng < NOUT);
      if (k0 < C1){
        if (KIND == 3 && mvstage == 0.f) valid = false;   // exact {0,1} mask
        brow = ((size_t)bz*NOUT + ng)*C1 + k0 + hp*16;
      } else {
        if (S2F == 1){
          usef = true;
          fbase = ((size_t)bz*C2 + (k0 - C1) + hp*16)*(size_t)NOUT + ng;
        } else {
          psh = s2h; psl = s2l;
          brow = ((size_t)bz*NOUT + ng)*C2 + (k0 - C1) + hp*16;
        }
      }
    }
    if (valid){
      if (usef){
        ushortT h[16], lo[16];
        #pragma unroll
        for (int e=0;e<16;e++){
          float v = xf32[fbase + (size_t)e*NOUT];
          split2(v, h[e], lo[e]);
        }
        b0  = make_uint4(packu(h[0],h[1]),  packu(h[2],h[3]),  packu(h[4],h[5]),  packu(h[6],h[7]));
        b1v = make_uint4(packu(h[8],h[9]),  packu(h[10],h[11]),packu(h[12],h[13]),packu(h[14],h[15]));
        b2v = make_uint4(packu(lo[0],lo[1]),packu(lo[2],lo[3]),packu(lo[4],lo[5]),packu(lo[6],lo[7]));
        b3v = make_uint4(packu(lo[8],lo[9]),packu(lo[10],lo[11]),packu(lo[12],lo[13]),packu(lo[14],lo[15]));
      } else {
        b0  = *(const uint4*)(psh + brow);
        b1v = *(const uint4*)(psh + brow + 8);
        b2v = *(const uint4*)(psl + brow);
        b3v = *(const uint4*)(psl + brow + 8);
      }
    }
    *(uint4*)(AH  + lws0) = a0;  *(uint4*)(AH  + lws1) = a1;
    *(uint4*)(AL  + lws0) = a2;  *(uint4*)(AL  + lws1) = a3;
    *(uint4*)(BHs + lws0) = b0;  *(uint4*)(BHs + lws1) = b1v;
    *(uint4*)(BLs + lws0) = b2v; *(uint4*)(BLs + lws1) = b3v;
    __syncthreads();

    short8 bh[4], bl[4];
    #pragma unroll
    for (int nf=0; nf<4; nf++){
      const int rr = wn*64 + nf*16 + (l & 15);
      const int ph = (l >> 4) ^ ((rr >> 1) & 3);
      bh[nf] = *(const short8*)(BHs + rr*32 + ph*8);
      bl[nf] = *(const short8*)(BLs + rr*32 + ph*8);
    }
    #pragma unroll
    for (int mf=0; mf<4; mf++){
      const int rr = wm*64 + mf*16 + (l & 15);
      const int ph = (l >> 4) ^ ((rr >> 1) & 3);
      short8 ah = *(const short8*)(AH + rr*32 + ph*8);
      short8 al = *(const short8*)(AL + rr*32 + ph*8);
      #pragma unroll
      for (int nf=0; nf<4; nf++)
        acc[mf][nf] = __builtin_amdgcn_mfma_f32_16x16x32_bf16(ah, bh[nf], acc[mf][nf], 0,0,0);
      #pragma unroll
      for (int nf=0; nf<4; nf++)
        acc[mf][nf] = __builtin_amdgcn_mfma_f32_16x16x32_bf16(ah, bl[nf], acc[mf][nf], 0,0,0);
      #pragma unroll
      for (int nf=0; nf<4; nf++)
        acc[mf][nf] = __builtin_amdgcn_mfma_f32_16x16x32_bf16(al, bh[nf], acc[mf][nf], 0,0,0);
    }
    __syncthreads();
  }

  // epilogue: C/D frag: col n = l&15, row m = (l>>4)*4 + r
  const int mb0 = mt*128 + wm*64;
  const int nb0 = nt*128 + wn*64;

  #pragma unroll
  for (int nf=0; nf<4; nf++){
    const int n = nb0 + nf*16 + (l & 15);
    if (n >= NOUT) continue;
    if constexpr (EPI == 0){
      const size_t ob = ((size_t)bz*NOUT + n)*MTOT;
      #pragma unroll
      for (int mf=0; mf<4; mf++){
        const int m0 = mb0 + mf*16 + (l>>4)*4;
        ushort4 hq, lq; ushortT h0, l0; float v;
        v = fmaxf(acc[mf][nf][0] + bias1[m0+0], 0.f); split2(v,h0,l0); hq.x=h0; lq.x=l0;
        v = fmaxf(acc[mf][nf][1] + bias1[m0+1], 0.f); split2(v,h0,l0); hq.y=h0; lq.y=l0;
        v = fmaxf(acc[mf][nf][2] + bias1[m0+2], 0.f); split2(v,h0,l0); hq.z=h0; lq.z=l0;
        v = fmaxf(acc[mf][nf][3] + bias1[m0+3], 0.f); split2(v,h0,l0); hq.w=h0; lq.w=l0;
        *(ushort4*)(oh + ob + m0) = hq;
        *(ushort4*)(ol + ob + m0) = lq;
      }
    } else if constexpr (EPI == 1){
      #pragma unroll
      for (int mf=0; mf<4; mf++){
        const int m0 = mb0 + mf*16 + (l>>4)*4;
        #pragma unroll
        for (int r=0;r<4;r++){
          const int m = m0 + r;
          of32[((size_t)bz*MTOT + m)*NOUT + n] = acc[mf][nf][r] + bias1[m] + bias2[m];
        }
      }
    } else if constexpr (EPI == 2){
      const int y = n / WOUT, x = n - (n / WOUT)*WOUT;
      const float mvv = maskf[((size_t)(bz*NG + mt)*MSZ + (y>>3))*MSZ + (x>>3)];
      const int iy = y >> 1, ix = x >> 1;
      int yA,yB,xA,xB; float wyA,wyB,wxA,wxB;
      if (y & 1){ yA=iy; wyA=0.75f; yB=(iy+1<HP)?iy+1:HP-1; wyB=0.25f; }
      else      { yA=(iy>0)?iy-1:0; wyA=0.25f; yB=iy; wyB=0.75f; }
      if (x & 1){ xA=ix; wxA=0.75f; xB=(ix+1<WP)?ix+1:WP-1; wxB=0.25f; }
      else      { xA=(ix>0)?ix-1:0; wxA=0.25f; xB=ix; wxB=0.75f; }
      const size_t ob = ((size_t)bz*NOUT + n)*MTOT;
      #pragma unroll
      for (int mf=0; mf<4; mf++){
        const int m0 = mb0 + mf*16 + (l>>4)*4;
        ushort4 hq, lq;
        #pragma unroll
        for (int r=0;r<4;r++){
          const int m = m0 + r;
          const float* xb = xbase + ((size_t)bz*MTOT + m)*HWP;
          float up = wyA*(wxA*xb[yA*WP+xA] + wxB*xb[yA*WP+xB])
                   + wyB*(wxA*xb[yB*WP+xA] + wxB*xb[yB*WP+xB]);
          float v = fmaxf(acc[mf][nf][r] + up + mvv*bias1[m] + bias2[m], 0.f);
          ushortT h0, l0; split2(v, h0, l0);
          if      (r==0){hq.x=h0;lq.x=l0;}
          else if (r==1){hq.y=h0;lq.y=l0;}
          else if (r==2){hq.z=h0;lq.z=l0;}
          else          {hq.w=h0;lq.w=l0;}
        }
        *(ushort4*)(oh + ob + m0) = hq;
        *(ushort4*)(ol + ob + m0) = lq;
      }
    } else { // EPI == 3: out = relu(acc + bias1 + pooledF)   (pooledF via xbase arg, f32 NHWC [bz][n][MTOT])
      const float* pfrow = xbase + ((size_t)bz*NOUT + n)*MTOT;
      #pragma unroll
      for (int mf=0; mf<4; mf++){
        const int m0 = mb0 + mf*16 + (l>>4)*4;
        const float4 pv = *(const float4*)(pfrow + m0);
        of32[((size_t)bz*MTOT + m0+0)*NOUT + n] = fmaxf(acc[mf][nf][0] + bias1[m0+0] + pv.x, 0.f);
        of32[((size_t)bz*MTOT + m0+1)*NOUT + n] = fmaxf(acc[mf][nf][1] + bias1[m0+1] + pv.y, 0.f);
        of32[((size_t)bz*MTOT + m0+2)*NOUT + n] = fmaxf(acc[mf][nf][2] + bias1[m0+2] + pv.z, 0.f);
        of32[((size_t)bz*MTOT + m0+3)*NOUT + n] = fmaxf(acc[mf][nf][3] + bias1[m0+3] + pv.w, 0.f);
      }
    }
  }
}

// ============ mask path tail (round-2 proven) ============
__global__ __launch_bounds__(256) void k_gmap(const float* __restrict__ xbase, const float* __restrict__ mw,
    const float* __restrict__ mg, const float* __restrict__ mb, float* __restrict__ gmap){
  __shared__ float wsh[PL*9];
  int tid = threadIdx.x;
  int oc = blockIdx.y; int b = blockIdx.x;
  for (int i=tid;i<PL*9;i+=256) wsh[i]=mw[(size_t)oc*PL*9+i];
  __syncthreads();
  float gg=mg[oc], bb2=mb[oc];
  int grp = oc >> 2;
  const float* src = xbase + ((size_t)b*CO + grp*PL)*HWP;
  for (int p=tid; p<HWP; p+=256){
    int oy=p/WP, ox=p%WP;
    float a = 0.f;
    for (int c=0;c<PL;c++){
      const float* sc = src + (size_t)c*HWP;
      #pragma unroll
      for (int dy=0;dy<3;dy++){
        int yy=oy-1+dy; if((unsigned)yy>=HP) continue;
        #pragma unroll
        for (int dx=0;dx<3;dx++){
          int xx=ox-1+dx; if((unsigned)xx>=WP) continue;
          a += sc[yy*WP+xx]*wsh[c*9+dy*3+dx];
        }
      }
    }
    gmap[((size_t)b*16+oc)*HWP + p] = fmaxf(a*gg+bb2, 0.f);
  }
}

__global__ __launch_bounds__(256) void k_gpool(const float* __restrict__ gmap, float* __restrict__ gpool){
  int idx = blockIdx.x*256 + threadIdx.x;
  if (idx >= BB*16*49) return;
  int q = idx % 49; int t = idx / 49; int ch = t % 16; int b = t / 16;
  int my = q/7, mx = q%7;
  const float* src = gmap + ((size_t)b*16 + ch)*HWP;
  float s = 0.f;
  #pragma unroll
  for (int yb=0;yb<4;yb++)
    #pragma unroll
    for (int xb=0;xb<4;xb++)
      s += src[(my*4+yb)*WP + (mx*4+xb)];
  gpool[idx] = s * (1.f/16.f);
}

__global__ __launch_bounds__(256) void k_mask(const float* __restrict__ gpool, const float* __restrict__ fcw,
    const float* __restrict__ fcb, const float* __restrict__ gum,
    float* __restrict__ maskf, float* __restrict__ mout){
  int idx = blockIdx.x*256 + threadIdx.x;
  if (idx >= BB*NG*49) return;
  int q = idx % 49; int t = idx / 49; int g = t % NG; int b = t / NG;
  float lgt[2];
  #pragma unroll
  for (int cls=0; cls<2; cls++){
    int c = cls*NG + g;
    int gc = c >> 1;
    float s = fcb[c];
    #pragma unroll
    for (int k=0;k<4;k++)
      s += fcw[c*4+k] * gpool[((size_t)b*16 + gc*4 + k)*49 + q];
    s += gum[(((size_t)b*2 + cls)*NG + g)*49 + q];
    lgt[cls] = s;
  }
  float m = (lgt[1] > lgt[0]) ? 1.f : 0.f;
  maskf[idx] = m;
  mout[idx] = m;
}

extern "C" void kernel_launch(void* const* d_in, const int* in_sizes, int n_in,
                              void* d_out, int out_size, void* d_ws, size_t ws_size,
                              hipStream_t stream){
  const float* x    = (const float*)d_in[0];
  const float* gum  = (const float*)d_in[1];
  const float* b_w1 = (const float*)d_in[2];
  const float* b_g1 = (const float*)d_in[3];
  const float* b_b1 = (const float*)d_in[4];
  const float* b_w2 = (const float*)d_in[5];
  const float* b_g2 = (const float*)d_in[6];
  const float* b_b2 = (const float*)d_in[7];
  const float* b_w3 = (const float*)d_in[8];
  const float* b_g3 = (const float*)d_in[9];
  const float* b_b3 = (const float*)d_in[10];
  const float* b_dw = (const float*)d_in[11];
  const float* b_dg = (const float*)d_in[12];
  const float* b_db = (const float*)d_in[13];
  const float* r_w1 = (const float*)d_in[14];
  const float* r_g1 = (const float*)d_in[15];
  const float* r_b1 = (const float*)d_in[16];
  const float* r_w2 = (const float*)d_in[17];
  const float* r_g2 = (const float*)d_in[18];
  const float* r_b2 = (const float*)d_in[19];
  const float* r_w3 = (const float*)d_in[20];
  const float* r_g3 = (const float*)d_in[21];
  const float* r_b3 = (const float*)d_in[22];
  const float* r_dw = (const float*)d_in[23];
  const float* r_dg = (const float*)d_in[24];
  const float* r_db = (const float*)d_in[25];
  const float* m_w  = (const float*)d_in[26];
  const float* m_g  = (const float*)d_in[27];
  const float* m_b  = (const float*)d_in[28];
  const float* m_fcw= (const float*)d_in[29];
  const float* m_fcb= (const float*)d_in[30];
  const float* f_w1 = (const float*)d_in[31];
  const float* f_g1 = (const float*)d_in[32];
  const float* f_b1 = (const float*)d_in[33];
  const float* f_w2 = (const float*)d_in[34];
  const float* f_g2 = (const float*)d_in[35];
  const float* f_b2 = (const float*)d_in[36];
  const float* f_w3 = (const float*)d_in[37];
  const float* f_g3 = (const float*)d_in[38];
  const float* f_b3 = (const float*)d_in[39];

  char* ws = (char*)d_ws;
  // ws layout v2 — total 378,366,464 B
  constexpr size_t O_WPH  = 0;            //  2,064,384
  constexpr size_t O_WPL  = 2064384;      //  2,064,384  -> 4,128,768
  constexpr size_t O_CH   = 4128768;      // 25,690,112  t1/r1/f1 hi
  constexpr size_t O_CL   = 29818880;     // 25,690,112  -> 55,508,992
  constexpr size_t O_DH   = 55508992;     //  6,422,528  t2/f2 hi
  constexpr size_t O_DL   = 61931520;     //  6,422,528  -> 68,354,048
  constexpr size_t O_EH   = 68354048;     // 25,690,112  r2 hi
  constexpr size_t O_EL   = 94044160;     // 25,690,112  -> 119,734,272
  constexpr size_t O_PF   = O_EH;         // 51,380,224  pooledF f32 NHWC (r2 dead after fuse)
  constexpr size_t O_XB   = 119734272;    // 51,380,224  xbase f32 NCHW (first 25.7MB doubles as pooled-NCHW tmp)
  constexpr size_t O_GMAP = 171114496;    //  1,605,632
  constexpr size_t O_GPOOL= 172720128;    //    100,352
  constexpr size_t O_MASK = 172820480;    //     25,088  -> 172,845,568
  constexpr size_t O_FH   = 172845568;    // 102,760,448 fused hi (overlaps PH/PL, dead by then)
  constexpr size_t O_PH   = 172845568;    // 12,845,056  pooled hi (dead after xbase GEMM)
  constexpr size_t O_PL   = 185690624;    // 12,845,056  -> 198,535,680 (inside FH region)
  constexpr size_t O_FL   = 275606016;    // 102,760,448 -> 378,366,464

  ushortT* WPH = (ushortT*)(ws + O_WPH);
  ushortT* WPL = (ushortT*)(ws + O_WPL);
  ushortT* CHp = (ushortT*)(ws + O_CH);
  ushortT* CLp = (ushortT*)(ws + O_CL);
  ushortT* DHp = (ushortT*)(ws + O_DH);
  ushortT* DLp = (ushortT*)(ws + O_DL);
  ushortT* EHp = (ushortT*)(ws + O_EH);
  ushortT* ELp = (ushortT*)(ws + O_EL);
  float*   PF  = (float*)(ws + O_PF);
  float*   XB  = (float*)(ws + O_XB);
  float*   PTMP= (float*)(ws + O_XB);     // pooled NCHW tmp, dead before XB written
  ushortT* PHp = (ushortT*)(ws + O_PH);
  ushortT* PLp = (ushortT*)(ws + O_PL);
  ushortT* FHp = (ushortT*)(ws + O_FH);
  ushortT* FLp = (ushortT*)(ws + O_FL);
  float*   GMAP = (float*)(ws + O_GMAP);
  float*   GPOOL= (float*)(ws + O_GPOOL);
  float*   MASKF= (float*)(ws + O_MASK);
  (void)ws_size;

  float* outp = (float*)d_out;
  float* mout = outp + (size_t)BB*CO*HWP;

  dim3 blk(256);
  const ushortT* nu = nullptr; const float* nf_ = nullptr;
  ushortT* nuo = nullptr; float* nfo = nullptr;

  // prep
  prep_w<<<dim3(768, 9), blk, 0, stream>>>(b_w1,b_g1,b_w2,b_g2,b_w3,b_g3,b_dw,b_dg,
      r_w1,r_g1,r_w2,r_g2,r_w3,r_g3,r_dw,r_dg,f_w1,f_g1,f_w2,f_g2,f_w3,f_g3, WPH, WPL);
  k_avgpool_x<<<dim3((BB*CINX*HWP+255)/256), blk, 0, stream>>>(x, PTMP);
  prep_p<<<dim3(49, 16, BB), blk, 0, stream>>>(PTMP, PHp, PLp);

  // base branch
  gemm_bf3<0,0,1,0,1,0,56,56,56,3136,256,0,128,256><<<dim3(25,1,BB), blk, 0, stream>>>(
      WPH+0, WPL+0, nu, nu, nu, nu, x, b_b1, nf_, nf_, nf_, CHp, CLp, nfo);
  gemm_bf3<1,0,0,0,2,1,56,56,28,784,128,0,128,1152><<<dim3(7,1,BB), blk, 0, stream>>>(
      WPH+32768, WPL+32768, CHp, CLp, nu, nu, nf_, b_b2, nf_, nf_, nf_, DHp, DLp, nfo);
  gemm_bf3<2,1,0,0,1,0,28,28,28,784,128,256,512,384><<<dim3(7,4,BB), blk, 0, stream>>>(
      WPH+180224, WPL+180224, DHp, DLp, PHp, PLp, nf_, b_b3, b_db, nf_, nf_, nuo, nuo, XB);

  // mask path
  k_gmap<<<dim3(BB,16), blk, 0, stream>>>(XB, m_w, m_g, m_b, GMAP);
  k_gpool<<<dim3(98), blk, 0, stream>>>(GMAP, GPOOL);
  k_mask<<<dim3(25), blk, 0, stream>>>(GPOOL, m_fcw, m_fcb, gum, MASKF, mout);

  // refine branch
  gemm_bf3<0,0,1,0,1,0,56,56,56,3136,256,0,128,256><<<dim3(25,1,BB), blk, 0, stream>>>(
      WPH+376832, WPL+376832, nu, nu, nu, nu, x, r_b1, nf_, nf_, nf_, CHp, CLp, nfo);
  gemm_bf3<1,0,0,0,1,1,56,56,56,3136,128,0,128,1152><<<dim3(25,1,BB), blk, 0, stream>>>(
      WPH+409600, WPL+409600, CHp, CLp, nu, nu, nf_, r_b2, nf_, nf_, nf_, EHp, ELp, nfo);
  // fused = relu(up(xbase) + mask*(conv(r2)+b3) + conv(x)+db)
  gemm_bf3<3,2,0,1,1,0,56,56,56,3136,128,256,512,384><<<dim3(25,4,BB), blk, 0, stream>>>(
      WPH+557056, WPL+557056, EHp, ELp, nu, nu, x, r_b3, r_db, MASKF, XB, FHp, FLp, nfo);

  // pooledF = avgpool3s2(fused)  (r2 region now dead -> PF)
  k_poolf<<<dim3(HWP, BB), blk, 0, stream>>>(FHp, FLp, PF);

  // fuse branch
  gemm_bf3<0,0,0,0,1,0,56,56,56,3136,512,0,128,512><<<dim3(25,1,BB), blk, 0, stream>>>(
      WPH+753664, WPL+753664, FHp, FLp, nu, nu, nf_, f_b1, nf_, nf_, nf_, CHp, CLp, nfo);
  gemm_bf3<1,0,0,0,2,1,56,56,28,784,128,0,128,1152><<<dim3(7,1,BB), blk, 0, stream>>>(
      WPH+819200, WPL+819200, CHp, CLp, nu, nu, nf_, f_b2, nf_, nf_, nf_, DHp, DLp, nfo);
  // out = relu(conv(f2)+b3 + pooledF)
  gemm_bf3<0,3,0,0,1,0,28,28,28,784,128,0,512,128><<<dim3(7,4,BB), blk, 0, stream>>>(
      WPH+966656, WPL+966656, DHp, DLp, nu, nu, nf_, f_b3, nf_, nf_, PF, nuo, nuo, outp);
}

// Round 6
// 1119.316 us; speedup vs baseline: 6.8420x; 1.3174x over previous
//
#include <hip/hip_runtime.h>
#include <cstdint>

// dims
#define BB   32
#define CINX 256
#define HH   56
#define WW   56
#define HWX  3136
#define CO   512
#define PL   128
#define HP   28
#define WP   28
#define HWP  784
#define NG   4
#define MSZ  7

typedef unsigned short ushortT;
typedef unsigned int   uint32;
typedef __attribute__((ext_vector_type(8))) short short8;
typedef __attribute__((ext_vector_type(4))) float f32x4;

__device__ __forceinline__ ushortT f2bf(float f){
  uint32 u = __float_as_uint(f);
  u = (u + 0x7fffu + ((u >> 16) & 1u)) >> 16;   // RNE
  return (ushortT)u;
}
__device__ __forceinline__ float bf2f(ushortT u){
  return __uint_as_float(((uint32)u) << 16);
}
__device__ __forceinline__ void split2(float v, ushortT& h, ushortT& lo){
  h = f2bf(v);
  lo = f2bf(v - bf2f(h));
}
__device__ __forceinline__ uint32 packu(ushortT a, ushortT b){
  return (uint32)a | ((uint32)b << 16);
}

// ============ weight prep ============
__device__ __forceinline__ void wsplit(float v, ushortT* dh, ushortT* dl, size_t i){
  ushortT h, lo; split2(v, h, lo); dh[i] = h; dl[i] = lo;
}

__global__ __launch_bounds__(256) void prep_w(
  const float* __restrict__ b_w1, const float* __restrict__ b_g1,
  const float* __restrict__ b_w2, const float* __restrict__ b_g2,
  const float* __restrict__ b_w3, const float* __restrict__ b_g3,
  const float* __restrict__ b_dw, const float* __restrict__ b_dg,
  const float* __restrict__ r_w1, const float* __restrict__ r_g1,
  const float* __restrict__ r_w2, const float* __restrict__ r_g2,
  const float* __restrict__ r_w3, const float* __restrict__ r_g3,
  const float* __restrict__ r_dw, const float* __restrict__ r_dg,
  const float* __restrict__ f_w1, const float* __restrict__ f_g1,
  const float* __restrict__ f_w2, const float* __restrict__ f_g2,
  const float* __restrict__ f_w3, const float* __restrict__ f_g3,
  ushortT* __restrict__ dh, ushortT* __restrict__ dl)
{
  const int idx = blockIdx.x*256 + threadIdx.x;
  switch (blockIdx.y){
    case 0: { // b1 [128][256]
      if (idx >= 32768) return; int m = idx >> 8;
      wsplit(b_w1[idx]*b_g1[m], dh, dl, (size_t)0 + idx); } break;
    case 1: { // b2 [128][1152] k = tap*128+c
      if (idx >= 147456) return; int m = idx / 1152; int k = idx - m*1152;
      int tap = k >> 7, c = k & 127;
      wsplit(b_w2[((size_t)(m*128 + c))*9 + tap]*b_g2[m], dh, dl, 32768 + (size_t)idx); } break;
    case 2: { // xbase dual [512][384]
      if (idx >= 196608) return; int m = idx / 384; int k = idx - m*384;
      float v = (k < 128) ? b_w3[m*128 + k]*b_g3[m] : b_dw[m*256 + (k-128)]*b_dg[m];
      wsplit(v, dh, dl, 180224 + (size_t)idx); } break;
    case 3: { // r1 [128][256]
      if (idx >= 32768) return; int m = idx >> 8;
      wsplit(r_w1[idx]*r_g1[m], dh, dl, 376832 + (size_t)idx); } break;
    case 4: { // r2 [128][1152]
      if (idx >= 147456) return; int m = idx / 1152; int k = idx - m*1152;
      int tap = k >> 7, c = k & 127;
      wsplit(r_w2[((size_t)(m*128 + c))*9 + tap]*r_g2[m], dh, dl, 409600 + (size_t)idx); } break;
    case 5: { // fuse dual [512][384]
      if (idx >= 196608) return; int m = idx / 384; int k = idx - m*384;
      float v = (k < 128) ? r_w3[m*128 + k]*r_g3[m] : r_dw[m*256 + (k-128)]*r_dg[m];
      wsplit(v, dh, dl, 557056 + (size_t)idx); } break;
    case 6: { // f1 [128][512]
      if (idx >= 65536) return; int m = idx >> 9;
      wsplit(f_w1[idx]*f_g1[m], dh, dl, 753664 + (size_t)idx); } break;
    case 7: { // f2 [128][1152]
      if (idx >= 147456) return; int m = idx / 1152; int k = idx - m*1152;
      int tap = k >> 7, c = k & 127;
      wsplit(f_w2[((size_t)(m*128 + c))*9 + tap]*f_g2[m], dh, dl, 819200 + (size_t)idx); } break;
    case 8: { // final [512][128]
      if (idx >= 65536) return; int m = idx >> 7;
      wsplit(f_w3[idx]*f_g3[m], dh, dl, 966656 + (size_t)idx); } break;
  }
}

// ============ avgpool 3x3 s2 p1 on x, f32 NCHW -> f32 NCHW temp ============
__global__ __launch_bounds__(256) void k_avgpool_x(const float* __restrict__ x, float* __restrict__ out){
  int idx = blockIdx.x*256 + threadIdx.x;
  if (idx >= BB*CINX*HWP) return;
  int p = idx % HWP; int bc = idx / HWP;
  int ox = p % WP, oy = p / WP;
  const float* src = x + (size_t)bc*HWX;
  float s = 0.f;
  #pragma unroll
  for (int dy=0; dy<3; dy++){
    int yy = 2*oy-1+dy;
    if ((unsigned)yy >= HH) continue;
    #pragma unroll
    for (int dx=0; dx<3; dx++){
      int xx = 2*ox-1+dx;
      if ((unsigned)xx >= WW) continue;
      s += src[yy*WW + xx];
    }
  }
  out[idx] = s * (1.f/9.f);
}

// ============ pooled f32 NCHW -> NHWC hi/lo (16x16 LDS transpose) ============
__global__ __launch_bounds__(256) void prep_p(const float* __restrict__ t,
    ushortT* __restrict__ ph_, ushortT* __restrict__ pl_){
  __shared__ float s[16][17];
  const int p0 = blockIdx.x*16, c0 = blockIdx.y*16, bz = blockIdx.z;
  const int ci = threadIdx.x >> 4, pi = threadIdx.x & 15;
  s[ci][pi] = t[((size_t)bz*CINX + c0 + ci)*HWP + p0 + pi];
  __syncthreads();
  const int pr = threadIdx.x >> 4, cj = threadIdx.x & 15;
  float v = s[cj][pr];
  ushortT h, lo; split2(v, h, lo);
  size_t o = ((size_t)bz*HWP + p0 + pr)*CINX + c0 + cj;
  ph_[o] = h; pl_[o] = lo;
}

// ============ avgpool 3x3 s2 p1 on fused (NHWC hi/lo) -> f32 NHWC [bz][p][512] ============
__global__ __launch_bounds__(256) void k_poolf(const ushortT* __restrict__ fzh,
    const ushortT* __restrict__ fzl, float* __restrict__ pf){
  const int p = blockIdx.x, bz = blockIdx.y;
  const int oy = p / WP, ox = p - oy*WP;
  const int c = threadIdx.x*2;            // 2 consecutive channels per thread
  float s0 = 0.f, s1 = 0.f;
  #pragma unroll
  for (int dy=0; dy<3; dy++){
    const int iy = 2*oy - 1 + dy;
    if ((unsigned)iy >= (unsigned)HH) continue;
    #pragma unroll
    for (int dx=0; dx<3; dx++){
      const int ix = 2*ox - 1 + dx;
      if ((unsigned)ix >= (unsigned)WW) continue;
      const size_t fi = ((size_t)bz*HWX + (size_t)(iy*WW + ix))*CO + c;
      uint32 hh = *(const uint32*)(fzh + fi);
      uint32 ll = *(const uint32*)(fzl + fi);
      s0 += bf2f((ushortT)(hh & 0xffff)) + bf2f((ushortT)(ll & 0xffff));
      s1 += bf2f((ushortT)(hh >> 16))    + bf2f((ushortT)(ll >> 16));
    }
  }
  const size_t o = ((size_t)bz*HWP + p)*CO + c;
  pf[o]   = s0 * (1.f/9.f);
  pf[o+1] = s1 * (1.f/9.f);
}

// ============ unified bf16x3-split MFMA implicit-GEMM ============
// KIND: 0=1x1, 1=3x3, 2=dual K-concat, 3=dual K-concat with mask on src1
// S1F/S2F: 0 = pre-split NHWC hi/lo pair, 1 = f32 NCHW gather (x), split on the fly
// EPI:  0=bias+relu->hi/lo NHWC, 1=bias1+bias2->f32 NCHW,
//       2=fuse(bilinear+mask+relu->hi/lo), 3=final(+pooledF NHWC f32 add+relu->f32 NCHW)
template<int KIND,int EPI,int S1F,int S2F,int STRIDE,int PAD,int HIN,int WIN,
         int WOUT,int NOUT,int C1,int C2,int MTOT,int KTOT>
__global__ __launch_bounds__(256)
void gemm_bf3(const ushortT* __restrict__ wph, const ushortT* __restrict__ wpl,
              const ushortT* __restrict__ s1h, const ushortT* __restrict__ s1l,
              const ushortT* __restrict__ s2h, const ushortT* __restrict__ s2l,
              const float* __restrict__ xf32,
              const float* __restrict__ bias1, const float* __restrict__ bias2,
              const float* __restrict__ maskf, const float* __restrict__ xbase,
              ushortT* __restrict__ oh, ushortT* __restrict__ ol,
              float* __restrict__ of32)
{
  __shared__ ushortT smem[16384];           // 32 KiB: A_hi A_lo B_hi B_lo
  ushortT* AH  = smem;
  ushortT* AL  = smem + 4096;
  ushortT* BHs = smem + 8192;
  ushortT* BLs = smem + 12288;

  const int tid = threadIdx.x;
  const int nt = blockIdx.x, mt = blockIdx.y, bz = blockIdx.z;
  const int l  = tid & 63, w = tid >> 6;
  const int wm = w >> 1, wn = w & 1;

  // staging: row sr (0..127), 16-elem half hp; swizzled 16B slots:
  // elem (row,k): off = row*32 + (slot ^ ((row>>1)&3))*8 + (k&7), slot=k>>3
  const int sr = tid >> 1;
  const int hp = tid & 1;
  const int swz = (sr >> 1) & 3;
  const int lws0 = sr*32 + ((2*hp) ^ swz)*8;
  const int lws1 = sr*32 + ((2*hp + 1) ^ swz)*8;

  const size_t arow = (size_t)(mt*128 + sr)*KTOT + hp*16;

  const int ng = nt*128 + sr;               // staging output position
  int oyS = 0, oxS = 0;
  if (KIND == 1){ oyS = ng / WOUT; oxS = ng - (ng / WOUT)*WOUT; }

  float mvstage = 1.f;
  if (KIND == 3){
    if (ng < NOUT){
      int yy = ng / WOUT, xx = ng - (ng / WOUT)*WOUT;
      mvstage = maskf[((size_t)(bz*NG + mt)*MSZ + (yy>>3))*MSZ + (xx>>3)];
    } else mvstage = 0.f;
  }

  f32x4 acc[4][4];
  f32x4 zf = {0.f,0.f,0.f,0.f};
  #pragma unroll
  for (int i=0;i<4;i++)
    #pragma unroll
    for (int j=0;j<4;j++) acc[i][j] = zf;

  const int NK = KTOT / 32;
  for (int ks=0; ks<NK; ks++){
    const int k0 = ks*32;
    // A stage
    uint4 a0 = *(const uint4*)(wph + arow + k0);
    uint4 a1 = *(const uint4*)(wph + arow + k0 + 8);
    uint4 a2 = *(const uint4*)(wpl + arow + k0);
    uint4 a3 = *(const uint4*)(wpl + arow + k0 + 8);
    // B stage
    uint4 b0 = make_uint4(0,0,0,0), b1v = b0, b2v = b0, b3v = b0;
    bool valid = false;
    bool usef = false;
    size_t brow = 0, fbase = 0;
    const ushortT* psh = s1h; const ushortT* psl = s1l;
    if (KIND == 0){
      valid = (ng < NOUT);
      if (S1F == 1){
        usef = true;
        fbase = ((size_t)bz*C1 + k0 + hp*16)*(size_t)NOUT + ng;
      } else {
        brow = ((size_t)bz*NOUT + ng)*C1 + k0 + hp*16;
      }
    } else if (KIND == 1){
      const int tap = k0 / C1;
      const int c   = k0 - tap*C1;
      const int dy = tap/3, dx = tap - 3*(tap/3);
      const int iy = oyS*STRIDE + dy - PAD;
      const int ix = oxS*STRIDE + dx - PAD;
      valid = (ng < NOUT) && (iy >= 0) && (iy < HIN) && (ix >= 0) && (ix < WIN);
      brow = ((size_t)bz*(HIN*WIN) + (size_t)(iy*WIN + ix))*C1 + c + hp*16;
    } else {
      valid = (ng < NOUT);
      if (k0 < C1){
        if (KIND == 3 && mvstage == 0.f) valid = false;   // exact {0,1} mask
        brow = ((size_t)bz*NOUT + ng)*C1 + k0 + hp*16;
      } else {
        if (S2F == 1){
          usef = true;
          fbase = ((size_t)bz*C2 + (k0 - C1) + hp*16)*(size_t)NOUT + ng;
        } else {
          psh = s2h; psl = s2l;
          brow = ((size_t)bz*NOUT + ng)*C2 + (k0 - C1) + hp*16;
        }
      }
    }
    if (valid){
      if (usef){
        ushortT h[16], lo[16];
        #pragma unroll
        for (int e=0;e<16;e++){
          float v = xf32[fbase + (size_t)e*NOUT];
          split2(v, h[e], lo[e]);
        }
        b0  = make_uint4(packu(h[0],h[1]),  packu(h[2],h[3]),  packu(h[4],h[5]),  packu(h[6],h[7]));
        b1v = make_uint4(packu(h[8],h[9]),  packu(h[10],h[11]),packu(h[12],h[13]),packu(h[14],h[15]));
        b2v = make_uint4(packu(lo[0],lo[1]),packu(lo[2],lo[3]),packu(lo[4],lo[5]),packu(lo[6],lo[7]));
        b3v = make_uint4(packu(lo[8],lo[9]),packu(lo[10],lo[11]),packu(lo[12],lo[13]),packu(lo[14],lo[15]));
      } else {
        b0  = *(const uint4*)(psh + brow);
        b1v = *(const uint4*)(psh + brow + 8);
        b2v = *(const uint4*)(psl + brow);
        b3v = *(const uint4*)(psl + brow + 8);
      }
    }
    *(uint4*)(AH  + lws0) = a0;  *(uint4*)(AH  + lws1) = a1;
    *(uint4*)(AL  + lws0) = a2;  *(uint4*)(AL  + lws1) = a3;
    *(uint4*)(BHs + lws0) = b0;  *(uint4*)(BHs + lws1) = b1v;
    *(uint4*)(BLs + lws0) = b2v; *(uint4*)(BLs + lws1) = b3v;
    __syncthreads();

    short8 bh[4], bl[4];
    #pragma unroll
    for (int nf=0; nf<4; nf++){
      const int rr = wn*64 + nf*16 + (l & 15);
      const int ph = (l >> 4) ^ ((rr >> 1) & 3);
      bh[nf] = *(const short8*)(BHs + rr*32 + ph*8);
      bl[nf] = *(const short8*)(BLs + rr*32 + ph*8);
    }
    #pragma unroll
    for (int mf=0; mf<4; mf++){
      const int rr = wm*64 + mf*16 + (l & 15);
      const int ph = (l >> 4) ^ ((rr >> 1) & 3);
      short8 ah = *(const short8*)(AH + rr*32 + ph*8);
      short8 al = *(const short8*)(AL + rr*32 + ph*8);
      #pragma unroll
      for (int nf=0; nf<4; nf++)
        acc[mf][nf] = __builtin_amdgcn_mfma_f32_16x16x32_bf16(ah, bh[nf], acc[mf][nf], 0,0,0);
      #pragma unroll
      for (int nf=0; nf<4; nf++)
        acc[mf][nf] = __builtin_amdgcn_mfma_f32_16x16x32_bf16(ah, bl[nf], acc[mf][nf], 0,0,0);
      #pragma unroll
      for (int nf=0; nf<4; nf++)
        acc[mf][nf] = __builtin_amdgcn_mfma_f32_16x16x32_bf16(al, bh[nf], acc[mf][nf], 0,0,0);
    }
    __syncthreads();
  }

  // epilogue: C/D frag: col n = l&15, row m = (l>>4)*4 + r
  const int mb0 = mt*128 + wm*64;
  const int nb0 = nt*128 + wn*64;

  #pragma unroll
  for (int nf=0; nf<4; nf++){
    const int n = nb0 + nf*16 + (l & 15);
    if (n >= NOUT) continue;
    if constexpr (EPI == 0){
      const size_t ob = ((size_t)bz*NOUT + n)*MTOT;
      #pragma unroll
      for (int mf=0; mf<4; mf++){
        const int m0 = mb0 + mf*16 + (l>>4)*4;
        ushort4 hq, lq; ushortT h0, l0; float v;
        v = fmaxf(acc[mf][nf][0] + bias1[m0+0], 0.f); split2(v,h0,l0); hq.x=h0; lq.x=l0;
        v = fmaxf(acc[mf][nf][1] + bias1[m0+1], 0.f); split2(v,h0,l0); hq.y=h0; lq.y=l0;
        v = fmaxf(acc[mf][nf][2] + bias1[m0+2], 0.f); split2(v,h0,l0); hq.z=h0; lq.z=l0;
        v = fmaxf(acc[mf][nf][3] + bias1[m0+3], 0.f); split2(v,h0,l0); hq.w=h0; lq.w=l0;
        *(ushort4*)(oh + ob + m0) = hq;
        *(ushort4*)(ol + ob + m0) = lq;
      }
    } else if constexpr (EPI == 1){
      #pragma unroll
      for (int mf=0; mf<4; mf++){
        const int m0 = mb0 + mf*16 + (l>>4)*4;
        #pragma unroll
        for (int r=0;r<4;r++){
          const int m = m0 + r;
          of32[((size_t)bz*MTOT + m)*NOUT + n] = acc[mf][nf][r] + bias1[m] + bias2[m];
        }
      }
    } else if constexpr (EPI == 2){
      const int y = n / WOUT, x = n - (n / WOUT)*WOUT;
      const float mvv = maskf[((size_t)(bz*NG + mt)*MSZ + (y>>3))*MSZ + (x>>3)];
      const int iy = y >> 1, ix = x >> 1;
      int yA,yB,xA,xB; float wyA,wyB,wxA,wxB;
      if (y & 1){ yA=iy; wyA=0.75f; yB=(iy+1<HP)?iy+1:HP-1; wyB=0.25f; }
      else      { yA=(iy>0)?iy-1:0; wyA=0.25f; yB=iy; wyB=0.75f; }
      if (x & 1){ xA=ix; wxA=0.75f; xB=(ix+1<WP)?ix+1:WP-1; wxB=0.25f; }
      else      { xA=(ix>0)?ix-1:0; wxA=0.25f; xB=ix; wxB=0.75f; }
      const size_t ob = ((size_t)bz*NOUT + n)*MTOT;
      #pragma unroll
      for (int mf=0; mf<4; mf++){
        const int m0 = mb0 + mf*16 + (l>>4)*4;
        ushort4 hq, lq;
        #pragma unroll
        for (int r=0;r<4;r++){
          const int m = m0 + r;
          const float* xb = xbase + ((size_t)bz*MTOT + m)*HWP;
          float up = wyA*(wxA*xb[yA*WP+xA] + wxB*xb[yA*WP+xB])
                   + wyB*(wxA*xb[yB*WP+xA] + wxB*xb[yB*WP+xB]);
          float v = fmaxf(acc[mf][nf][r] + up + mvv*bias1[m] + bias2[m], 0.f);
          ushortT h0, l0; split2(v, h0, l0);
          if      (r==0){hq.x=h0;lq.x=l0;}
          else if (r==1){hq.y=h0;lq.y=l0;}
          else if (r==2){hq.z=h0;lq.z=l0;}
          else          {hq.w=h0;lq.w=l0;}
        }
        *(ushort4*)(oh + ob + m0) = hq;
        *(ushort4*)(ol + ob + m0) = lq;
      }
    } else { // EPI == 3: out = relu(acc + bias1 + pooledF)   (pooledF via xbase arg, f32 NHWC [bz][n][MTOT])
      const float* pfrow = xbase + ((size_t)bz*NOUT + n)*MTOT;
      #pragma unroll
      for (int mf=0; mf<4; mf++){
        const int m0 = mb0 + mf*16 + (l>>4)*4;
        const float4 pv = *(const float4*)(pfrow + m0);
        of32[((size_t)bz*MTOT + m0+0)*NOUT + n] = fmaxf(acc[mf][nf][0] + bias1[m0+0] + pv.x, 0.f);
        of32[((size_t)bz*MTOT + m0+1)*NOUT + n] = fmaxf(acc[mf][nf][1] + bias1[m0+1] + pv.y, 0.f);
        of32[((size_t)bz*MTOT + m0+2)*NOUT + n] = fmaxf(acc[mf][nf][2] + bias1[m0+2] + pv.z, 0.f);
        of32[((size_t)bz*MTOT + m0+3)*NOUT + n] = fmaxf(acc[mf][nf][3] + bias1[m0+3] + pv.w, 0.f);
      }
    }
  }
}

// ============ gmap v2: grouped 3x3 conv, high-parallelism VALU ============
// grid (49 pos-tiles, 32 b); 256 threads = 16 positions (pl) x 16 channel-slices (cs).
// Two passes of 256 channels; thread handles 16 ch/pass, accumulates 4 ocs of the
// slice's group (amortizes each xbase read over 4 outputs). gamma folded at stage.
#define GM_LDSW 9216   // 256 ch * 9 taps * 4 ocl  (f32)
__global__ __launch_bounds__(256) void k_gmap2(const float* __restrict__ xbase,
    const float* __restrict__ mw, const float* __restrict__ mg, const float* __restrict__ mb,
    float* __restrict__ gmap){
  __shared__ float wsh[GM_LDSW];        // [c_rel 256][tap 9][ocl 4]
  __shared__ float red[16][2][4][16];   // [cs][pass][ocl][pl]
  const int tile = blockIdx.x, b = blockIdx.y;
  const int tid = threadIdx.x;
  const int pl = tid & 15, cs = tid >> 4;
  const int p = tile*16 + pl;
  const int oy = p / WP, ox = p - oy*WP;
  int toff[9];
  #pragma unroll
  for (int tap=0; tap<9; tap++){
    int dy = tap/3, dx = tap - 3*dy;
    int yy = oy + dy - 1, xx = ox + dx - 1;
    toff[tap] = ((unsigned)yy < (unsigned)HP && (unsigned)xx < (unsigned)WP) ? (yy*WP + xx) : -1;
  }
  float acc[2][4] = {{0.f,0.f,0.f,0.f},{0.f,0.f,0.f,0.f}};
  for (int pass=0; pass<2; pass++){
    __syncthreads();
    for (int i = tid; i < GM_LDSW; i += 256){
      int ocl = i & 3, tap = (i >> 2) % 9, c_rel = i / 36;
      int cg = pass*256 + c_rel;
      int g = cg >> 7;
      int oc = g*4 + ocl;
      wsh[i] = mw[((size_t)(oc*128 + (cg & 127)))*9 + tap] * mg[oc];
    }
    __syncthreads();
    const float* xb = xbase + ((size_t)b*CO + pass*256 + cs*16)*HWP;
    for (int cl=0; cl<16; cl++){
      const float* xc = xb + (size_t)cl*HWP;
      const float* wr = &wsh[(cs*16 + cl)*36];
      #pragma unroll
      for (int tap=0; tap<9; tap++){
        if (toff[tap] < 0) continue;
        float v = xc[toff[tap]];
        f32x4 w4 = *(const f32x4*)(wr + tap*4);
        acc[pass][0] += v*w4[0];
        acc[pass][1] += v*w4[1];
        acc[pass][2] += v*w4[2];
        acc[pass][3] += v*w4[3];
      }
    }
  }
  #pragma unroll
  for (int pp=0; pp<2; pp++)
    #pragma unroll
    for (int o=0; o<4; o++)
      red[cs][pp][o][pl] = acc[pp][o];
  __syncthreads();
  const int oc = tid >> 4;               // reduce thread = (oc, pl)
  const int g = oc >> 2, ocl = oc & 3, pg = g >> 1, cs0 = (g & 1)*8;
  float s = 0.f;
  #pragma unroll
  for (int t=0; t<8; t++) s += red[cs0 + t][pg][ocl][pl];
  s = fmaxf(s + mb[oc], 0.f);
  gmap[((size_t)b*16 + oc)*HWP + p] = s;
}

__global__ __launch_bounds__(256) void k_gpool(const float* __restrict__ gmap, float* __restrict__ gpool){
  int idx = blockIdx.x*256 + threadIdx.x;
  if (idx >= BB*16*49) return;
  int q = idx % 49; int t = idx / 49; int ch = t % 16; int b = t / 16;
  int my = q/7, mx = q%7;
  const float* src = gmap + ((size_t)b*16 + ch)*HWP;
  float s = 0.f;
  #pragma unroll
  for (int yb=0;yb<4;yb++)
    #pragma unroll
    for (int xb=0;xb<4;xb++)
      s += src[(my*4+yb)*WP + (mx*4+xb)];
  gpool[idx] = s * (1.f/16.f);
}

__global__ __launch_bounds__(256) void k_mask(const float* __restrict__ gpool, const float* __restrict__ fcw,
    const float* __restrict__ fcb, const float* __restrict__ gum,
    float* __restrict__ maskf, float* __restrict__ mout){
  int idx = blockIdx.x*256 + threadIdx.x;
  if (idx >= BB*NG*49) return;
  int q = idx % 49; int t = idx / 49; int g = t % NG; int b = t / NG;
  float lgt[2];
  #pragma unroll
  for (int cls=0; cls<2; cls++){
    int c = cls*NG + g;
    int gc = c >> 1;
    float s = fcb[c];
    #pragma unroll
    for (int k=0;k<4;k++)
      s += fcw[c*4+k] * gpool[((size_t)b*16 + gc*4 + k)*49 + q];
    s += gum[(((size_t)b*2 + cls)*NG + g)*49 + q];
    lgt[cls] = s;
  }
  float m = (lgt[1] > lgt[0]) ? 1.f : 0.f;
  maskf[idx] = m;
  mout[idx] = m;
}

extern "C" void kernel_launch(void* const* d_in, const int* in_sizes, int n_in,
                              void* d_out, int out_size, void* d_ws, size_t ws_size,
                              hipStream_t stream){
  const float* x    = (const float*)d_in[0];
  const float* gum  = (const float*)d_in[1];
  const float* b_w1 = (const float*)d_in[2];
  const float* b_g1 = (const float*)d_in[3];
  const float* b_b1 = (const float*)d_in[4];
  const float* b_w2 = (const float*)d_in[5];
  const float* b_g2 = (const float*)d_in[6];
  const float* b_b2 = (const float*)d_in[7];
  const float* b_w3 = (const float*)d_in[8];
  const float* b_g3 = (const float*)d_in[9];
  const float* b_b3 = (const float*)d_in[10];
  const float* b_dw = (const float*)d_in[11];
  const float* b_dg = (const float*)d_in[12];
  const float* b_db = (const float*)d_in[13];
  const float* r_w1 = (const float*)d_in[14];
  const float* r_g1 = (const float*)d_in[15];
  const float* r_b1 = (const float*)d_in[16];
  const float* r_w2 = (const float*)d_in[17];
  const float* r_g2 = (const float*)d_in[18];
  const float* r_b2 = (const float*)d_in[19];
  const float* r_w3 = (const float*)d_in[20];
  const float* r_g3 = (const float*)d_in[21];
  const float* r_b3 = (const float*)d_in[22];
  const float* r_dw = (const float*)d_in[23];
  const float* r_dg = (const float*)d_in[24];
  const float* r_db = (const float*)d_in[25];
  const float* m_w  = (const float*)d_in[26];
  const float* m_g  = (const float*)d_in[27];
  const float* m_b  = (const float*)d_in[28];
  const float* m_fcw= (const float*)d_in[29];
  const float* m_fcb= (const float*)d_in[30];
  const float* f_w1 = (const float*)d_in[31];
  const float* f_g1 = (const float*)d_in[32];
  const float* f_b1 = (const float*)d_in[33];
  const float* f_w2 = (const float*)d_in[34];
  const float* f_g2 = (const float*)d_in[35];
  const float* f_b2 = (const float*)d_in[36];
  const float* f_w3 = (const float*)d_in[37];
  const float* f_g3 = (const float*)d_in[38];
  const float* f_b3 = (const float*)d_in[39];

  char* ws = (char*)d_ws;
  // ws layout v2 — total 378,366,464 B
  constexpr size_t O_WPH  = 0;            //  2,064,384
  constexpr size_t O_WPL  = 2064384;      //  2,064,384  -> 4,128,768
  constexpr size_t O_CH   = 4128768;      // 25,690,112  t1/r1/f1 hi
  constexpr size_t O_CL   = 29818880;     // 25,690,112  -> 55,508,992
  constexpr size_t O_DH   = 55508992;     //  6,422,528  t2/f2 hi
  constexpr size_t O_DL   = 61931520;     //  6,422,528  -> 68,354,048
  constexpr size_t O_EH   = 68354048;     // 25,690,112  r2 hi
  constexpr size_t O_EL   = 94044160;     // 25,690,112  -> 119,734,272
  constexpr size_t O_PF   = O_EH;         // 51,380,224  pooledF f32 NHWC (r2 dead after fuse)
  constexpr size_t O_XB   = 119734272;    // 51,380,224  xbase f32 NCHW (first 25.7MB doubles as pooled-NCHW tmp)
  constexpr size_t O_GMAP = 171114496;    //  1,605,632
  constexpr size_t O_GPOOL= 172720128;    //    100,352
  constexpr size_t O_MASK = 172820480;    //     25,088  -> 172,845,568
  constexpr size_t O_FH   = 172845568;    // 102,760,448 fused hi (overlaps PH/PL, dead by then)
  constexpr size_t O_PH   = 172845568;    // 12,845,056  pooled hi (dead after xbase GEMM)
  constexpr size_t O_PL   = 185690624;    // 12,845,056  -> 198,535,680 (inside FH region)
  constexpr size_t O_FL   = 275606016;    // 102,760,448 -> 378,366,464

  ushortT* WPH = (ushortT*)(ws + O_WPH);
  ushortT* WPL = (ushortT*)(ws + O_WPL);
  ushortT* CHp = (ushortT*)(ws + O_CH);
  ushortT* CLp = (ushortT*)(ws + O_CL);
  ushortT* DHp = (ushortT*)(ws + O_DH);
  ushortT* DLp = (ushortT*)(ws + O_DL);
  ushortT* EHp = (ushortT*)(ws + O_EH);
  ushortT* ELp = (ushortT*)(ws + O_EL);
  float*   PF  = (float*)(ws + O_PF);
  float*   XB  = (float*)(ws + O_XB);
  float*   PTMP= (float*)(ws + O_XB);     // pooled NCHW tmp, dead before XB written
  ushortT* PHp = (ushortT*)(ws + O_PH);
  ushortT* PLp = (ushortT*)(ws + O_PL);
  ushortT* FHp = (ushortT*)(ws + O_FH);
  ushortT* FLp = (ushortT*)(ws + O_FL);
  float*   GMAP = (float*)(ws + O_GMAP);
  float*   GPOOL= (float*)(ws + O_GPOOL);
  float*   MASKF= (float*)(ws + O_MASK);
  (void)ws_size;

  float* outp = (float*)d_out;
  float* mout = outp + (size_t)BB*CO*HWP;

  dim3 blk(256);
  const ushortT* nu = nullptr; const float* nf_ = nullptr;
  ushortT* nuo = nullptr; float* nfo = nullptr;

  // prep
  prep_w<<<dim3(768, 9), blk, 0, stream>>>(b_w1,b_g1,b_w2,b_g2,b_w3,b_g3,b_dw,b_dg,
      r_w1,r_g1,r_w2,r_g2,r_w3,r_g3,r_dw,r_dg,f_w1,f_g1,f_w2,f_g2,f_w3,f_g3, WPH, WPL);
  k_avgpool_x<<<dim3((BB*CINX*HWP+255)/256), blk, 0, stream>>>(x, PTMP);
  prep_p<<<dim3(49, 16, BB), blk, 0, stream>>>(PTMP, PHp, PLp);

  // base branch
  gemm_bf3<0,0,1,0,1,0,56,56,56,3136,256,0,128,256><<<dim3(25,1,BB), blk, 0, stream>>>(
      WPH+0, WPL+0, nu, nu, nu, nu, x, b_b1, nf_, nf_, nf_, CHp, CLp, nfo);
  gemm_bf3<1,0,0,0,2,1,56,56,28,784,128,0,128,1152><<<dim3(7,1,BB), blk, 0, stream>>>(
      WPH+32768, WPL+32768, CHp, CLp, nu, nu, nf_, b_b2, nf_, nf_, nf_, DHp, DLp, nfo);
  gemm_bf3<2,1,0,0,1,0,28,28,28,784,128,256,512,384><<<dim3(7,4,BB), blk, 0, stream>>>(
      WPH+180224, WPL+180224, DHp, DLp, PHp, PLp, nf_, b_b3, b_db, nf_, nf_, nuo, nuo, XB);

  // mask path
  k_gmap2<<<dim3(49, BB), blk, 0, stream>>>(XB, m_w, m_g, m_b, GMAP);
  k_gpool<<<dim3(98), blk, 0, stream>>>(GMAP, GPOOL);
  k_mask<<<dim3(25), blk, 0, stream>>>(GPOOL, m_fcw, m_fcb, gum, MASKF, mout);

  // refine branch
  gemm_bf3<0,0,1,0,1,0,56,56,56,3136,256,0,128,256><<<dim3(25,1,BB), blk, 0, stream>>>(
      WPH+376832, WPL+376832, nu, nu, nu, nu, x, r_b1, nf_, nf_, nf_, CHp, CLp, nfo);
  gemm_bf3<1,0,0,0,1,1,56,56,56,3136,128,0,128,1152><<<dim3(25,1,BB), blk, 0, stream>>>(
      WPH+409600, WPL+409600, CHp, CLp, nu, nu, nf_, r_b2, nf_, nf_, nf_, EHp, ELp, nfo);
  // fused = relu(up(xbase) + mask*(conv(r2)+b3) + conv(x)+db)
  gemm_bf3<3,2,0,1,1,0,56,56,56,3136,128,256,512,384><<<dim3(25,4,BB), blk, 0, stream>>>(
      WPH+557056, WPL+557056, EHp, ELp, nu, nu, x, r_b3, r_db, MASKF, XB, FHp, FLp, nfo);

  // pooledF = avgpool3s2(fused)  (r2 region now dead -> PF)
  k_poolf<<<dim3(HWP, BB), blk, 0, stream>>>(FHp, FLp, PF);

  // fuse branch
  gemm_bf3<0,0,0,0,1,0,56,56,56,3136,512,0,128,512><<<dim3(25,1,BB), blk, 0, stream>>>(
      WPH+753664, WPL+753664, FHp, FLp, nu, nu, nf_, f_b1, nf_, nf_, nf_, CHp, CLp, nfo);
  gemm_bf3<1,0,0,0,2,1,56,56,28,784,128,0,128,1152><<<dim3(7,1,BB), blk, 0, stream>>>(
      WPH+819200, WPL+819200, CHp, CLp, nu, nu, nf_, f_b2, nf_, nf_, nf_, DHp, DLp, nfo);
  // out = relu(conv(f2)+b3 + pooledF)
  gemm_bf3<0,3,0,0,1,0,28,28,28,784,128,0,512,128><<<dim3(7,4,BB), blk, 0, stream>>>(
      WPH+966656, WPL+966656, DHp, DLp, nu, nu, nf_, f_b3, nf_, nf_, PF, nuo, nuo, outp);
}

// Round 7
// 1104.478 us; speedup vs baseline: 6.9340x; 1.0134x over previous
//
#include <hip/hip_runtime.h>
#include <cstdint>

// dims
#define BB   32
#define CINX 256
#define HH   56
#define WW   56
#define HWX  3136
#define CO   512
#define PL   128
#define HP   28
#define WP   28
#define HWP  784
#define NG   4
#define MSZ  7

typedef unsigned short ushortT;
typedef unsigned int   uint32;
typedef __attribute__((ext_vector_type(8))) short short8;
typedef __attribute__((ext_vector_type(4))) float f32x4;

__device__ __forceinline__ ushortT f2bf(float f){
  uint32 u = __float_as_uint(f);
  u = (u + 0x7fffu + ((u >> 16) & 1u)) >> 16;   // RNE
  return (ushortT)u;
}
__device__ __forceinline__ float bf2f(ushortT u){
  return __uint_as_float(((uint32)u) << 16);
}
__device__ __forceinline__ void split2(float v, ushortT& h, ushortT& lo){
  h = f2bf(v);
  lo = f2bf(v - bf2f(h));
}
__device__ __forceinline__ uint32 packu(ushortT a, ushortT b){
  return (uint32)a | ((uint32)b << 16);
}

// async global->LDS, 16B per lane; dest = wave-uniform base + lane*16
typedef __attribute__((address_space(1))) const void g_void;
typedef __attribute__((address_space(3))) void l_void;
__device__ __forceinline__ void glds16(const ushortT* g, ushortT* l){
  __builtin_amdgcn_global_load_lds((g_void*)g, (l_void*)l, 16, 0, 0);
}

// ============ weight prep: new layout ============
// 0:       merged b1r1 [256][256]   (rows 0-127 b1, 128-255 r1)
// 65536:   b2   [128][1152]
// 212992:  xbase dual [512][384]
// 409600:  r2   [128][1152]
// 557056:  fuse dual [512][384]
// 753664:  f1   [128][512]
// 819200:  f2   [128][1152]
// 966656:  final [512][128]         -> 1032192 total
__device__ __forceinline__ void wsplit(float v, ushortT* dh, ushortT* dl, size_t i){
  ushortT h, lo; split2(v, h, lo); dh[i] = h; dl[i] = lo;
}

__global__ __launch_bounds__(256) void prep_w(
  const float* __restrict__ b_w1, const float* __restrict__ b_g1,
  const float* __restrict__ b_w2, const float* __restrict__ b_g2,
  const float* __restrict__ b_w3, const float* __restrict__ b_g3,
  const float* __restrict__ b_dw, const float* __restrict__ b_dg,
  const float* __restrict__ r_w1, const float* __restrict__ r_g1,
  const float* __restrict__ r_w2, const float* __restrict__ r_g2,
  const float* __restrict__ r_w3, const float* __restrict__ r_g3,
  const float* __restrict__ r_dw, const float* __restrict__ r_dg,
  const float* __restrict__ f_w1, const float* __restrict__ f_g1,
  const float* __restrict__ f_w2, const float* __restrict__ f_g2,
  const float* __restrict__ f_w3, const float* __restrict__ f_g3,
  const float* __restrict__ b_b1, const float* __restrict__ r_b1,
  ushortT* __restrict__ dh, ushortT* __restrict__ dl,
  ushortT* __restrict__ zp, float* __restrict__ biasC)
{
  const int idx = blockIdx.x*256 + threadIdx.x;
  switch (blockIdx.y){
    case 0: { // b1 rows 0-127 of merged
      if (idx >= 32768) return; int m = idx >> 8;
      wsplit(b_w1[idx]*b_g1[m], dh, dl, (size_t)0 + idx); } break;
    case 3: { // r1 rows 128-255 of merged
      if (idx >= 32768) return; int m = idx >> 8;
      wsplit(r_w1[idx]*r_g1[m], dh, dl, 32768 + (size_t)idx); } break;
    case 1: { // b2 [128][1152] k = tap*128+c
      if (idx >= 147456) return; int m = idx / 1152; int k = idx - m*1152;
      int tap = k >> 7, c = k & 127;
      wsplit(b_w2[((size_t)(m*128 + c))*9 + tap]*b_g2[m], dh, dl, 65536 + (size_t)idx); } break;
    case 2: { // xbase dual [512][384]
      if (idx >= 196608) return; int m = idx / 384; int k = idx - m*384;
      float v = (k < 128) ? b_w3[m*128 + k]*b_g3[m] : b_dw[m*256 + (k-128)]*b_dg[m];
      wsplit(v, dh, dl, 212992 + (size_t)idx); } break;
    case 4: { // r2 [128][1152]
      if (idx >= 147456) return; int m = idx / 1152; int k = idx - m*1152;
      int tap = k >> 7, c = k & 127;
      wsplit(r_w2[((size_t)(m*128 + c))*9 + tap]*r_g2[m], dh, dl, 409600 + (size_t)idx); } break;
    case 5: { // fuse dual [512][384]
      if (idx >= 196608) return; int m = idx / 384; int k = idx - m*384;
      float v = (k < 128) ? r_w3[m*128 + k]*r_g3[m] : r_dw[m*256 + (k-128)]*r_dg[m];
      wsplit(v, dh, dl, 557056 + (size_t)idx); } break;
    case 6: { // f1 [128][512]
      if (idx >= 65536) return; int m = idx >> 9;
      wsplit(f_w1[idx]*f_g1[m], dh, dl, 753664 + (size_t)idx); } break;
    case 7: { // f2 [128][1152]
      if (idx >= 147456) return; int m = idx / 1152; int k = idx - m*1152;
      int tap = k >> 7, c = k & 127;
      wsplit(f_w2[((size_t)(m*128 + c))*9 + tap]*f_g2[m], dh, dl, 819200 + (size_t)idx); } break;
    case 8: { // final [512][128]
      if (idx >= 65536) return; int m = idx >> 7;
      wsplit(f_w3[idx]*f_g3[m], dh, dl, 966656 + (size_t)idx); } break;
    case 9: { // zero page + concat bias
      if (idx < 64) zp[idx] = 0;
      if (idx < 128) biasC[idx] = b_b1[idx];
      else if (idx < 256) biasC[idx] = r_b1[idx-128];
    } break;
  }
}

// ============ avgpool 3x3 s2 p1 on x, f32 NCHW -> f32 NCHW temp ============
__global__ __launch_bounds__(256) void k_avgpool_x(const float* __restrict__ x, float* __restrict__ out){
  int idx = blockIdx.x*256 + threadIdx.x;
  if (idx >= BB*CINX*HWP) return;
  int p = idx % HWP; int bc = idx / HWP;
  int ox = p % WP, oy = p / WP;
  const float* src = x + (size_t)bc*HWX;
  float s = 0.f;
  #pragma unroll
  for (int dy=0; dy<3; dy++){
    int yy = 2*oy-1+dy;
    if ((unsigned)yy >= HH) continue;
    #pragma unroll
    for (int dx=0; dx<3; dx++){
      int xx = 2*ox-1+dx;
      if ((unsigned)xx >= WW) continue;
      s += src[yy*WW + xx];
    }
  }
  out[idx] = s * (1.f/9.f);
}

// ============ pooled f32 NCHW -> NHWC hi/lo (16x16 LDS transpose) ============
__global__ __launch_bounds__(256) void prep_p(const float* __restrict__ t,
    ushortT* __restrict__ ph_, ushortT* __restrict__ pl_){
  __shared__ float s[16][17];
  const int p0 = blockIdx.x*16, c0 = blockIdx.y*16, bz = blockIdx.z;
  const int ci = threadIdx.x >> 4, pi = threadIdx.x & 15;
  s[ci][pi] = t[((size_t)bz*CINX + c0 + ci)*HWP + p0 + pi];
  __syncthreads();
  const int pr = threadIdx.x >> 4, cj = threadIdx.x & 15;
  float v = s[cj][pr];
  ushortT h, lo; split2(v, h, lo);
  size_t o = ((size_t)bz*HWP + p0 + pr)*CINX + c0 + cj;
  ph_[o] = h; pl_[o] = lo;
}

// ============ avgpool 3x3 s2 p1 on fused (NHWC hi/lo) -> f32 NHWC [bz][p][512] ============
__global__ __launch_bounds__(256) void k_poolf(const ushortT* __restrict__ fzh,
    const ushortT* __restrict__ fzl, float* __restrict__ pf){
  const int p = blockIdx.x, bz = blockIdx.y;
  const int oy = p / WP, ox = p - oy*WP;
  const int c = threadIdx.x*2;
  float s0 = 0.f, s1 = 0.f;
  #pragma unroll
  for (int dy=0; dy<3; dy++){
    const int iy = 2*oy - 1 + dy;
    if ((unsigned)iy >= (unsigned)HH) continue;
    #pragma unroll
    for (int dx=0; dx<3; dx++){
      const int ix = 2*ox - 1 + dx;
      if ((unsigned)ix >= (unsigned)WW) continue;
      const size_t fi = ((size_t)bz*HWX + (size_t)(iy*WW + ix))*CO + c;
      uint32 hh = *(const uint32*)(fzh + fi);
      uint32 ll = *(const uint32*)(fzl + fi);
      s0 += bf2f((ushortT)(hh & 0xffff)) + bf2f((ushortT)(ll & 0xffff));
      s1 += bf2f((ushortT)(hh >> 16))    + bf2f((ushortT)(ll >> 16));
    }
  }
  const size_t o = ((size_t)bz*HWP + p)*CO + c;
  pf[o]   = s0 * (1.f/9.f);
  pf[o+1] = s1 * (1.f/9.f);
}

// ============ unified bf16x3-split MFMA implicit-GEMM (v3: glds staging, MT param) ============
// KIND: 0=1x1, 1=3x3, 2=dual K-concat, 3=dual K-concat w/ mask on src1 (MT must be 128)
// S1F/S2F: 1 = f32 NCHW gather (x) split on the fly (VGPR path); 0 = pre-split planes via glds
// EPI: 0=bias+relu->hi/lo NHWC, 1=bias1+bias2->f32 NCHW, 2=fuse, 3=final(+pooledF)
// BSTR1 = channel stride of src1 planes
template<int KIND,int EPI,int S1F,int S2F,int MT,int STRIDE,int PAD,int HIN,int WIN,
         int WOUT,int NOUT,int C1,int C2,int BSTR1,int MTOT,int KTOT>
__global__ __launch_bounds__(MT*2)
void gemm_bf3(const ushortT* __restrict__ wph, const ushortT* __restrict__ wpl,
              const ushortT* __restrict__ s1h, const ushortT* __restrict__ s1l,
              const ushortT* __restrict__ s2h, const ushortT* __restrict__ s2l,
              const float* __restrict__ xf32,
              const float* __restrict__ bias1, const float* __restrict__ bias2,
              const float* __restrict__ maskf, const float* __restrict__ xbase,
              const ushortT* __restrict__ zp,
              ushortT* __restrict__ oh, ushortT* __restrict__ ol,
              float* __restrict__ of32)
{
  constexpr int NW = MT/32;        // waves: 4 (MT=128) or 8 (MT=256)
  constexpr int BCALLS = 8/NW;     // B glds calls/wave: 2 or 1
  constexpr bool GATHER1 = (KIND==0 && S1F==1);
  constexpr bool GATHER2 = (KIND>=2 && S2F==1);
  __shared__ ushortT smem[MT*64 + 8192];
  ushortT* AH  = smem;
  ushortT* AL  = smem + MT*32;
  ushortT* BHs = smem + MT*64;
  ushortT* BLs = smem + MT*64 + 4096;

  const int tid = threadIdx.x;
  const int nt = blockIdx.x, mt = blockIdx.y, bz = blockIdx.z;
  const int l  = tid & 63, w = tid >> 6;
  const int wm = w >> 1, wn = w & 1;

  // ---- A glds precompute: 2 calls/wave/plane ----
  size_t a_src[2]; int a_dst[2];
  #pragma unroll
  for (int c=0;c<2;c++){
    int s = (w*2 + c)*64 + l;
    int row = s >> 2, slotm = s & 3;
    int logical = slotm ^ ((row >> 1) & 3);
    a_src[c] = (size_t)(mt*MT + row)*KTOT + logical*8;
    a_dst[c] = (w*2 + c)*512;
  }

  // ---- B glds precompute ----
  int b_dst[2]; size_t b_base1[2], b_base2[2]; int b_klane[2];
  int b_oy[2], b_ox[2]; bool b_ok[2]; float b_mv[2];
  #pragma unroll
  for (int c=0;c<BCALLS;c++){
    int s = (w*BCALLS + c)*64 + l;
    int row = s >> 2, slotm = s & 3;
    int logical = slotm ^ ((row >> 1) & 3);
    b_klane[c] = logical*8;
    b_dst[c] = (w*BCALLS + c)*512;
    int ngr = nt*128 + row;
    b_ok[c] = (ngr < NOUT);
    int oyv = ngr / WOUT, oxv = ngr - (ngr / WOUT)*WOUT;
    b_oy[c] = oyv; b_ox[c] = oxv;
    b_base1[c] = ((size_t)bz*NOUT + ngr)*BSTR1 + b_klane[c];
    b_base2[c] = ((size_t)bz*NOUT + ngr)*C2 + b_klane[c];
    b_mv[c] = 1.f;
    if (KIND == 3)
      b_mv[c] = b_ok[c] ? maskf[((size_t)(bz*NG + mt)*MSZ + (oyv>>3))*MSZ + (oxv>>3)] : 0.f;
  }

  // ---- gather-path (VGPR) ids ----
  const int sr = tid >> 1;
  const int hp = tid & 1;
  const int swz = (sr >> 1) & 3;
  const int lws0 = sr*32 + ((2*hp) ^ swz)*8;
  const int lws1 = sr*32 + ((2*hp + 1) ^ swz)*8;
  const int ng = nt*128 + sr;

  f32x4 acc[4][4];
  f32x4 zf = {0.f,0.f,0.f,0.f};
  #pragma unroll
  for (int i=0;i<4;i++)
    #pragma unroll
    for (int j=0;j<4;j++) acc[i][j] = zf;

  const int NK = KTOT / 32;
  for (int ks=0; ks<NK; ks++){
    const int k0 = ks*32;
    // A stage (always glds)
    #pragma unroll
    for (int c=0;c<2;c++){
      glds16(wph + a_src[c] + k0, AH + a_dst[c]);
      glds16(wpl + a_src[c] + k0, AL + a_dst[c]);
    }
    // B stage
    if constexpr (GATHER1){
      if (tid < 256){
        uint4 b0 = make_uint4(0,0,0,0), b1v = b0, b2v = b0, b3v = b0;
        if (ng < NOUT){
          size_t fbase = ((size_t)bz*C1 + k0 + hp*16)*(size_t)NOUT + ng;
          ushortT h[16], lo[16];
          #pragma unroll
          for (int e=0;e<16;e++){ split2(xf32[fbase + (size_t)e*NOUT], h[e], lo[e]); }
          b0  = make_uint4(packu(h[0],h[1]),  packu(h[2],h[3]),  packu(h[4],h[5]),  packu(h[6],h[7]));
          b1v = make_uint4(packu(h[8],h[9]),  packu(h[10],h[11]),packu(h[12],h[13]),packu(h[14],h[15]));
          b2v = make_uint4(packu(lo[0],lo[1]),packu(lo[2],lo[3]),packu(lo[4],lo[5]),packu(lo[6],lo[7]));
          b3v = make_uint4(packu(lo[8],lo[9]),packu(lo[10],lo[11]),packu(lo[12],lo[13]),packu(lo[14],lo[15]));
        }
        *(uint4*)(BHs + lws0) = b0;  *(uint4*)(BHs + lws1) = b1v;
        *(uint4*)(BLs + lws0) = b2v; *(uint4*)(BLs + lws1) = b3v;
      }
    } else if (GATHER2 && k0 >= C1){
      if (tid < 256){
        uint4 b0 = make_uint4(0,0,0,0), b1v = b0, b2v = b0, b3v = b0;
        if (ng < NOUT){
          size_t fbase = ((size_t)bz*C2 + (k0 - C1) + hp*16)*(size_t)NOUT + ng;
          ushortT h[16], lo[16];
          #pragma unroll
          for (int e=0;e<16;e++){ split2(xf32[fbase + (size_t)e*NOUT], h[e], lo[e]); }
          b0  = make_uint4(packu(h[0],h[1]),  packu(h[2],h[3]),  packu(h[4],h[5]),  packu(h[6],h[7]));
          b1v = make_uint4(packu(h[8],h[9]),  packu(h[10],h[11]),packu(h[12],h[13]),packu(h[14],h[15]));
          b2v = make_uint4(packu(lo[0],lo[1]),packu(lo[2],lo[3]),packu(lo[4],lo[5]),packu(lo[6],lo[7]));
          b3v = make_uint4(packu(lo[8],lo[9]),packu(lo[10],lo[11]),packu(lo[12],lo[13]),packu(lo[14],lo[15]));
        }
        *(uint4*)(BHs + lws0) = b0;  *(uint4*)(BHs + lws1) = b1v;
        *(uint4*)(BLs + lws0) = b2v; *(uint4*)(BLs + lws1) = b3v;
      }
    } else {
      #pragma unroll
      for (int c=0;c<BCALLS;c++){
        const ushortT *sh, *sl;
        if constexpr (KIND == 0){
          bool ok = b_ok[c];
          size_t off = b_base1[c] + k0;
          sh = ok ? s1h + off : zp;  sl = ok ? s1l + off : zp;
        } else if constexpr (KIND == 1){
          const int tap = k0 >> 7;             // C1 == 128
          const int cb  = (k0 & 127);
          const int dy = tap/3, dx = tap - 3*(tap/3);
          int iy = b_oy[c]*STRIDE + dy - PAD;
          int ix = b_ox[c]*STRIDE + dx - PAD;
          bool ok = b_ok[c] && (unsigned)iy < (unsigned)HIN && (unsigned)ix < (unsigned)WIN;
          size_t off = ((size_t)bz*(HIN*WIN) + (size_t)(iy*WIN + ix))*BSTR1 + cb + b_klane[c];
          sh = ok ? s1h + off : zp;  sl = ok ? s1l + off : zp;
        } else {
          if (k0 < C1){
            bool ok = b_ok[c] && (KIND != 3 || b_mv[c] != 0.f);
            size_t off = b_base1[c] + k0;
            sh = ok ? s1h + off : zp;  sl = ok ? s1l + off : zp;
          } else {
            bool ok = b_ok[c];
            size_t off = b_base2[c] + (k0 - C1);
            sh = ok ? s2h + off : zp;  sl = ok ? s2l + off : zp;
          }
        }
        glds16(sh, BHs + b_dst[c]);
        glds16(sl, BLs + b_dst[c]);
      }
    }
    __syncthreads();

    short8 bh[4], bl[4];
    #pragma unroll
    for (int nf=0; nf<4; nf++){
      const int rr = wn*64 + nf*16 + (l & 15);
      const int ph = (l >> 4) ^ ((rr >> 1) & 3);
      bh[nf] = *(const short8*)(BHs + rr*32 + ph*8);
      bl[nf] = *(const short8*)(BLs + rr*32 + ph*8);
    }
    #pragma unroll
    for (int mf=0; mf<4; mf++){
      const int rr = wm*64 + mf*16 + (l & 15);
      const int ph = (l >> 4) ^ ((rr >> 1) & 3);
      short8 ah = *(const short8*)(AH + rr*32 + ph*8);
      short8 al = *(const short8*)(AL + rr*32 + ph*8);
      #pragma unroll
      for (int nf=0; nf<4; nf++)
        acc[mf][nf] = __builtin_amdgcn_mfma_f32_16x16x32_bf16(ah, bh[nf], acc[mf][nf], 0,0,0);
      #pragma unroll
      for (int nf=0; nf<4; nf++)
        acc[mf][nf] = __builtin_amdgcn_mfma_f32_16x16x32_bf16(ah, bl[nf], acc[mf][nf], 0,0,0);
      #pragma unroll
      for (int nf=0; nf<4; nf++)
        acc[mf][nf] = __builtin_amdgcn_mfma_f32_16x16x32_bf16(al, bh[nf], acc[mf][nf], 0,0,0);
    }
    __syncthreads();
  }

  // epilogue: C/D frag: col n = l&15, row m = (l>>4)*4 + r
  const int mb0 = mt*MT + wm*64;
  const int nb0 = nt*128 + wn*64;

  #pragma unroll
  for (int nf=0; nf<4; nf++){
    const int n = nb0 + nf*16 + (l & 15);
    if (n >= NOUT) continue;
    if constexpr (EPI == 0){
      const size_t ob = ((size_t)bz*NOUT + n)*MTOT;
      #pragma unroll
      for (int mf=0; mf<4; mf++){
        const int m0 = mb0 + mf*16 + (l>>4)*4;
        ushort4 hq, lq; ushortT h0, l0; float v;
        v = fmaxf(acc[mf][nf][0] + bias1[m0+0], 0.f); split2(v,h0,l0); hq.x=h0; lq.x=l0;
        v = fmaxf(acc[mf][nf][1] + bias1[m0+1], 0.f); split2(v,h0,l0); hq.y=h0; lq.y=l0;
        v = fmaxf(acc[mf][nf][2] + bias1[m0+2], 0.f); split2(v,h0,l0); hq.z=h0; lq.z=l0;
        v = fmaxf(acc[mf][nf][3] + bias1[m0+3], 0.f); split2(v,h0,l0); hq.w=h0; lq.w=l0;
        *(ushort4*)(oh + ob + m0) = hq;
        *(ushort4*)(ol + ob + m0) = lq;
      }
    } else if constexpr (EPI == 1){
      #pragma unroll
      for (int mf=0; mf<4; mf++){
        const int m0 = mb0 + mf*16 + (l>>4)*4;
        #pragma unroll
        for (int r=0;r<4;r++){
          const int m = m0 + r;
          of32[((size_t)bz*MTOT + m)*NOUT + n] = acc[mf][nf][r] + bias1[m] + bias2[m];
        }
      }
    } else if constexpr (EPI == 2){
      const int y = n / WOUT, x = n - (n / WOUT)*WOUT;
      const int grpw = (mt*MT + wm*64) >> 7;
      const float mvv = maskf[((size_t)(bz*NG + grpw)*MSZ + (y>>3))*MSZ + (x>>3)];
      const int iy = y >> 1, ix = x >> 1;
      int yA,yB,xA,xB; float wyA,wyB,wxA,wxB;
      if (y & 1){ yA=iy; wyA=0.75f; yB=(iy+1<HP)?iy+1:HP-1; wyB=0.25f; }
      else      { yA=(iy>0)?iy-1:0; wyA=0.25f; yB=iy; wyB=0.75f; }
      if (x & 1){ xA=ix; wxA=0.75f; xB=(ix+1<WP)?ix+1:WP-1; wxB=0.25f; }
      else      { xA=(ix>0)?ix-1:0; wxA=0.25f; xB=ix; wxB=0.75f; }
      const size_t ob = ((size_t)bz*NOUT + n)*MTOT;
      #pragma unroll
      for (int mf=0; mf<4; mf++){
        const int m0 = mb0 + mf*16 + (l>>4)*4;
        ushort4 hq, lq;
        #pragma unroll
        for (int r=0;r<4;r++){
          const int m = m0 + r;
          const float* xb = xbase + ((size_t)bz*MTOT + m)*HWP;
          float up = wyA*(wxA*xb[yA*WP+xA] + wxB*xb[yA*WP+xB])
                   + wyB*(wxA*xb[yB*WP+xA] + wxB*xb[yB*WP+xB]);
          float v = fmaxf(acc[mf][nf][r] + up + mvv*bias1[m] + bias2[m], 0.f);
          ushortT h0, l0; split2(v, h0, l0);
          if      (r==0){hq.x=h0;lq.x=l0;}
          else if (r==1){hq.y=h0;lq.y=l0;}
          else if (r==2){hq.z=h0;lq.z=l0;}
          else          {hq.w=h0;lq.w=l0;}
        }
        *(ushort4*)(oh + ob + m0) = hq;
        *(ushort4*)(ol + ob + m0) = lq;
      }
    } else { // EPI == 3: out = relu(acc + bias1 + pooledF[bz][n][m])
      const float* pfrow = xbase + ((size_t)bz*NOUT + n)*MTOT;
      #pragma unroll
      for (int mf=0; mf<4; mf++){
        const int m0 = mb0 + mf*16 + (l>>4)*4;
        const float4 pv = *(const float4*)(pfrow + m0);
        of32[((size_t)bz*MTOT + m0+0)*NOUT + n] = fmaxf(acc[mf][nf][0] + bias1[m0+0] + pv.x, 0.f);
        of32[((size_t)bz*MTOT + m0+1)*NOUT + n] = fmaxf(acc[mf][nf][1] + bias1[m0+1] + pv.y, 0.f);
        of32[((size_t)bz*MTOT + m0+2)*NOUT + n] = fmaxf(acc[mf][nf][2] + bias1[m0+2] + pv.z, 0.f);
        of32[((size_t)bz*MTOT + m0+3)*NOUT + n] = fmaxf(acc[mf][nf][3] + bias1[m0+3] + pv.w, 0.f);
      }
    }
  }
}

// ============ gmap v2 (round-6 proven) ============
#define GM_LDSW 9216
__global__ __launch_bounds__(256) void k_gmap2(const float* __restrict__ xbase,
    const float* __restrict__ mw, const float* __restrict__ mg, const float* __restrict__ mb,
    float* __restrict__ gmap){
  __shared__ float wsh[GM_LDSW];
  __shared__ float red[16][2][4][16];
  const int tile = blockIdx.x, b = blockIdx.y;
  const int tid = threadIdx.x;
  const int pl = tid & 15, cs = tid >> 4;
  const int p = tile*16 + pl;
  const int oy = p / WP, ox = p - oy*WP;
  int toff[9];
  #pragma unroll
  for (int tap=0; tap<9; tap++){
    int dy = tap/3, dx = tap - 3*dy;
    int yy = oy + dy - 1, xx = ox + dx - 1;
    toff[tap] = ((unsigned)yy < (unsigned)HP && (unsigned)xx < (unsigned)WP) ? (yy*WP + xx) : -1;
  }
  float acc[2][4] = {{0.f,0.f,0.f,0.f},{0.f,0.f,0.f,0.f}};
  for (int pass=0; pass<2; pass++){
    __syncthreads();
    for (int i = tid; i < GM_LDSW; i += 256){
      int ocl = i & 3, tap = (i >> 2) % 9, c_rel = i / 36;
      int cg = pass*256 + c_rel;
      int g = cg >> 7;
      int oc = g*4 + ocl;
      wsh[i] = mw[((size_t)(oc*128 + (cg & 127)))*9 + tap] * mg[oc];
    }
    __syncthreads();
    const float* xb = xbase + ((size_t)b*CO + pass*256 + cs*16)*HWP;
    for (int cl=0; cl<16; cl++){
      const float* xc = xb + (size_t)cl*HWP;
      const float* wr = &wsh[(cs*16 + cl)*36];
      #pragma unroll
      for (int tap=0; tap<9; tap++){
        if (toff[tap] < 0) continue;
        float v = xc[toff[tap]];
        f32x4 w4 = *(const f32x4*)(wr + tap*4);
        acc[pass][0] += v*w4[0];
        acc[pass][1] += v*w4[1];
        acc[pass][2] += v*w4[2];
        acc[pass][3] += v*w4[3];
      }
    }
  }
  #pragma unroll
  for (int pp=0; pp<2; pp++)
    #pragma unroll
    for (int o=0; o<4; o++)
      red[cs][pp][o][pl] = acc[pp][o];
  __syncthreads();
  const int oc = tid >> 4;
  const int g = oc >> 2, ocl = oc & 3, pg = g >> 1, cs0 = (g & 1)*8;
  float s = 0.f;
  #pragma unroll
  for (int t=0; t<8; t++) s += red[cs0 + t][pg][ocl][pl];
  s = fmaxf(s + mb[oc], 0.f);
  gmap[((size_t)b*16 + oc)*HWP + p] = s;
}

__global__ __launch_bounds__(256) void k_gpool(const float* __restrict__ gmap, float* __restrict__ gpool){
  int idx = blockIdx.x*256 + threadIdx.x;
  if (idx >= BB*16*49) return;
  int q = idx % 49; int t = idx / 49; int ch = t % 16; int b = t / 16;
  int my = q/7, mx = q%7;
  const float* src = gmap + ((size_t)b*16 + ch)*HWP;
  float s = 0.f;
  #pragma unroll
  for (int yb=0;yb<4;yb++)
    #pragma unroll
    for (int xb=0;xb<4;xb++)
      s += src[(my*4+yb)*WP + (mx*4+xb)];
  gpool[idx] = s * (1.f/16.f);
}

__global__ __launch_bounds__(256) void k_mask(const float* __restrict__ gpool, const float* __restrict__ fcw,
    const float* __restrict__ fcb, const float* __restrict__ gum,
    float* __restrict__ maskf, float* __restrict__ mout){
  int idx = blockIdx.x*256 + threadIdx.x;
  if (idx >= BB*NG*49) return;
  int q = idx % 49; int t = idx / 49; int g = t % NG; int b = t / NG;
  float lgt[2];
  #pragma unroll
  for (int cls=0; cls<2; cls++){
    int c = cls*NG + g;
    int gc = c >> 1;
    float s = fcb[c];
    #pragma unroll
    for (int k=0;k<4;k++)
      s += fcw[c*4+k] * gpool[((size_t)b*16 + gc*4 + k)*49 + q];
    s += gum[(((size_t)b*2 + cls)*NG + g)*49 + q];
    lgt[cls] = s;
  }
  float m = (lgt[1] > lgt[0]) ? 1.f : 0.f;
  maskf[idx] = m;
  mout[idx] = m;
}

extern "C" void kernel_launch(void* const* d_in, const int* in_sizes, int n_in,
                              void* d_out, int out_size, void* d_ws, size_t ws_size,
                              hipStream_t stream){
  const float* x    = (const float*)d_in[0];
  const float* gum  = (const float*)d_in[1];
  const float* b_w1 = (const float*)d_in[2];
  const float* b_g1 = (const float*)d_in[3];
  const float* b_b1 = (const float*)d_in[4];
  const float* b_w2 = (const float*)d_in[5];
  const float* b_g2 = (const float*)d_in[6];
  const float* b_b2 = (const float*)d_in[7];
  const float* b_w3 = (const float*)d_in[8];
  const float* b_g3 = (const float*)d_in[9];
  const float* b_b3 = (const float*)d_in[10];
  const float* b_dw = (const float*)d_in[11];
  const float* b_dg = (const float*)d_in[12];
  const float* b_db = (const float*)d_in[13];
  const float* r_w1 = (const float*)d_in[14];
  const float* r_g1 = (const float*)d_in[15];
  const float* r_b1 = (const float*)d_in[16];
  const float* r_w2 = (const float*)d_in[17];
  const float* r_g2 = (const float*)d_in[18];
  const float* r_b2 = (const float*)d_in[19];
  const float* r_w3 = (const float*)d_in[20];
  const float* r_g3 = (const float*)d_in[21];
  const float* r_b3 = (const float*)d_in[22];
  const float* r_dw = (const float*)d_in[23];
  const float* r_dg = (const float*)d_in[24];
  const float* r_db = (const float*)d_in[25];
  const float* m_w  = (const float*)d_in[26];
  const float* m_g  = (const float*)d_in[27];
  const float* m_b  = (const float*)d_in[28];
  const float* m_fcw= (const float*)d_in[29];
  const float* m_fcb= (const float*)d_in[30];
  const float* f_w1 = (const float*)d_in[31];
  const float* f_g1 = (const float*)d_in[32];
  const float* f_b1 = (const float*)d_in[33];
  const float* f_w2 = (const float*)d_in[34];
  const float* f_g2 = (const float*)d_in[35];
  const float* f_b2 = (const float*)d_in[36];
  const float* f_w3 = (const float*)d_in[37];
  const float* f_g3 = (const float*)d_in[38];
  const float* f_b3 = (const float*)d_in[39];

  char* ws = (char*)d_ws;
  // ws layout v3 — total 378,367,616 B
  constexpr size_t O_WPH  = 0;            //  2,064,384
  constexpr size_t O_WPL  = 2064384;      //  2,064,384  -> 4,128,768
  constexpr size_t O_CH   = 4128768;      // 51,380,224  merged t1|r1 hi plane [bz][3136][256]; later f1 hi+lo
  constexpr size_t O_DH   = 55508992;     //  6,422,528  t2/f2 hi
  constexpr size_t O_DL   = 61931520;     //  6,422,528  -> 68,354,048
  constexpr size_t O_EH   = 68354048;     // 25,690,112  r2 hi
  constexpr size_t O_EL   = 94044160;     // 25,690,112  -> 119,734,272
  constexpr size_t O_PF   = O_EH;         // 51,380,224  pooledF f32 NHWC (r2 dead after fuse)
  constexpr size_t O_XB   = 119734272;    // 51,380,224  xbase f32 NCHW (first 25.7MB doubles as pooled tmp)
  constexpr size_t O_GMAP = 171114496;    //  1,605,632
  constexpr size_t O_GPOOL= 172720128;    //    100,352
  constexpr size_t O_MASK = 172820480;    //     25,088
  constexpr size_t O_FH   = 172845568;    // 102,760,448 fused hi (overlaps PH/PL)
  constexpr size_t O_PH   = 172845568;    // 12,845,056  pooled hi (dead after xbase GEMM)
  constexpr size_t O_PL   = 185690624;    // 12,845,056
  constexpr size_t O_FL   = 275606016;    // 102,760,448 -> 378,366,464
  constexpr size_t O_ZP   = 378366464;    //        128  zero page
  constexpr size_t O_BIASC= 378366592;    //      1,024  concat bias -> 378,367,616

  ushortT* WPH = (ushortT*)(ws + O_WPH);
  ushortT* WPL = (ushortT*)(ws + O_WPL);
  ushortT* MGH = (ushortT*)(ws + O_CH);          // merged hi plane, stride 256
  ushortT* F1H = (ushortT*)(ws + O_CH);          // f1 hi (after merged dead)
  ushortT* F1L = (ushortT*)(ws + O_CH + 25690112);
  ushortT* DHp = (ushortT*)(ws + O_DH);
  ushortT* DLp = (ushortT*)(ws + O_DL);
  ushortT* EHp = (ushortT*)(ws + O_EH);
  ushortT* ELp = (ushortT*)(ws + O_EL);
  float*   PF  = (float*)(ws + O_PF);
  float*   XB  = (float*)(ws + O_XB);
  float*   PTMP= (float*)(ws + O_XB);
  ushortT* PHp = (ushortT*)(ws + O_PH);
  ushortT* PLp = (ushortT*)(ws + O_PL);
  ushortT* FHp = (ushortT*)(ws + O_FH);
  ushortT* FLp = (ushortT*)(ws + O_FL);
  float*   GMAP = (float*)(ws + O_GMAP);
  float*   GPOOL= (float*)(ws + O_GPOOL);
  float*   MASKF= (float*)(ws + O_MASK);
  ushortT* ZP  = (ushortT*)(ws + O_ZP);
  float*   BIASC = (float*)(ws + O_BIASC);
  (void)ws_size;

  float* outp = (float*)d_out;
  float* mout = outp + (size_t)BB*CO*HWP;
  ushortT* dout_u = (ushortT*)d_out;             // merged lo plane until final GEMM

  dim3 blk(256), blk2(512);
  const ushortT* nu = nullptr; const float* nf_ = nullptr;
  ushortT* nuo = nullptr; float* nfo = nullptr;

  // prep
  prep_w<<<dim3(768, 10), blk, 0, stream>>>(b_w1,b_g1,b_w2,b_g2,b_w3,b_g3,b_dw,b_dg,
      r_w1,r_g1,r_w2,r_g2,r_w3,r_g3,r_dw,r_dg,f_w1,f_g1,f_w2,f_g2,f_w3,f_g3,
      b_b1, r_b1, WPH, WPL, ZP, BIASC);
  k_avgpool_x<<<dim3((BB*CINX*HWP+255)/256), blk, 0, stream>>>(x, PTMP);
  prep_p<<<dim3(49, 16, BB), blk, 0, stream>>>(PTMP, PHp, PLp);

  // merged b1|r1: one x-gather pass, MT=256
  gemm_bf3<0,0,1,0,256, 1,0,56,56,56,3136, 256,0,256, 256,256><<<dim3(25,1,BB), blk2, 0, stream>>>(
      WPH+0, WPL+0, nu, nu, nu, nu, x, BIASC, nf_, nf_, nf_, ZP, MGH, dout_u, nfo);
  // b2 (reads t1 = merged rows 0-127, stride 256)
  gemm_bf3<1,0,0,0,128, 2,1,56,56,28,784, 128,0,256, 128,1152><<<dim3(7,1,BB), blk, 0, stream>>>(
      WPH+65536, WPL+65536, MGH, dout_u, nu, nu, nf_, b_b2, nf_, nf_, nf_, ZP, DHp, DLp, nfo);
  // xbase dual (MT=256)
  gemm_bf3<2,1,0,0,256, 1,0,28,28,28,784, 128,256,128, 512,384><<<dim3(7,2,BB), blk2, 0, stream>>>(
      WPH+212992, WPL+212992, DHp, DLp, PHp, PLp, nf_, b_b3, b_db, nf_, nf_, ZP, nuo, nuo, XB);

  // mask path
  k_gmap2<<<dim3(49, BB), blk, 0, stream>>>(XB, m_w, m_g, m_b, GMAP);
  k_gpool<<<dim3(98), blk, 0, stream>>>(GMAP, GPOOL);
  k_mask<<<dim3(25), blk, 0, stream>>>(GPOOL, m_fcw, m_fcb, gum, MASKF, mout);

  // r2 (reads r1 = merged rows 128-255)
  gemm_bf3<1,0,0,0,128, 1,1,56,56,56,3136, 128,0,256, 128,1152><<<dim3(25,1,BB), blk, 0, stream>>>(
      WPH+409600, WPL+409600, MGH+128, dout_u+128, nu, nu, nf_, r_b2, nf_, nf_, nf_, ZP, EHp, ELp, nfo);
  // fused = relu(up(xbase) + mask*(conv(r2)+b3) + conv(x)+db)
  gemm_bf3<3,2,0,1,128, 1,0,56,56,56,3136, 128,256,128, 512,384><<<dim3(25,4,BB), blk, 0, stream>>>(
      WPH+557056, WPL+557056, EHp, ELp, nu, nu, x, r_b3, r_db, MASKF, XB, ZP, FHp, FLp, nfo);

  // pooledF = avgpool3s2(fused)
  k_poolf<<<dim3(HWP, BB), blk, 0, stream>>>(FHp, FLp, PF);

  // fuse branch
  gemm_bf3<0,0,0,0,128, 1,0,56,56,56,3136, 512,0,512, 128,512><<<dim3(25,1,BB), blk, 0, stream>>>(
      WPH+753664, WPL+753664, FHp, FLp, nu, nu, nf_, f_b1, nf_, nf_, nf_, ZP, F1H, F1L, nfo);
  gemm_bf3<1,0,0,0,128, 2,1,56,56,28,784, 128,0,128, 128,1152><<<dim3(7,1,BB), blk, 0, stream>>>(
      WPH+819200, WPL+819200, F1H, F1L, nu, nu, nf_, f_b2, nf_, nf_, nf_, ZP, DHp, DLp, nfo);
  // out = relu(conv(f2)+b3 + pooledF)   (MT=256)
  gemm_bf3<0,3,0,0,256, 1,0,28,28,28,784, 128,0,128, 512,128><<<dim3(7,2,BB), blk2, 0, stream>>>(
      WPH+966656, WPL+966656, DHp, DLp, nu, nu, nf_, f_b3, nf_, nf_, PF, ZP, nuo, nuo, outp);
}

// Round 8
// 1074.383 us; speedup vs baseline: 7.1282x; 1.0280x over previous
//
#include <hip/hip_runtime.h>
#include <cstdint>

// dims
#define BB   32
#define CINX 256
#define HH   56
#define WW   56
#define HWX  3136
#define CO   512
#define PL   128
#define HP   28
#define WP   28
#define HWP  784
#define NG   4
#define MSZ  7

typedef unsigned short ushortT;
typedef unsigned int   uint32;
typedef __attribute__((ext_vector_type(8))) short short8;
typedef __attribute__((ext_vector_type(4))) float f32x4;

__device__ __forceinline__ ushortT f2bf(float f){
  uint32 u = __float_as_uint(f);
  u = (u + 0x7fffu + ((u >> 16) & 1u)) >> 16;   // RNE
  return (ushortT)u;
}
__device__ __forceinline__ float bf2f(ushortT u){
  return __uint_as_float(((uint32)u) << 16);
}
__device__ __forceinline__ void split2(float v, ushortT& h, ushortT& lo){
  h = f2bf(v);
  lo = f2bf(v - bf2f(h));
}
__device__ __forceinline__ uint32 packu(ushortT a, ushortT b){
  return (uint32)a | ((uint32)b << 16);
}

// async global->LDS, 16B per lane; dest = wave-uniform base + lane*16
typedef __attribute__((address_space(1))) const void g_void;
typedef __attribute__((address_space(3))) void l_void;
__device__ __forceinline__ void glds16(const ushortT* g, ushortT* l){
  __builtin_amdgcn_global_load_lds((g_void*)g, (l_void*)l, 16, 0, 0);
}

// ============ weight prep (round-7 layout) ============
__device__ __forceinline__ void wsplit(float v, ushortT* dh, ushortT* dl, size_t i){
  ushortT h, lo; split2(v, h, lo); dh[i] = h; dl[i] = lo;
}

__global__ __launch_bounds__(256) void prep_w(
  const float* __restrict__ b_w1, const float* __restrict__ b_g1,
  const float* __restrict__ b_w2, const float* __restrict__ b_g2,
  const float* __restrict__ b_w3, const float* __restrict__ b_g3,
  const float* __restrict__ b_dw, const float* __restrict__ b_dg,
  const float* __restrict__ r_w1, const float* __restrict__ r_g1,
  const float* __restrict__ r_w2, const float* __restrict__ r_g2,
  const float* __restrict__ r_w3, const float* __restrict__ r_g3,
  const float* __restrict__ r_dw, const float* __restrict__ r_dg,
  const float* __restrict__ f_w1, const float* __restrict__ f_g1,
  const float* __restrict__ f_w2, const float* __restrict__ f_g2,
  const float* __restrict__ f_w3, const float* __restrict__ f_g3,
  const float* __restrict__ b_b1, const float* __restrict__ r_b1,
  ushortT* __restrict__ dh, ushortT* __restrict__ dl,
  ushortT* __restrict__ zp, float* __restrict__ biasC)
{
  const int idx = blockIdx.x*256 + threadIdx.x;
  switch (blockIdx.y){
    case 0: { // b1 rows 0-127 of merged
      if (idx >= 32768) return; int m = idx >> 8;
      wsplit(b_w1[idx]*b_g1[m], dh, dl, (size_t)0 + idx); } break;
    case 3: { // r1 rows 128-255 of merged
      if (idx >= 32768) return; int m = idx >> 8;
      wsplit(r_w1[idx]*r_g1[m], dh, dl, 32768 + (size_t)idx); } break;
    case 1: { // b2 [128][1152] k = tap*128+c
      if (idx >= 147456) return; int m = idx / 1152; int k = idx - m*1152;
      int tap = k >> 7, c = k & 127;
      wsplit(b_w2[((size_t)(m*128 + c))*9 + tap]*b_g2[m], dh, dl, 65536 + (size_t)idx); } break;
    case 2: { // xbase dual [512][384]
      if (idx >= 196608) return; int m = idx / 384; int k = idx - m*384;
      float v = (k < 128) ? b_w3[m*128 + k]*b_g3[m] : b_dw[m*256 + (k-128)]*b_dg[m];
      wsplit(v, dh, dl, 212992 + (size_t)idx); } break;
    case 4: { // r2 [128][1152]
      if (idx >= 147456) return; int m = idx / 1152; int k = idx - m*1152;
      int tap = k >> 7, c = k & 127;
      wsplit(r_w2[((size_t)(m*128 + c))*9 + tap]*r_g2[m], dh, dl, 409600 + (size_t)idx); } break;
    case 5: { // fuse dual [512][384]
      if (idx >= 196608) return; int m = idx / 384; int k = idx - m*384;
      float v = (k < 128) ? r_w3[m*128 + k]*r_g3[m] : r_dw[m*256 + (k-128)]*r_dg[m];
      wsplit(v, dh, dl, 557056 + (size_t)idx); } break;
    case 6: { // f1 [128][512]
      if (idx >= 65536) return; int m = idx >> 9;
      wsplit(f_w1[idx]*f_g1[m], dh, dl, 753664 + (size_t)idx); } break;
    case 7: { // f2 [128][1152]
      if (idx >= 147456) return; int m = idx / 1152; int k = idx - m*1152;
      int tap = k >> 7, c = k & 127;
      wsplit(f_w2[((size_t)(m*128 + c))*9 + tap]*f_g2[m], dh, dl, 819200 + (size_t)idx); } break;
    case 8: { // final [512][128]
      if (idx >= 65536) return; int m = idx >> 7;
      wsplit(f_w3[idx]*f_g3[m], dh, dl, 966656 + (size_t)idx); } break;
    case 9: { // zero page + concat bias
      if (idx < 64) zp[idx] = 0;
      if (idx < 128) biasC[idx] = b_b1[idx];
      else if (idx < 256) biasC[idx] = r_b1[idx-128];
    } break;
  }
}

// ============ avgpool 3x3 s2 p1 on x, f32 NCHW -> f32 NCHW temp ============
__global__ __launch_bounds__(256) void k_avgpool_x(const float* __restrict__ x, float* __restrict__ out){
  int idx = blockIdx.x*256 + threadIdx.x;
  if (idx >= BB*CINX*HWP) return;
  int p = idx % HWP; int bc = idx / HWP;
  int ox = p % WP, oy = p / WP;
  const float* src = x + (size_t)bc*HWX;
  float s = 0.f;
  #pragma unroll
  for (int dy=0; dy<3; dy++){
    int yy = 2*oy-1+dy;
    if ((unsigned)yy >= HH) continue;
    #pragma unroll
    for (int dx=0; dx<3; dx++){
      int xx = 2*ox-1+dx;
      if ((unsigned)xx >= WW) continue;
      s += src[yy*WW + xx];
    }
  }
  out[idx] = s * (1.f/9.f);
}

// ============ pooled f32 NCHW -> NHWC hi/lo (16x16 LDS transpose) ============
__global__ __launch_bounds__(256) void prep_p(const float* __restrict__ t,
    ushortT* __restrict__ ph_, ushortT* __restrict__ pl_){
  __shared__ float s[16][17];
  const int p0 = blockIdx.x*16, c0 = blockIdx.y*16, bz = blockIdx.z;
  const int ci = threadIdx.x >> 4, pi = threadIdx.x & 15;
  s[ci][pi] = t[((size_t)bz*CINX + c0 + ci)*HWP + p0 + pi];
  __syncthreads();
  const int pr = threadIdx.x >> 4, cj = threadIdx.x & 15;
  float v = s[cj][pr];
  ushortT h, lo; split2(v, h, lo);
  size_t o = ((size_t)bz*HWP + p0 + pr)*CINX + c0 + cj;
  ph_[o] = h; pl_[o] = lo;
}

// ============ x f32 NCHW -> NHWC hi/lo (16x16 LDS transpose) ============
__global__ __launch_bounds__(256) void prep_x2(const float* __restrict__ x,
    ushortT* __restrict__ xh, ushortT* __restrict__ xl){
  __shared__ float s[16][17];
  const int p0 = blockIdx.x*16, c0 = blockIdx.y*16, bz = blockIdx.z;
  const int ci = threadIdx.x >> 4, pi = threadIdx.x & 15;
  s[ci][pi] = x[((size_t)bz*CINX + c0 + ci)*HWX + p0 + pi];
  __syncthreads();
  const int pr = threadIdx.x >> 4, cj = threadIdx.x & 15;
  float v = s[cj][pr];
  ushortT h, lo; split2(v, h, lo);
  size_t o = ((size_t)bz*HWX + p0 + pr)*CINX + c0 + cj;
  xh[o] = h; xl[o] = lo;
}

// ============ avgpool 3x3 s2 p1 on fused (NHWC hi/lo) -> f32 NHWC [bz][p][512] ============
__global__ __launch_bounds__(256) void k_poolf(const ushortT* __restrict__ fzh,
    const ushortT* __restrict__ fzl, float* __restrict__ pf){
  const int p = blockIdx.x, bz = blockIdx.y;
  const int oy = p / WP, ox = p - oy*WP;
  const int c = threadIdx.x*2;
  float s0 = 0.f, s1 = 0.f;
  #pragma unroll
  for (int dy=0; dy<3; dy++){
    const int iy = 2*oy - 1 + dy;
    if ((unsigned)iy >= (unsigned)HH) continue;
    #pragma unroll
    for (int dx=0; dx<3; dx++){
      const int ix = 2*ox - 1 + dx;
      if ((unsigned)ix >= (unsigned)WW) continue;
      const size_t fi = ((size_t)bz*HWX + (size_t)(iy*WW + ix))*CO + c;
      uint32 hh = *(const uint32*)(fzh + fi);
      uint32 ll = *(const uint32*)(fzl + fi);
      s0 += bf2f((ushortT)(hh & 0xffff)) + bf2f((ushortT)(ll & 0xffff));
      s1 += bf2f((ushortT)(hh >> 16))    + bf2f((ushortT)(ll >> 16));
    }
  }
  const size_t o = ((size_t)bz*HWP + p)*CO + c;
  pf[o]   = s0 * (1.f/9.f);
  pf[o+1] = s1 * (1.f/9.f);
}

// ============ unified bf16x3-split MFMA implicit-GEMM (v4: 2-phase dbuf) ============
// KIND: 0=1x1, 1=3x3, 2=dual K-concat, 3=dual K-concat w/ mask on src1 (MT must be 128)
// S1F: 1 = f32 NCHW gather (x) split on the fly (only with DBUF=0)
// DBUF: 1 = double-buffered LDS, stage(k+1) overlaps compute(k), one barrier/iter
// SWAP: 1 = grid (mt, nt, bz) instead of (nt, mt, bz)
// EPI: 0=bias+relu->hi/lo NHWC, 1=bias1+bias2->f32 NCHW, 2=fuse, 3=final(+pooledF)
template<int KIND,int EPI,int S1F,int MT,int DBUF,int SWAP,int STRIDE,int PAD,
         int HIN,int WIN,int WOUT,int NOUT,int C1,int C2,int BSTR1,int MTOT,int KTOT>
__global__ __launch_bounds__(MT*2)
void gemm_bf3(const ushortT* __restrict__ wph, const ushortT* __restrict__ wpl,
              const ushortT* __restrict__ s1h, const ushortT* __restrict__ s1l,
              const ushortT* __restrict__ s2h, const ushortT* __restrict__ s2l,
              const float* __restrict__ xf32,
              const float* __restrict__ bias1, const float* __restrict__ bias2,
              const float* __restrict__ maskf, const float* __restrict__ xbase,
              const ushortT* __restrict__ zp,
              ushortT* __restrict__ oh, ushortT* __restrict__ ol,
              float* __restrict__ of32)
{
  constexpr int NW = MT/32;        // waves: 4 (MT=128) or 8 (MT=256)
  constexpr int BCALLS = 8/NW;     // B glds calls/wave: 2 or 1
  constexpr bool GATHER1 = (KIND==0 && S1F==1);
  constexpr int BUFSZ = MT*64 + 8192;   // ushorts per buffer
  __shared__ ushortT smem[BUFSZ*(DBUF+1)];

  const int tid = threadIdx.x;
  const int nt = SWAP ? blockIdx.y : blockIdx.x;
  const int mt = SWAP ? blockIdx.x : blockIdx.y;
  const int bz = blockIdx.z;
  const int l  = tid & 63, w = tid >> 6;
  const int wm = w >> 1, wn = w & 1;

  // ---- A glds precompute: 2 calls/wave/plane ----
  size_t a_src[2]; int a_dst[2];
  #pragma unroll
  for (int c=0;c<2;c++){
    int s = (w*2 + c)*64 + l;
    int row = s >> 2, slotm = s & 3;
    int logical = slotm ^ ((row >> 1) & 3);
    a_src[c] = (size_t)(mt*MT + row)*KTOT + logical*8;
    a_dst[c] = (w*2 + c)*512;
  }

  // ---- B glds precompute ----
  int b_dst[2]; size_t b_base1[2], b_base2[2]; int b_klane[2];
  int b_oy[2], b_ox[2]; bool b_ok[2]; float b_mv[2];
  #pragma unroll
  for (int c=0;c<BCALLS;c++){
    int s = (w*BCALLS + c)*64 + l;
    int row = s >> 2, slotm = s & 3;
    int logical = slotm ^ ((row >> 1) & 3);
    b_klane[c] = logical*8;
    b_dst[c] = (w*BCALLS + c)*512;
    int ngr = nt*128 + row;
    b_ok[c] = (ngr < NOUT);
    int oyv = ngr / WOUT, oxv = ngr - (ngr / WOUT)*WOUT;
    b_oy[c] = oyv; b_ox[c] = oxv;
    b_base1[c] = ((size_t)bz*NOUT + ngr)*BSTR1 + b_klane[c];
    b_base2[c] = ((size_t)bz*NOUT + ngr)*C2 + b_klane[c];
    b_mv[c] = 1.f;
    if (KIND == 3)
      b_mv[c] = b_ok[c] ? maskf[((size_t)(bz*NG + mt)*MSZ + (oyv>>3))*MSZ + (oxv>>3)] : 0.f;
  }

  // ---- gather-path (VGPR) ids ----
  const int sr = tid >> 1;
  const int hp = tid & 1;
  const int swz = (sr >> 1) & 3;
  const int lws0 = sr*32 + ((2*hp) ^ swz)*8;
  const int lws1 = sr*32 + ((2*hp + 1) ^ swz)*8;
  const int ng = nt*128 + sr;

  f32x4 acc[4][4];
  f32x4 zf = {0.f,0.f,0.f,0.f};
  #pragma unroll
  for (int i=0;i<4;i++)
    #pragma unroll
    for (int j=0;j<4;j++) acc[i][j] = zf;

  auto stagef = [&](int ks, ushortT* AHb, ushortT* ALb, ushortT* BHb, ushortT* BLb){
    const int k0 = ks*32;
    #pragma unroll
    for (int c=0;c<2;c++){
      glds16(wph + a_src[c] + k0, AHb + a_dst[c]);
      glds16(wpl + a_src[c] + k0, ALb + a_dst[c]);
    }
    if constexpr (GATHER1){
      if (tid < 256){
        uint4 b0 = make_uint4(0,0,0,0), b1v = b0, b2v = b0, b3v = b0;
        if (ng < NOUT){
          size_t fbase = ((size_t)bz*C1 + k0 + hp*16)*(size_t)NOUT + ng;
          ushortT h[16], lo[16];
          #pragma unroll
          for (int e=0;e<16;e++){ split2(xf32[fbase + (size_t)e*NOUT], h[e], lo[e]); }
          b0  = make_uint4(packu(h[0],h[1]),  packu(h[2],h[3]),  packu(h[4],h[5]),  packu(h[6],h[7]));
          b1v = make_uint4(packu(h[8],h[9]),  packu(h[10],h[11]),packu(h[12],h[13]),packu(h[14],h[15]));
          b2v = make_uint4(packu(lo[0],lo[1]),packu(lo[2],lo[3]),packu(lo[4],lo[5]),packu(lo[6],lo[7]));
          b3v = make_uint4(packu(lo[8],lo[9]),packu(lo[10],lo[11]),packu(lo[12],lo[13]),packu(lo[14],lo[15]));
        }
        *(uint4*)(BHb + lws0) = b0;  *(uint4*)(BHb + lws1) = b1v;
        *(uint4*)(BLb + lws0) = b2v; *(uint4*)(BLb + lws1) = b3v;
      }
    } else {
      #pragma unroll
      for (int c=0;c<BCALLS;c++){
        const ushortT *sh, *sl;
        if constexpr (KIND == 0){
          bool ok = b_ok[c];
          size_t off = b_base1[c] + k0;
          sh = ok ? s1h + off : zp;  sl = ok ? s1l + off : zp;
        } else if constexpr (KIND == 1){
          const int tap = k0 >> 7;             // C1 == 128
          const int cb  = (k0 & 127);
          const int dy = tap/3, dx = tap - 3*(tap/3);
          int iy = b_oy[c]*STRIDE + dy - PAD;
          int ix = b_ox[c]*STRIDE + dx - PAD;
          bool ok = b_ok[c] && (unsigned)iy < (unsigned)HIN && (unsigned)ix < (unsigned)WIN;
          size_t off = ((size_t)bz*(HIN*WIN) + (size_t)(iy*WIN + ix))*BSTR1 + cb + b_klane[c];
          sh = ok ? s1h + off : zp;  sl = ok ? s1l + off : zp;
        } else {
          if (k0 < C1){
            bool ok = b_ok[c] && (KIND != 3 || b_mv[c] != 0.f);
            size_t off = b_base1[c] + k0;
            sh = ok ? s1h + off : zp;  sl = ok ? s1l + off : zp;
          } else {
            bool ok = b_ok[c];
            size_t off = b_base2[c] + (k0 - C1);
            sh = ok ? s2h + off : zp;  sl = ok ? s2l + off : zp;
          }
        }
        glds16(sh, BHb + b_dst[c]);
        glds16(sl, BLb + b_dst[c]);
      }
    }
  };

  auto computef = [&](const ushortT* AHb, const ushortT* ALb,
                      const ushortT* BHb, const ushortT* BLb){
    short8 bh[4], bl[4];
    #pragma unroll
    for (int nf=0; nf<4; nf++){
      const int rr = wn*64 + nf*16 + (l & 15);
      const int ph = (l >> 4) ^ ((rr >> 1) & 3);
      bh[nf] = *(const short8*)(BHb + rr*32 + ph*8);
      bl[nf] = *(const short8*)(BLb + rr*32 + ph*8);
    }
    #pragma unroll
    for (int mf=0; mf<4; mf++){
      const int rr = wm*64 + mf*16 + (l & 15);
      const int ph = (l >> 4) ^ ((rr >> 1) & 3);
      short8 ah = *(const short8*)(AHb + rr*32 + ph*8);
      short8 al = *(const short8*)(ALb + rr*32 + ph*8);
      #pragma unroll
      for (int nf=0; nf<4; nf++)
        acc[mf][nf] = __builtin_amdgcn_mfma_f32_16x16x32_bf16(ah, bh[nf], acc[mf][nf], 0,0,0);
      #pragma unroll
      for (int nf=0; nf<4; nf++)
        acc[mf][nf] = __builtin_amdgcn_mfma_f32_16x16x32_bf16(ah, bl[nf], acc[mf][nf], 0,0,0);
      #pragma unroll
      for (int nf=0; nf<4; nf++)
        acc[mf][nf] = __builtin_amdgcn_mfma_f32_16x16x32_bf16(al, bh[nf], acc[mf][nf], 0,0,0);
    }
  };

  const int NK = KTOT / 32;
  if constexpr (DBUF == 0){
    ushortT* AH  = smem;
    ushortT* AL  = smem + MT*32;
    ushortT* BHs = smem + MT*64;
    ushortT* BLs = smem + MT*64 + 4096;
    for (int ks=0; ks<NK; ks++){
      stagef(ks, AH, AL, BHs, BLs);
      __syncthreads();
      computef(AH, AL, BHs, BLs);
      __syncthreads();
    }
  } else {
    // 2-phase: stage(k+1) overlaps compute(k); one barrier per iteration
    stagef(0, smem, smem + MT*32, smem + MT*64, smem + MT*64 + 4096);
    __syncthreads();
    for (int ks=0; ks<NK; ks++){
      ushortT* cb = smem + (ks & 1)*BUFSZ;
      ushortT* nb = smem + ((ks & 1) ^ 1)*BUFSZ;
      if (ks + 1 < NK)
        stagef(ks + 1, nb, nb + MT*32, nb + MT*64, nb + MT*64 + 4096);
      computef(cb, cb + MT*32, cb + MT*64, cb + MT*64 + 4096);
      __syncthreads();
    }
  }

  // epilogue: C/D frag: col n = l&15, row m = (l>>4)*4 + r
  const int mb0 = mt*MT + wm*64;
  const int nb0 = nt*128 + wn*64;

  #pragma unroll
  for (int nf=0; nf<4; nf++){
    const int n = nb0 + nf*16 + (l & 15);
    if (n >= NOUT) continue;
    if constexpr (EPI == 0){
      const size_t ob = ((size_t)bz*NOUT + n)*MTOT;
      #pragma unroll
      for (int mf=0; mf<4; mf++){
        const int m0 = mb0 + mf*16 + (l>>4)*4;
        ushort4 hq, lq; ushortT h0, l0; float v;
        v = fmaxf(acc[mf][nf][0] + bias1[m0+0], 0.f); split2(v,h0,l0); hq.x=h0; lq.x=l0;
        v = fmaxf(acc[mf][nf][1] + bias1[m0+1], 0.f); split2(v,h0,l0); hq.y=h0; lq.y=l0;
        v = fmaxf(acc[mf][nf][2] + bias1[m0+2], 0.f); split2(v,h0,l0); hq.z=h0; lq.z=l0;
        v = fmaxf(acc[mf][nf][3] + bias1[m0+3], 0.f); split2(v,h0,l0); hq.w=h0; lq.w=l0;
        *(ushort4*)(oh + ob + m0) = hq;
        *(ushort4*)(ol + ob + m0) = lq;
      }
    } else if constexpr (EPI == 1){
      #pragma unroll
      for (int mf=0; mf<4; mf++){
        const int m0 = mb0 + mf*16 + (l>>4)*4;
        #pragma unroll
        for (int r=0;r<4;r++){
          const int m = m0 + r;
          of32[((size_t)bz*MTOT + m)*NOUT + n] = acc[mf][nf][r] + bias1[m] + bias2[m];
        }
      }
    } else if constexpr (EPI == 2){
      const int y = n / WOUT, x = n - (n / WOUT)*WOUT;
      const int grpw = (mt*MT + wm*64) >> 7;
      const float mvv = maskf[((size_t)(bz*NG + grpw)*MSZ + (y>>3))*MSZ + (x>>3)];
      const int iy = y >> 1, ix = x >> 1;
      int yA,yB,xA,xB; float wyA,wyB,wxA,wxB;
      if (y & 1){ yA=iy; wyA=0.75f; yB=(iy+1<HP)?iy+1:HP-1; wyB=0.25f; }
      else      { yA=(iy>0)?iy-1:0; wyA=0.25f; yB=iy; wyB=0.75f; }
      if (x & 1){ xA=ix; wxA=0.75f; xB=(ix+1<WP)?ix+1:WP-1; wxB=0.25f; }
      else      { xA=(ix>0)?ix-1:0; wxA=0.25f; xB=ix; wxB=0.75f; }
      const size_t ob = ((size_t)bz*NOUT + n)*MTOT;
      #pragma unroll
      for (int mf=0; mf<4; mf++){
        const int m0 = mb0 + mf*16 + (l>>4)*4;
        ushort4 hq, lq;
        #pragma unroll
        for (int r=0;r<4;r++){
          const int m = m0 + r;
          const float* xb = xbase + ((size_t)bz*MTOT + m)*HWP;
          float up = wyA*(wxA*xb[yA*WP+xA] + wxB*xb[yA*WP+xB])
                   + wyB*(wxA*xb[yB*WP+xA] + wxB*xb[yB*WP+xB]);
          float v = fmaxf(acc[mf][nf][r] + up + mvv*bias1[m] + bias2[m], 0.f);
          ushortT h0, l0; split2(v, h0, l0);
          if      (r==0){hq.x=h0;lq.x=l0;}
          else if (r==1){hq.y=h0;lq.y=l0;}
          else if (r==2){hq.z=h0;lq.z=l0;}
          else          {hq.w=h0;lq.w=l0;}
        }
        *(ushort4*)(oh + ob + m0) = hq;
        *(ushort4*)(ol + ob + m0) = lq;
      }
    } else { // EPI == 3: out = relu(acc + bias1 + pooledF[bz][n][m])
      const float* pfrow = xbase + ((size_t)bz*NOUT + n)*MTOT;
      #pragma unroll
      for (int mf=0; mf<4; mf++){
        const int m0 = mb0 + mf*16 + (l>>4)*4;
        const float4 pv = *(const float4*)(pfrow + m0);
        of32[((size_t)bz*MTOT + m0+0)*NOUT + n] = fmaxf(acc[mf][nf][0] + bias1[m0+0] + pv.x, 0.f);
        of32[((size_t)bz*MTOT + m0+1)*NOUT + n] = fmaxf(acc[mf][nf][1] + bias1[m0+1] + pv.y, 0.f);
        of32[((size_t)bz*MTOT + m0+2)*NOUT + n] = fmaxf(acc[mf][nf][2] + bias1[m0+2] + pv.z, 0.f);
        of32[((size_t)bz*MTOT + m0+3)*NOUT + n] = fmaxf(acc[mf][nf][3] + bias1[m0+3] + pv.w, 0.f);
      }
    }
  }
}

// ============ gmap v2 (round-6 proven) ============
#define GM_LDSW 9216
__global__ __launch_bounds__(256) void k_gmap2(const float* __restrict__ xbase,
    const float* __restrict__ mw, const float* __restrict__ mg, const float* __restrict__ mb,
    float* __restrict__ gmap){
  __shared__ float wsh[GM_LDSW];
  __shared__ float red[16][2][4][16];
  const int tile = blockIdx.x, b = blockIdx.y;
  const int tid = threadIdx.x;
  const int pl = tid & 15, cs = tid >> 4;
  const int p = tile*16 + pl;
  const int oy = p / WP, ox = p - oy*WP;
  int toff[9];
  #pragma unroll
  for (int tap=0; tap<9; tap++){
    int dy = tap/3, dx = tap - 3*dy;
    int yy = oy + dy - 1, xx = ox + dx - 1;
    toff[tap] = ((unsigned)yy < (unsigned)HP && (unsigned)xx < (unsigned)WP) ? (yy*WP + xx) : -1;
  }
  float acc[2][4] = {{0.f,0.f,0.f,0.f},{0.f,0.f,0.f,0.f}};
  for (int pass=0; pass<2; pass++){
    __syncthreads();
    for (int i = tid; i < GM_LDSW; i += 256){
      int ocl = i & 3, tap = (i >> 2) % 9, c_rel = i / 36;
      int cg = pass*256 + c_rel;
      int g = cg >> 7;
      int oc = g*4 + ocl;
      wsh[i] = mw[((size_t)(oc*128 + (cg & 127)))*9 + tap] * mg[oc];
    }
    __syncthreads();
    const float* xb = xbase + ((size_t)b*CO + pass*256 + cs*16)*HWP;
    for (int cl=0; cl<16; cl++){
      const float* xc = xb + (size_t)cl*HWP;
      const float* wr = &wsh[(cs*16 + cl)*36];
      #pragma unroll
      for (int tap=0; tap<9; tap++){
        if (toff[tap] < 0) continue;
        float v = xc[toff[tap]];
        f32x4 w4 = *(const f32x4*)(wr + tap*4);
        acc[pass][0] += v*w4[0];
        acc[pass][1] += v*w4[1];
        acc[pass][2] += v*w4[2];
        acc[pass][3] += v*w4[3];
      }
    }
  }
  #pragma unroll
  for (int pp=0; pp<2; pp++)
    #pragma unroll
    for (int o=0; o<4; o++)
      red[cs][pp][o][pl] = acc[pp][o];
  __syncthreads();
  const int oc = tid >> 4;
  const int g = oc >> 2, ocl = oc & 3, pg = g >> 1, cs0 = (g & 1)*8;
  float s = 0.f;
  #pragma unroll
  for (int t=0; t<8; t++) s += red[cs0 + t][pg][ocl][pl];
  s = fmaxf(s + mb[oc], 0.f);
  gmap[((size_t)b*16 + oc)*HWP + p] = s;
}

__global__ __launch_bounds__(256) void k_gpool(const float* __restrict__ gmap, float* __restrict__ gpool){
  int idx = blockIdx.x*256 + threadIdx.x;
  if (idx >= BB*16*49) return;
  int q = idx % 49; int t = idx / 49; int ch = t % 16; int b = t / 16;
  int my = q/7, mx = q%7;
  const float* src = gmap + ((size_t)b*16 + ch)*HWP;
  float s = 0.f;
  #pragma unroll
  for (int yb=0;yb<4;yb++)
    #pragma unroll
    for (int xb=0;xb<4;xb++)
      s += src[(my*4+yb)*WP + (mx*4+xb)];
  gpool[idx] = s * (1.f/16.f);
}

__global__ __launch_bounds__(256) void k_mask(const float* __restrict__ gpool, const float* __restrict__ fcw,
    const float* __restrict__ fcb, const float* __restrict__ gum,
    float* __restrict__ maskf, float* __restrict__ mout){
  int idx = blockIdx.x*256 + threadIdx.x;
  if (idx >= BB*NG*49) return;
  int q = idx % 49; int t = idx / 49; int g = t % NG; int b = t / NG;
  float lgt[2];
  #pragma unroll
  for (int cls=0; cls<2; cls++){
    int c = cls*NG + g;
    int gc = c >> 1;
    float s = fcb[c];
    #pragma unroll
    for (int k=0;k<4;k++)
      s += fcw[c*4+k] * gpool[((size_t)b*16 + gc*4 + k)*49 + q];
    s += gum[(((size_t)b*2 + cls)*NG + g)*49 + q];
    lgt[cls] = s;
  }
  float m = (lgt[1] > lgt[0]) ? 1.f : 0.f;
  maskf[idx] = m;
  mout[idx] = m;
}

extern "C" void kernel_launch(void* const* d_in, const int* in_sizes, int n_in,
                              void* d_out, int out_size, void* d_ws, size_t ws_size,
                              hipStream_t stream){
  const float* x    = (const float*)d_in[0];
  const float* gum  = (const float*)d_in[1];
  const float* b_w1 = (const float*)d_in[2];
  const float* b_g1 = (const float*)d_in[3];
  const float* b_b1 = (const float*)d_in[4];
  const float* b_w2 = (const float*)d_in[5];
  const float* b_g2 = (const float*)d_in[6];
  const float* b_b2 = (const float*)d_in[7];
  const float* b_w3 = (const float*)d_in[8];
  const float* b_g3 = (const float*)d_in[9];
  const float* b_b3 = (const float*)d_in[10];
  const float* b_dw = (const float*)d_in[11];
  const float* b_dg = (const float*)d_in[12];
  const float* b_db = (const float*)d_in[13];
  const float* r_w1 = (const float*)d_in[14];
  const float* r_g1 = (const float*)d_in[15];
  const float* r_b1 = (const float*)d_in[16];
  const float* r_w2 = (const float*)d_in[17];
  const float* r_g2 = (const float*)d_in[18];
  const float* r_b2 = (const float*)d_in[19];
  const float* r_w3 = (const float*)d_in[20];
  const float* r_g3 = (const float*)d_in[21];
  const float* r_b3 = (const float*)d_in[22];
  const float* r_dw = (const float*)d_in[23];
  const float* r_dg = (const float*)d_in[24];
  const float* r_db = (const float*)d_in[25];
  const float* m_w  = (const float*)d_in[26];
  const float* m_g  = (const float*)d_in[27];
  const float* m_b  = (const float*)d_in[28];
  const float* m_fcw= (const float*)d_in[29];
  const float* m_fcb= (const float*)d_in[30];
  const float* f_w1 = (const float*)d_in[31];
  const float* f_g1 = (const float*)d_in[32];
  const float* f_b1 = (const float*)d_in[33];
  const float* f_w2 = (const float*)d_in[34];
  const float* f_g2 = (const float*)d_in[35];
  const float* f_b2 = (const float*)d_in[36];
  const float* f_w3 = (const float*)d_in[37];
  const float* f_g3 = (const float*)d_in[38];
  const float* f_b3 = (const float*)d_in[39];

  char* ws = (char*)d_ws;
  // ws layout v4 — total 378,367,616 B
  constexpr size_t O_WPH  = 0;            //  2,064,384
  constexpr size_t O_WPL  = 2064384;      //  2,064,384  -> 4,128,768
  constexpr size_t O_CH   = 4128768;      // 51,380,224  merged hi; then XH (x hi NHWC); then f1 hi+lo
  constexpr size_t O_DH   = 55508992;     //  6,422,528  t2/f2 hi
  constexpr size_t O_DL   = 61931520;     //  6,422,528  -> 68,354,048
  constexpr size_t O_EH   = 68354048;     // 25,690,112  r2 hi
  constexpr size_t O_EL   = 94044160;     // 25,690,112  -> 119,734,272
  constexpr size_t O_PF   = O_EH;         // 51,380,224  pooledF f32 NHWC (r2 dead after fuse)
  constexpr size_t O_XB   = 119734272;    // 51,380,224  xbase f32 NCHW (first 25.7MB doubles as pooled tmp)
  constexpr size_t O_GMAP = 171114496;    //  1,605,632
  constexpr size_t O_GPOOL= 172720128;    //    100,352
  constexpr size_t O_MASK = 172820480;    //     25,088
  constexpr size_t O_FH   = 172845568;    // 102,760,448 fused hi (overlaps PH/PL)
  constexpr size_t O_PH   = 172845568;    // 12,845,056  pooled hi (dead after xbase GEMM)
  constexpr size_t O_PL   = 185690624;    // 12,845,056
  constexpr size_t O_FL   = 275606016;    // 102,760,448 -> 378,366,464
  constexpr size_t O_ZP   = 378366464;    //        128  zero page
  constexpr size_t O_BIASC= 378366592;    //      1,024  concat bias -> 378,367,616

  ushortT* WPH = (ushortT*)(ws + O_WPH);
  ushortT* WPL = (ushortT*)(ws + O_WPL);
  ushortT* MGH = (ushortT*)(ws + O_CH);          // merged hi plane, stride 256 (b2/r2 input)
  ushortT* XH  = (ushortT*)(ws + O_CH);          // x hi NHWC (after r2; fuse input)
  ushortT* F1H = (ushortT*)(ws + O_CH);          // f1 hi (after fuse)
  ushortT* F1L = (ushortT*)(ws + O_CH + 25690112);
  ushortT* DHp = (ushortT*)(ws + O_DH);
  ushortT* DLp = (ushortT*)(ws + O_DL);
  ushortT* EHp = (ushortT*)(ws + O_EH);
  ushortT* ELp = (ushortT*)(ws + O_EL);
  float*   PF  = (float*)(ws + O_PF);
  float*   XB  = (float*)(ws + O_XB);
  float*   PTMP= (float*)(ws + O_XB);
  ushortT* PHp = (ushortT*)(ws + O_PH);
  ushortT* PLp = (ushortT*)(ws + O_PL);
  ushortT* FHp = (ushortT*)(ws + O_FH);
  ushortT* FLp = (ushortT*)(ws + O_FL);
  float*   GMAP = (float*)(ws + O_GMAP);
  float*   GPOOL= (float*)(ws + O_GPOOL);
  float*   MASKF= (float*)(ws + O_MASK);
  ushortT* ZP  = (ushortT*)(ws + O_ZP);
  float*   BIASC = (float*)(ws + O_BIASC);
  (void)ws_size;

  float* outp = (float*)d_out;
  float* mout = outp + (size_t)BB*CO*HWP;
  ushortT* dout_u = (ushortT*)d_out;             // merged lo plane, then XL (x lo NHWC)

  dim3 blk(256), blk2(512);
  const ushortT* nu = nullptr; const float* nf_ = nullptr;
  ushortT* nuo = nullptr; float* nfo = nullptr;

  // prep
  prep_w<<<dim3(768, 10), blk, 0, stream>>>(b_w1,b_g1,b_w2,b_g2,b_w3,b_g3,b_dw,b_dg,
      r_w1,r_g1,r_w2,r_g2,r_w3,r_g3,r_dw,r_dg,f_w1,f_g1,f_w2,f_g2,f_w3,f_g3,
      b_b1, r_b1, WPH, WPL, ZP, BIASC);
  k_avgpool_x<<<dim3((BB*CINX*HWP+255)/256), blk, 0, stream>>>(x, PTMP);
  prep_p<<<dim3(49, 16, BB), blk, 0, stream>>>(PTMP, PHp, PLp);

  // merged b1|r1: one x-gather pass, MT=256 (single-buffer, gather path)
  gemm_bf3<0,0,1,256,0,0, 1,0,56,56,56,3136, 256,0,256, 256,256><<<dim3(25,1,BB), blk2, 0, stream>>>(
      WPH+0, WPL+0, nu, nu, nu, nu, x, BIASC, nf_, nf_, nf_, ZP, MGH, dout_u, nfo);
  // b2 (reads t1 = merged rows 0-127, stride 256) — dbuf
  gemm_bf3<1,0,0,128,1,0, 2,1,56,56,28,784, 128,0,256, 128,1152><<<dim3(7,1,BB), blk, 0, stream>>>(
      WPH+65536, WPL+65536, MGH, dout_u, nu, nu, nf_, b_b2, nf_, nf_, nf_, ZP, DHp, DLp, nfo);
  // xbase dual (MT=256, single-buffer)
  gemm_bf3<2,1,0,256,0,0, 1,0,28,28,28,784, 128,256,128, 512,384><<<dim3(7,2,BB), blk2, 0, stream>>>(
      WPH+212992, WPL+212992, DHp, DLp, PHp, PLp, nf_, b_b3, b_db, nf_, nf_, ZP, nuo, nuo, XB);

  // mask path
  k_gmap2<<<dim3(49, BB), blk, 0, stream>>>(XB, m_w, m_g, m_b, GMAP);
  k_gpool<<<dim3(98), blk, 0, stream>>>(GMAP, GPOOL);
  k_mask<<<dim3(25), blk, 0, stream>>>(GPOOL, m_fcw, m_fcb, gum, MASKF, mout);

  // r2 (reads r1 = merged rows 128-255) — dbuf
  gemm_bf3<1,0,0,128,1,0, 1,1,56,56,56,3136, 128,0,256, 128,1152><<<dim3(25,1,BB), blk, 0, stream>>>(
      WPH+409600, WPL+409600, MGH+128, dout_u+128, nu, nu, nf_, r_b2, nf_, nf_, nf_, ZP, EHp, ELp, nfo);

  // pre-split x -> XH (CH region, merged dead) + XL (d_out, merged-lo dead)
  prep_x2<<<dim3(196, 16, BB), blk, 0, stream>>>(x, XH, dout_u);

  // fused = relu(up(xbase) + mask*(conv(r2)+b3) + conv(x)+db) — all-glds, dbuf, mt-fastest grid
  gemm_bf3<3,2,0,128,1,1, 1,0,56,56,56,3136, 128,256,128, 512,384><<<dim3(4,25,BB), blk, 0, stream>>>(
      WPH+557056, WPL+557056, EHp, ELp, XH, dout_u, nf_, r_b3, r_db, MASKF, XB, ZP, FHp, FLp, nfo);

  // pooledF = avgpool3s2(fused)
  k_poolf<<<dim3(HWP, BB), blk, 0, stream>>>(FHp, FLp, PF);

  // fuse branch
  gemm_bf3<0,0,0,128,1,0, 1,0,56,56,56,3136, 512,0,512, 128,512><<<dim3(25,1,BB), blk, 0, stream>>>(
      WPH+753664, WPL+753664, FHp, FLp, nu, nu, nf_, f_b1, nf_, nf_, nf_, ZP, F1H, F1L, nfo);
  gemm_bf3<1,0,0,128,1,0, 2,1,56,56,28,784, 128,0,128, 128,1152><<<dim3(7,1,BB), blk, 0, stream>>>(
      WPH+819200, WPL+819200, F1H, F1L, nu, nu, nf_, f_b2, nf_, nf_, nf_, ZP, DHp, DLp, nfo);
  // out = relu(conv(f2)+b3 + pooledF)   (MT=256, single-buffer)
  gemm_bf3<0,3,0,256,0,0, 1,0,28,28,28,784, 128,0,128, 512,128><<<dim3(7,2,BB), blk2, 0, stream>>>(
      WPH+966656, WPL+966656, DHp, DLp, nu, nu, nf_, f_b3, nf_, nf_, PF, ZP, nuo, nuo, outp);
}

// Round 9
// 1055.350 us; speedup vs baseline: 7.2567x; 1.0180x over previous
//
#include <hip/hip_runtime.h>
#include <cstdint>

// dims
#define BB   32
#define CINX 256
#define HH   56
#define WW   56
#define HWX  3136
#define CO   512
#define PL   128
#define HP   28
#define WP   28
#define HWP  784
#define NG   4
#define MSZ  7

typedef unsigned short ushortT;
typedef unsigned int   uint32;
typedef __attribute__((ext_vector_type(8))) short short8;
typedef __attribute__((ext_vector_type(4))) float f32x4;

__device__ __forceinline__ ushortT f2bf(float f){
  uint32 u = __float_as_uint(f);
  u = (u + 0x7fffu + ((u >> 16) & 1u)) >> 16;   // RNE
  return (ushortT)u;
}
__device__ __forceinline__ float bf2f(ushortT u){
  return __uint_as_float(((uint32)u) << 16);
}
__device__ __forceinline__ void split2(float v, ushortT& h, ushortT& lo){
  h = f2bf(v);
  lo = f2bf(v - bf2f(h));
}
__device__ __forceinline__ uint32 packu(ushortT a, ushortT b){
  return (uint32)a | ((uint32)b << 16);
}

// async global->LDS, 16B per lane; dest = wave-uniform base + lane*16
typedef __attribute__((address_space(1))) const void g_void;
typedef __attribute__((address_space(3))) void l_void;
__device__ __forceinline__ void glds16(const ushortT* g, ushortT* l){
  __builtin_amdgcn_global_load_lds((g_void*)g, (l_void*)l, 16, 0, 0);
}

// ============ weight prep (round-7 layout) ============
__device__ __forceinline__ void wsplit(float v, ushortT* dh, ushortT* dl, size_t i){
  ushortT h, lo; split2(v, h, lo); dh[i] = h; dl[i] = lo;
}

__global__ __launch_bounds__(256) void prep_w(
  const float* __restrict__ b_w1, const float* __restrict__ b_g1,
  const float* __restrict__ b_w2, const float* __restrict__ b_g2,
  const float* __restrict__ b_w3, const float* __restrict__ b_g3,
  const float* __restrict__ b_dw, const float* __restrict__ b_dg,
  const float* __restrict__ r_w1, const float* __restrict__ r_g1,
  const float* __restrict__ r_w2, const float* __restrict__ r_g2,
  const float* __restrict__ r_w3, const float* __restrict__ r_g3,
  const float* __restrict__ r_dw, const float* __restrict__ r_dg,
  const float* __restrict__ f_w1, const float* __restrict__ f_g1,
  const float* __restrict__ f_w2, const float* __restrict__ f_g2,
  const float* __restrict__ f_w3, const float* __restrict__ f_g3,
  const float* __restrict__ b_b1, const float* __restrict__ r_b1,
  ushortT* __restrict__ dh, ushortT* __restrict__ dl,
  ushortT* __restrict__ zp, float* __restrict__ biasC)
{
  const int idx = blockIdx.x*256 + threadIdx.x;
  switch (blockIdx.y){
    case 0: { // b1 rows 0-127 of merged
      if (idx >= 32768) return; int m = idx >> 8;
      wsplit(b_w1[idx]*b_g1[m], dh, dl, (size_t)0 + idx); } break;
    case 3: { // r1 rows 128-255 of merged
      if (idx >= 32768) return; int m = idx >> 8;
      wsplit(r_w1[idx]*r_g1[m], dh, dl, 32768 + (size_t)idx); } break;
    case 1: { // b2 [128][1152] k = tap*128+c
      if (idx >= 147456) return; int m = idx / 1152; int k = idx - m*1152;
      int tap = k >> 7, c = k & 127;
      wsplit(b_w2[((size_t)(m*128 + c))*9 + tap]*b_g2[m], dh, dl, 65536 + (size_t)idx); } break;
    case 2: { // xbase dual [512][384]
      if (idx >= 196608) return; int m = idx / 384; int k = idx - m*384;
      float v = (k < 128) ? b_w3[m*128 + k]*b_g3[m] : b_dw[m*256 + (k-128)]*b_dg[m];
      wsplit(v, dh, dl, 212992 + (size_t)idx); } break;
    case 4: { // r2 [128][1152]
      if (idx >= 147456) return; int m = idx / 1152; int k = idx - m*1152;
      int tap = k >> 7, c = k & 127;
      wsplit(r_w2[((size_t)(m*128 + c))*9 + tap]*r_g2[m], dh, dl, 409600 + (size_t)idx); } break;
    case 5: { // fuse dual [512][384]
      if (idx >= 196608) return; int m = idx / 384; int k = idx - m*384;
      float v = (k < 128) ? r_w3[m*128 + k]*r_g3[m] : r_dw[m*256 + (k-128)]*r_dg[m];
      wsplit(v, dh, dl, 557056 + (size_t)idx); } break;
    case 6: { // f1 [128][512]
      if (idx >= 65536) return; int m = idx >> 9;
      wsplit(f_w1[idx]*f_g1[m], dh, dl, 753664 + (size_t)idx); } break;
    case 7: { // f2 [128][1152]
      if (idx >= 147456) return; int m = idx / 1152; int k = idx - m*1152;
      int tap = k >> 7, c = k & 127;
      wsplit(f_w2[((size_t)(m*128 + c))*9 + tap]*f_g2[m], dh, dl, 819200 + (size_t)idx); } break;
    case 8: { // final [512][128]
      if (idx >= 65536) return; int m = idx >> 7;
      wsplit(f_w3[idx]*f_g3[m], dh, dl, 966656 + (size_t)idx); } break;
    case 9: { // zero page + concat bias
      if (idx < 64) zp[idx] = 0;
      if (idx < 128) biasC[idx] = b_b1[idx];
      else if (idx < 256) biasC[idx] = r_b1[idx-128];
    } break;
  }
}

// ============ pooled: avgpool3s2(x) NCHW f32 -> NHWC hi/lo, fused transpose ============
__global__ __launch_bounds__(256) void k_pool2(const float* __restrict__ x,
    ushortT* __restrict__ ph_, ushortT* __restrict__ pl_){
  __shared__ float s[16][17];
  const int p0 = blockIdx.x*16, c0 = blockIdx.y*16, bz = blockIdx.z;
  const int ci = threadIdx.x >> 4, pi = threadIdx.x & 15;
  {
    const int p = p0 + pi;
    const int oy = p / WP, ox = p - oy*WP;
    const float* src = x + ((size_t)bz*CINX + c0 + ci)*HWX;
    float sum = 0.f;
    #pragma unroll
    for (int dy=0; dy<3; dy++){
      int yy = 2*oy-1+dy;
      if ((unsigned)yy >= HH) continue;
      #pragma unroll
      for (int dx=0; dx<3; dx++){
        int xx = 2*ox-1+dx;
        if ((unsigned)xx >= WW) continue;
        sum += src[yy*WW + xx];
      }
    }
    s[ci][pi] = sum * (1.f/9.f);
  }
  __syncthreads();
  const int pr = threadIdx.x >> 4, cj = threadIdx.x & 15;
  float v = s[cj][pr];
  ushortT h, lo; split2(v, h, lo);
  size_t o = ((size_t)bz*HWP + p0 + pr)*CINX + c0 + cj;
  ph_[o] = h; pl_[o] = lo;
}

// ============ x f32 NCHW -> NHWC hi/lo (16x16 LDS transpose) ============
__global__ __launch_bounds__(256) void prep_x2(const float* __restrict__ x,
    ushortT* __restrict__ xh, ushortT* __restrict__ xl){
  __shared__ float s[16][17];
  const int p0 = blockIdx.x*16, c0 = blockIdx.y*16, bz = blockIdx.z;
  const int ci = threadIdx.x >> 4, pi = threadIdx.x & 15;
  s[ci][pi] = x[((size_t)bz*CINX + c0 + ci)*HWX + p0 + pi];
  __syncthreads();
  const int pr = threadIdx.x >> 4, cj = threadIdx.x & 15;
  float v = s[cj][pr];
  ushortT h, lo; split2(v, h, lo);
  size_t o = ((size_t)bz*HWX + p0 + pr)*CINX + c0 + cj;
  xh[o] = h; xl[o] = lo;
}

// ============ avgpool 3x3 s2 p1 on fused (NHWC hi/lo) -> f32 NHWC [bz][p][512] ============
__global__ __launch_bounds__(256) void k_poolf(const ushortT* __restrict__ fzh,
    const ushortT* __restrict__ fzl, float* __restrict__ pf){
  const int p = blockIdx.x, bz = blockIdx.y;
  const int oy = p / WP, ox = p - oy*WP;
  const int c = threadIdx.x*2;
  float s0 = 0.f, s1 = 0.f;
  #pragma unroll
  for (int dy=0; dy<3; dy++){
    const int iy = 2*oy - 1 + dy;
    if ((unsigned)iy >= (unsigned)HH) continue;
    #pragma unroll
    for (int dx=0; dx<3; dx++){
      const int ix = 2*ox - 1 + dx;
      if ((unsigned)ix >= (unsigned)WW) continue;
      const size_t fi = ((size_t)bz*HWX + (size_t)(iy*WW + ix))*CO + c;
      uint32 hh = *(const uint32*)(fzh + fi);
      uint32 ll = *(const uint32*)(fzl + fi);
      s0 += bf2f((ushortT)(hh & 0xffff)) + bf2f((ushortT)(ll & 0xffff));
      s1 += bf2f((ushortT)(hh >> 16))    + bf2f((ushortT)(ll >> 16));
    }
  }
  const size_t o = ((size_t)bz*HWP + p)*CO + c;
  pf[o]   = s0 * (1.f/9.f);
  pf[o+1] = s1 * (1.f/9.f);
}

// ============ unified bf16x3-split MFMA implicit-GEMM (v5: XCD-chunked remap) ============
// Launched on a 1D grid of T = GX*GY*BB blocks. In-kernel bijective remap gives each
// XCD a contiguous chunk of (x,y,bz) space so B-sharing / tap-sharing blocks co-locate
// on one XCD's L2. x-coord fastest within chunk.
// KIND: 0=1x1, 1=3x3, 2=dual K-concat, 3=dual K-concat w/ mask on src1 (MT must be 128)
// S1F: 1 = f32 NCHW gather (x) split on the fly
// DBUF: 1 = double-buffered LDS; SWAP: 1 = x-coord is mt (else x-coord is nt)
// EPI: 0=bias+relu->hi/lo NHWC, 1=bias1+bias2->f32 NCHW, 2=fuse, 3=final(+pooledF)
template<int KIND,int EPI,int S1F,int MT,int DBUF,int SWAP,int GX,int GY,int STRIDE,int PAD,
         int HIN,int WIN,int WOUT,int NOUT,int C1,int C2,int BSTR1,int MTOT,int KTOT>
__global__ __launch_bounds__(MT*2)
void gemm_bf3(const ushortT* __restrict__ wph, const ushortT* __restrict__ wpl,
              const ushortT* __restrict__ s1h, const ushortT* __restrict__ s1l,
              const ushortT* __restrict__ s2h, const ushortT* __restrict__ s2l,
              const float* __restrict__ xf32,
              const float* __restrict__ bias1, const float* __restrict__ bias2,
              const float* __restrict__ maskf, const float* __restrict__ xbase,
              const ushortT* __restrict__ zp,
              ushortT* __restrict__ oh, ushortT* __restrict__ ol,
              float* __restrict__ of32)
{
  constexpr int NW = MT/32;        // waves: 4 (MT=128) or 8 (MT=256)
  constexpr int BCALLS = 8/NW;     // B glds calls/wave: 2 or 1
  constexpr bool GATHER1 = (KIND==0 && S1F==1);
  constexpr int BUFSZ = MT*64 + 8192;   // ushorts per buffer
  constexpr int T = GX*GY*BB;
  static_assert(T % 8 == 0, "grid not divisible by 8 XCDs");
  constexpr int QX = T/8;
  __shared__ ushortT smem[BUFSZ*(DBUF+1)];

  const int tid = threadIdx.x;
  const int lin = blockIdx.x;
  const int virt = (lin & 7)*QX + (lin >> 3);        // bijective XCD-chunked remap
  const int vx = virt % GX;
  const int vrest = virt / GX;
  const int vy = vrest % GY;
  const int bz = vrest / GY;
  const int nt = SWAP ? vy : vx;
  const int mt = SWAP ? vx : vy;
  const int l  = tid & 63, w = tid >> 6;
  const int wm = w >> 1, wn = w & 1;

  // ---- A glds precompute: 2 calls/wave/plane ----
  size_t a_src[2]; int a_dst[2];
  #pragma unroll
  for (int c=0;c<2;c++){
    int s = (w*2 + c)*64 + l;
    int row = s >> 2, slotm = s & 3;
    int logical = slotm ^ ((row >> 1) & 3);
    a_src[c] = (size_t)(mt*MT + row)*KTOT + logical*8;
    a_dst[c] = (w*2 + c)*512;
  }

  // ---- B glds precompute ----
  int b_dst[2]; size_t b_base1[2], b_base2[2]; int b_klane[2];
  int b_oy[2], b_ox[2]; bool b_ok[2]; float b_mv[2];
  #pragma unroll
  for (int c=0;c<BCALLS;c++){
    int s = (w*BCALLS + c)*64 + l;
    int row = s >> 2, slotm = s & 3;
    int logical = slotm ^ ((row >> 1) & 3);
    b_klane[c] = logical*8;
    b_dst[c] = (w*BCALLS + c)*512;
    int ngr = nt*128 + row;
    b_ok[c] = (ngr < NOUT);
    int oyv = ngr / WOUT, oxv = ngr - (ngr / WOUT)*WOUT;
    b_oy[c] = oyv; b_ox[c] = oxv;
    b_base1[c] = ((size_t)bz*NOUT + ngr)*BSTR1 + b_klane[c];
    b_base2[c] = ((size_t)bz*NOUT + ngr)*C2 + b_klane[c];
    b_mv[c] = 1.f;
    if (KIND == 3)
      b_mv[c] = b_ok[c] ? maskf[((size_t)(bz*NG + mt)*MSZ + (oyv>>3))*MSZ + (oxv>>3)] : 0.f;
  }

  // ---- gather-path (VGPR) ids ----
  const int sr = tid >> 1;
  const int hp = tid & 1;
  const int swz = (sr >> 1) & 3;
  const int lws0 = sr*32 + ((2*hp) ^ swz)*8;
  const int lws1 = sr*32 + ((2*hp + 1) ^ swz)*8;
  const int ng = nt*128 + sr;

  f32x4 acc[4][4];
  f32x4 zf = {0.f,0.f,0.f,0.f};
  #pragma unroll
  for (int i=0;i<4;i++)
    #pragma unroll
    for (int j=0;j<4;j++) acc[i][j] = zf;

  auto stagef = [&](int ks, ushortT* AHb, ushortT* ALb, ushortT* BHb, ushortT* BLb){
    const int k0 = ks*32;
    #pragma unroll
    for (int c=0;c<2;c++){
      glds16(wph + a_src[c] + k0, AHb + a_dst[c]);
      glds16(wpl + a_src[c] + k0, ALb + a_dst[c]);
    }
    if constexpr (GATHER1){
      if (tid < 256){
        uint4 b0 = make_uint4(0,0,0,0), b1v = b0, b2v = b0, b3v = b0;
        if (ng < NOUT){
          size_t fbase = ((size_t)bz*C1 + k0 + hp*16)*(size_t)NOUT + ng;
          ushortT h[16], lo[16];
          #pragma unroll
          for (int e=0;e<16;e++){ split2(xf32[fbase + (size_t)e*NOUT], h[e], lo[e]); }
          b0  = make_uint4(packu(h[0],h[1]),  packu(h[2],h[3]),  packu(h[4],h[5]),  packu(h[6],h[7]));
          b1v = make_uint4(packu(h[8],h[9]),  packu(h[10],h[11]),packu(h[12],h[13]),packu(h[14],h[15]));
          b2v = make_uint4(packu(lo[0],lo[1]),packu(lo[2],lo[3]),packu(lo[4],lo[5]),packu(lo[6],lo[7]));
          b3v = make_uint4(packu(lo[8],lo[9]),packu(lo[10],lo[11]),packu(lo[12],lo[13]),packu(lo[14],lo[15]));
        }
        *(uint4*)(BHb + lws0) = b0;  *(uint4*)(BHb + lws1) = b1v;
        *(uint4*)(BLb + lws0) = b2v; *(uint4*)(BLb + lws1) = b3v;
      }
    } else {
      #pragma unroll
      for (int c=0;c<BCALLS;c++){
        const ushortT *sh, *sl;
        if constexpr (KIND == 0){
          bool ok = b_ok[c];
          size_t off = b_base1[c] + k0;
          sh = ok ? s1h + off : zp;  sl = ok ? s1l + off : zp;
        } else if constexpr (KIND == 1){
          const int tap = k0 >> 7;             // C1 == 128
          const int cb  = (k0 & 127);
          const int dy = tap/3, dx = tap - 3*(tap/3);
          int iy = b_oy[c]*STRIDE + dy - PAD;
          int ix = b_ox[c]*STRIDE + dx - PAD;
          bool ok = b_ok[c] && (unsigned)iy < (unsigned)HIN && (unsigned)ix < (unsigned)WIN;
          size_t off = ((size_t)bz*(HIN*WIN) + (size_t)(iy*WIN + ix))*BSTR1 + cb + b_klane[c];
          sh = ok ? s1h + off : zp;  sl = ok ? s1l + off : zp;
        } else {
          if (k0 < C1){
            bool ok = b_ok[c] && (KIND != 3 || b_mv[c] != 0.f);
            size_t off = b_base1[c] + k0;
            sh = ok ? s1h + off : zp;  sl = ok ? s1l + off : zp;
          } else {
            bool ok = b_ok[c];
            size_t off = b_base2[c] + (k0 - C1);
            sh = ok ? s2h + off : zp;  sl = ok ? s2l + off : zp;
          }
        }
        glds16(sh, BHb + b_dst[c]);
        glds16(sl, BLb + b_dst[c]);
      }
    }
  };

  auto computef = [&](const ushortT* AHb, const ushortT* ALb,
                      const ushortT* BHb, const ushortT* BLb){
    short8 bh[4], bl[4];
    #pragma unroll
    for (int nf=0; nf<4; nf++){
      const int rr = wn*64 + nf*16 + (l & 15);
      const int ph = (l >> 4) ^ ((rr >> 1) & 3);
      bh[nf] = *(const short8*)(BHb + rr*32 + ph*8);
      bl[nf] = *(const short8*)(BLb + rr*32 + ph*8);
    }
    #pragma unroll
    for (int mf=0; mf<4; mf++){
      const int rr = wm*64 + mf*16 + (l & 15);
      const int ph = (l >> 4) ^ ((rr >> 1) & 3);
      short8 ah = *(const short8*)(AHb + rr*32 + ph*8);
      short8 al = *(const short8*)(ALb + rr*32 + ph*8);
      #pragma unroll
      for (int nf=0; nf<4; nf++)
        acc[mf][nf] = __builtin_amdgcn_mfma_f32_16x16x32_bf16(ah, bh[nf], acc[mf][nf], 0,0,0);
      #pragma unroll
      for (int nf=0; nf<4; nf++)
        acc[mf][nf] = __builtin_amdgcn_mfma_f32_16x16x32_bf16(ah, bl[nf], acc[mf][nf], 0,0,0);
      #pragma unroll
      for (int nf=0; nf<4; nf++)
        acc[mf][nf] = __builtin_amdgcn_mfma_f32_16x16x32_bf16(al, bh[nf], acc[mf][nf], 0,0,0);
    }
  };

  const int NK = KTOT / 32;
  if constexpr (DBUF == 0){
    ushortT* AH  = smem;
    ushortT* AL  = smem + MT*32;
    ushortT* BHs = smem + MT*64;
    ushortT* BLs = smem + MT*64 + 4096;
    for (int ks=0; ks<NK; ks++){
      stagef(ks, AH, AL, BHs, BLs);
      __syncthreads();
      computef(AH, AL, BHs, BLs);
      __syncthreads();
    }
  } else {
    // 2-phase: stage(k+1) overlaps compute(k); one barrier per iteration
    stagef(0, smem, smem + MT*32, smem + MT*64, smem + MT*64 + 4096);
    __syncthreads();
    for (int ks=0; ks<NK; ks++){
      ushortT* cb = smem + (ks & 1)*BUFSZ;
      ushortT* nb = smem + ((ks & 1) ^ 1)*BUFSZ;
      if (ks + 1 < NK)
        stagef(ks + 1, nb, nb + MT*32, nb + MT*64, nb + MT*64 + 4096);
      computef(cb, cb + MT*32, cb + MT*64, cb + MT*64 + 4096);
      __syncthreads();
    }
  }

  // epilogue: C/D frag: col n = l&15, row m = (l>>4)*4 + r
  const int mb0 = mt*MT + wm*64;
  const int nb0 = nt*128 + wn*64;

  #pragma unroll
  for (int nf=0; nf<4; nf++){
    const int n = nb0 + nf*16 + (l & 15);
    if (n >= NOUT) continue;
    if constexpr (EPI == 0){
      const size_t ob = ((size_t)bz*NOUT + n)*MTOT;
      #pragma unroll
      for (int mf=0; mf<4; mf++){
        const int m0 = mb0 + mf*16 + (l>>4)*4;
        ushort4 hq, lq; ushortT h0, l0; float v;
        v = fmaxf(acc[mf][nf][0] + bias1[m0+0], 0.f); split2(v,h0,l0); hq.x=h0; lq.x=l0;
        v = fmaxf(acc[mf][nf][1] + bias1[m0+1], 0.f); split2(v,h0,l0); hq.y=h0; lq.y=l0;
        v = fmaxf(acc[mf][nf][2] + bias1[m0+2], 0.f); split2(v,h0,l0); hq.z=h0; lq.z=l0;
        v = fmaxf(acc[mf][nf][3] + bias1[m0+3], 0.f); split2(v,h0,l0); hq.w=h0; lq.w=l0;
        *(ushort4*)(oh + ob + m0) = hq;
        *(ushort4*)(ol + ob + m0) = lq;
      }
    } else if constexpr (EPI == 1){
      #pragma unroll
      for (int mf=0; mf<4; mf++){
        const int m0 = mb0 + mf*16 + (l>>4)*4;
        #pragma unroll
        for (int r=0;r<4;r++){
          const int m = m0 + r;
          of32[((size_t)bz*MTOT + m)*NOUT + n] = acc[mf][nf][r] + bias1[m] + bias2[m];
        }
      }
    } else if constexpr (EPI == 2){
      const int y = n / WOUT, x = n - (n / WOUT)*WOUT;
      const int grpw = (mt*MT + wm*64) >> 7;
      const float mvv = maskf[((size_t)(bz*NG + grpw)*MSZ + (y>>3))*MSZ + (x>>3)];
      const int iy = y >> 1, ix = x >> 1;
      int yA,yB,xA,xB; float wyA,wyB,wxA,wxB;
      if (y & 1){ yA=iy; wyA=0.75f; yB=(iy+1<HP)?iy+1:HP-1; wyB=0.25f; }
      else      { yA=(iy>0)?iy-1:0; wyA=0.25f; yB=iy; wyB=0.75f; }
      if (x & 1){ xA=ix; wxA=0.75f; xB=(ix+1<WP)?ix+1:WP-1; wxB=0.25f; }
      else      { xA=(ix>0)?ix-1:0; wxA=0.25f; xB=ix; wxB=0.75f; }
      const size_t ob = ((size_t)bz*NOUT + n)*MTOT;
      #pragma unroll
      for (int mf=0; mf<4; mf++){
        const int m0 = mb0 + mf*16 + (l>>4)*4;
        ushort4 hq, lq;
        #pragma unroll
        for (int r=0;r<4;r++){
          const int m = m0 + r;
          const float* xb = xbase + ((size_t)bz*MTOT + m)*HWP;
          float up = wyA*(wxA*xb[yA*WP+xA] + wxB*xb[yA*WP+xB])
                   + wyB*(wxA*xb[yB*WP+xA] + wxB*xb[yB*WP+xB]);
          float v = fmaxf(acc[mf][nf][r] + up + mvv*bias1[m] + bias2[m], 0.f);
          ushortT h0, l0; split2(v, h0, l0);
          if      (r==0){hq.x=h0;lq.x=l0;}
          else if (r==1){hq.y=h0;lq.y=l0;}
          else if (r==2){hq.z=h0;lq.z=l0;}
          else          {hq.w=h0;lq.w=l0;}
        }
        *(ushort4*)(oh + ob + m0) = hq;
        *(ushort4*)(ol + ob + m0) = lq;
      }
    } else { // EPI == 3: out = relu(acc + bias1 + pooledF[bz][n][m])
      const float* pfrow = xbase + ((size_t)bz*NOUT + n)*MTOT;
      #pragma unroll
      for (int mf=0; mf<4; mf++){
        const int m0 = mb0 + mf*16 + (l>>4)*4;
        const float4 pv = *(const float4*)(pfrow + m0);
        of32[((size_t)bz*MTOT + m0+0)*NOUT + n] = fmaxf(acc[mf][nf][0] + bias1[m0+0] + pv.x, 0.f);
        of32[((size_t)bz*MTOT + m0+1)*NOUT + n] = fmaxf(acc[mf][nf][1] + bias1[m0+1] + pv.y, 0.f);
        of32[((size_t)bz*MTOT + m0+2)*NOUT + n] = fmaxf(acc[mf][nf][2] + bias1[m0+2] + pv.z, 0.f);
        of32[((size_t)bz*MTOT + m0+3)*NOUT + n] = fmaxf(acc[mf][nf][3] + bias1[m0+3] + pv.w, 0.f);
      }
    }
  }
}

// ============ gmap v2 (round-6 proven) ============
#define GM_LDSW 9216
__global__ __launch_bounds__(256) void k_gmap2(const float* __restrict__ xbase,
    const float* __restrict__ mw, const float* __restrict__ mg, const float* __restrict__ mb,
    float* __restrict__ gmap){
  __shared__ float wsh[GM_LDSW];
  __shared__ float red[16][2][4][16];
  const int tile = blockIdx.x, b = blockIdx.y;
  const int tid = threadIdx.x;
  const int pl = tid & 15, cs = tid >> 4;
  const int p = tile*16 + pl;
  const int oy = p / WP, ox = p - oy*WP;
  int toff[9];
  #pragma unroll
  for (int tap=0; tap<9; tap++){
    int dy = tap/3, dx = tap - 3*dy;
    int yy = oy + dy - 1, xx = ox + dx - 1;
    toff[tap] = ((unsigned)yy < (unsigned)HP && (unsigned)xx < (unsigned)WP) ? (yy*WP + xx) : -1;
  }
  float acc[2][4] = {{0.f,0.f,0.f,0.f},{0.f,0.f,0.f,0.f}};
  for (int pass=0; pass<2; pass++){
    __syncthreads();
    for (int i = tid; i < GM_LDSW; i += 256){
      int ocl = i & 3, tap = (i >> 2) % 9, c_rel = i / 36;
      int cg = pass*256 + c_rel;
      int g = cg >> 7;
      int oc = g*4 + ocl;
      wsh[i] = mw[((size_t)(oc*128 + (cg & 127)))*9 + tap] * mg[oc];
    }
    __syncthreads();
    const float* xb = xbase + ((size_t)b*CO + pass*256 + cs*16)*HWP;
    for (int cl=0; cl<16; cl++){
      const float* xc = xb + (size_t)cl*HWP;
      const float* wr = &wsh[(cs*16 + cl)*36];
      #pragma unroll
      for (int tap=0; tap<9; tap++){
        if (toff[tap] < 0) continue;
        float v = xc[toff[tap]];
        f32x4 w4 = *(const f32x4*)(wr + tap*4);
        acc[pass][0] += v*w4[0];
        acc[pass][1] += v*w4[1];
        acc[pass][2] += v*w4[2];
        acc[pass][3] += v*w4[3];
      }
    }
  }
  #pragma unroll
  for (int pp=0; pp<2; pp++)
    #pragma unroll
    for (int o=0; o<4; o++)
      red[cs][pp][o][pl] = acc[pp][o];
  __syncthreads();
  const int oc = tid >> 4;
  const int g = oc >> 2, ocl = oc & 3, pg = g >> 1, cs0 = (g & 1)*8;
  float s = 0.f;
  #pragma unroll
  for (int t=0; t<8; t++) s += red[cs0 + t][pg][ocl][pl];
  s = fmaxf(s + mb[oc], 0.f);
  gmap[((size_t)b*16 + oc)*HWP + p] = s;
}

__global__ __launch_bounds__(256) void k_gpool(const float* __restrict__ gmap, float* __restrict__ gpool){
  int idx = blockIdx.x*256 + threadIdx.x;
  if (idx >= BB*16*49) return;
  int q = idx % 49; int t = idx / 49; int ch = t % 16; int b = t / 16;
  int my = q/7, mx = q%7;
  const float* src = gmap + ((size_t)b*16 + ch)*HWP;
  float s = 0.f;
  #pragma unroll
  for (int yb=0;yb<4;yb++)
    #pragma unroll
    for (int xb=0;xb<4;xb++)
      s += src[(my*4+yb)*WP + (mx*4+xb)];
  gpool[idx] = s * (1.f/16.f);
}

__global__ __launch_bounds__(256) void k_mask(const float* __restrict__ gpool, const float* __restrict__ fcw,
    const float* __restrict__ fcb, const float* __restrict__ gum,
    float* __restrict__ maskf, float* __restrict__ mout){
  int idx = blockIdx.x*256 + threadIdx.x;
  if (idx >= BB*NG*49) return;
  int q = idx % 49; int t = idx / 49; int g = t % NG; int b = t / NG;
  float lgt[2];
  #pragma unroll
  for (int cls=0; cls<2; cls++){
    int c = cls*NG + g;
    int gc = c >> 1;
    float s = fcb[c];
    #pragma unroll
    for (int k=0;k<4;k++)
      s += fcw[c*4+k] * gpool[((size_t)b*16 + gc*4 + k)*49 + q];
    s += gum[(((size_t)b*2 + cls)*NG + g)*49 + q];
    lgt[cls] = s;
  }
  float m = (lgt[1] > lgt[0]) ? 1.f : 0.f;
  maskf[idx] = m;
  mout[idx] = m;
}

extern "C" void kernel_launch(void* const* d_in, const int* in_sizes, int n_in,
                              void* d_out, int out_size, void* d_ws, size_t ws_size,
                              hipStream_t stream){
  const float* x    = (const float*)d_in[0];
  const float* gum  = (const float*)d_in[1];
  const float* b_w1 = (const float*)d_in[2];
  const float* b_g1 = (const float*)d_in[3];
  const float* b_b1 = (const float*)d_in[4];
  const float* b_w2 = (const float*)d_in[5];
  const float* b_g2 = (const float*)d_in[6];
  const float* b_b2 = (const float*)d_in[7];
  const float* b_w3 = (const float*)d_in[8];
  const float* b_g3 = (const float*)d_in[9];
  const float* b_b3 = (const float*)d_in[10];
  const float* b_dw = (const float*)d_in[11];
  const float* b_dg = (const float*)d_in[12];
  const float* b_db = (const float*)d_in[13];
  const float* r_w1 = (const float*)d_in[14];
  const float* r_g1 = (const float*)d_in[15];
  const float* r_b1 = (const float*)d_in[16];
  const float* r_w2 = (const float*)d_in[17];
  const float* r_g2 = (const float*)d_in[18];
  const float* r_b2 = (const float*)d_in[19];
  const float* r_w3 = (const float*)d_in[20];
  const float* r_g3 = (const float*)d_in[21];
  const float* r_b3 = (const float*)d_in[22];
  const float* r_dw = (const float*)d_in[23];
  const float* r_dg = (const float*)d_in[24];
  const float* r_db = (const float*)d_in[25];
  const float* m_w  = (const float*)d_in[26];
  const float* m_g  = (const float*)d_in[27];
  const float* m_b  = (const float*)d_in[28];
  const float* m_fcw= (const float*)d_in[29];
  const float* m_fcb= (const float*)d_in[30];
  const float* f_w1 = (const float*)d_in[31];
  const float* f_g1 = (const float*)d_in[32];
  const float* f_b1 = (const float*)d_in[33];
  const float* f_w2 = (const float*)d_in[34];
  const float* f_g2 = (const float*)d_in[35];
  const float* f_b2 = (const float*)d_in[36];
  const float* f_w3 = (const float*)d_in[37];
  const float* f_g3 = (const float*)d_in[38];
  const float* f_b3 = (const float*)d_in[39];

  char* ws = (char*)d_ws;
  // ws layout v5 — total 378,367,616 B
  constexpr size_t O_WPH  = 0;            //  2,064,384
  constexpr size_t O_WPL  = 2064384;      //  2,064,384  -> 4,128,768
  constexpr size_t O_CH   = 4128768;      // 51,380,224  merged hi; then XH (x hi NHWC); then f1 hi+lo
  constexpr size_t O_DH   = 55508992;     //  6,422,528  t2/f2 hi
  constexpr size_t O_DL   = 61931520;     //  6,422,528  -> 68,354,048
  constexpr size_t O_EH   = 68354048;     // 25,690,112  r2 hi
  constexpr size_t O_EL   = 94044160;     // 25,690,112  -> 119,734,272
  constexpr size_t O_PF   = O_EH;         // 51,380,224  pooledF f32 NHWC (r2 dead after fuse)
  constexpr size_t O_XB   = 119734272;    // 51,380,224  xbase f32 NCHW
  constexpr size_t O_GMAP = 171114496;    //  1,605,632
  constexpr size_t O_GPOOL= 172720128;    //    100,352
  constexpr size_t O_MASK = 172820480;    //     25,088
  constexpr size_t O_FH   = 172845568;    // 102,760,448 fused hi (overlaps PH/PL)
  constexpr size_t O_PH   = 172845568;    // 12,845,056  pooled hi (dead after xbase GEMM)
  constexpr size_t O_PL   = 185690624;    // 12,845,056
  constexpr size_t O_FL   = 275606016;    // 102,760,448 -> 378,366,464
  constexpr size_t O_ZP   = 378366464;    //        128  zero page
  constexpr size_t O_BIASC= 378366592;    //      1,024  concat bias -> 378,367,616

  ushortT* WPH = (ushortT*)(ws + O_WPH);
  ushortT* WPL = (ushortT*)(ws + O_WPL);
  ushortT* MGH = (ushortT*)(ws + O_CH);          // merged hi plane, stride 256 (b2/r2 input)
  ushortT* XH  = (ushortT*)(ws + O_CH);          // x hi NHWC (after r2; fuse input)
  ushortT* F1H = (ushortT*)(ws + O_CH);          // f1 hi (after fuse)
  ushortT* F1L = (ushortT*)(ws + O_CH + 25690112);
  ushortT* DHp = (ushortT*)(ws + O_DH);
  ushortT* DLp = (ushortT*)(ws + O_DL);
  ushortT* EHp = (ushortT*)(ws + O_EH);
  ushortT* ELp = (ushortT*)(ws + O_EL);
  float*   PF  = (float*)(ws + O_PF);
  float*   XB  = (float*)(ws + O_XB);
  ushortT* PHp = (ushortT*)(ws + O_PH);
  ushortT* PLp = (ushortT*)(ws + O_PL);
  ushortT* FHp = (ushortT*)(ws + O_FH);
  ushortT* FLp = (ushortT*)(ws + O_FL);
  float*   GMAP = (float*)(ws + O_GMAP);
  float*   GPOOL= (float*)(ws + O_GPOOL);
  float*   MASKF= (float*)(ws + O_MASK);
  ushortT* ZP  = (ushortT*)(ws + O_ZP);
  float*   BIASC = (float*)(ws + O_BIASC);
  (void)ws_size;

  float* outp = (float*)d_out;
  float* mout = outp + (size_t)BB*CO*HWP;
  ushortT* dout_u = (ushortT*)d_out;             // merged lo plane, then XL (x lo NHWC)

  dim3 blk(256), blk2(512);
  const ushortT* nu = nullptr; const float* nf_ = nullptr;
  ushortT* nuo = nullptr; float* nfo = nullptr;

  // prep
  prep_w<<<dim3(768, 10), blk, 0, stream>>>(b_w1,b_g1,b_w2,b_g2,b_w3,b_g3,b_dw,b_dg,
      r_w1,r_g1,r_w2,r_g2,r_w3,r_g3,r_dw,r_dg,f_w1,f_g1,f_w2,f_g2,f_w3,f_g3,
      b_b1, r_b1, WPH, WPL, ZP, BIASC);
  k_pool2<<<dim3(49, 16, BB), blk, 0, stream>>>(x, PHp, PLp);

  // merged b1|r1: one x-gather pass, MT=256 (single-buffer, gather path)  T=25*1*32=800
  gemm_bf3<0,0,1,256,0,0, 25,1, 1,0,56,56,56,3136, 256,0,256, 256,256><<<dim3(800), blk2, 0, stream>>>(
      WPH+0, WPL+0, nu, nu, nu, nu, x, BIASC, nf_, nf_, nf_, ZP, MGH, dout_u, nfo);
  // b2 (reads t1 = merged rows 0-127, stride 256) — dbuf  T=7*1*32=224
  gemm_bf3<1,0,0,128,1,0, 7,1, 2,1,56,56,28,784, 128,0,256, 128,1152><<<dim3(224), blk, 0, stream>>>(
      WPH+65536, WPL+65536, MGH, dout_u, nu, nu, nf_, b_b2, nf_, nf_, nf_, ZP, DHp, DLp, nfo);
  // xbase dual (MT=256, single-buffer)  T=7*2*32=448
  gemm_bf3<2,1,0,256,0,0, 7,2, 1,0,28,28,28,784, 128,256,128, 512,384><<<dim3(448), blk2, 0, stream>>>(
      WPH+212992, WPL+212992, DHp, DLp, PHp, PLp, nf_, b_b3, b_db, nf_, nf_, ZP, nuo, nuo, XB);

  // mask path
  k_gmap2<<<dim3(49, BB), blk, 0, stream>>>(XB, m_w, m_g, m_b, GMAP);
  k_gpool<<<dim3(98), blk, 0, stream>>>(GMAP, GPOOL);
  k_mask<<<dim3(25), blk, 0, stream>>>(GPOOL, m_fcw, m_fcb, gum, MASKF, mout);

  // r2 (reads r1 = merged rows 128-255) — dbuf  T=800
  gemm_bf3<1,0,0,128,1,0, 25,1, 1,1,56,56,56,3136, 128,0,256, 128,1152><<<dim3(800), blk, 0, stream>>>(
      WPH+409600, WPL+409600, MGH+128, dout_u+128, nu, nu, nf_, r_b2, nf_, nf_, nf_, ZP, EHp, ELp, nfo);

  // pre-split x -> XH (CH region, merged dead) + XL (d_out, merged-lo dead)
  prep_x2<<<dim3(196, 16, BB), blk, 0, stream>>>(x, XH, dout_u);

  // fused = relu(up(xbase) + mask*(conv(r2)+b3) + conv(x)+db) — all-glds, dbuf, mt-fastest  T=4*25*32=3200
  gemm_bf3<3,2,0,128,1,1, 4,25, 1,0,56,56,56,3136, 128,256,128, 512,384><<<dim3(3200), blk, 0, stream>>>(
      WPH+557056, WPL+557056, EHp, ELp, XH, dout_u, nf_, r_b3, r_db, MASKF, XB, ZP, FHp, FLp, nfo);

  // pooledF = avgpool3s2(fused)
  k_poolf<<<dim3(HWP, BB), blk, 0, stream>>>(FHp, FLp, PF);

  // fuse branch
  gemm_bf3<0,0,0,128,1,0, 25,1, 1,0,56,56,56,3136, 512,0,512, 128,512><<<dim3(800), blk, 0, stream>>>(
      WPH+753664, WPL+753664, FHp, FLp, nu, nu, nf_, f_b1, nf_, nf_, nf_, ZP, F1H, F1L, nfo);
  gemm_bf3<1,0,0,128,1,0, 7,1, 2,1,56,56,28,784, 128,0,128, 128,1152><<<dim3(224), blk, 0, stream>>>(
      WPH+819200, WPL+819200, F1H, F1L, nu, nu, nf_, f_b2, nf_, nf_, nf_, ZP, DHp, DLp, nfo);
  // out = relu(conv(f2)+b3 + pooledF)   (MT=256, single-buffer)  T=448
  gemm_bf3<0,3,0,256,0,0, 7,2, 1,0,28,28,28,784, 128,0,128, 512,128><<<dim3(448), blk2, 0, stream>>>(
      WPH+966656, WPL+966656, DHp, DLp, nu, nu, nf_, f_b3, nf_, nf_, PF, ZP, nuo, nuo, outp);
}

// Round 10
// 1054.405 us; speedup vs baseline: 7.2632x; 1.0009x over previous
//
#include <hip/hip_runtime.h>
#include <cstdint>

// dims
#define BB   32
#define CINX 256
#define HH   56
#define WW   56
#define HWX  3136
#define CO   512
#define PL   128
#define HP   28
#define WP   28
#define HWP  784
#define NG   4
#define MSZ  7

typedef unsigned short ushortT;
typedef unsigned int   uint32;
typedef __attribute__((ext_vector_type(8))) short short8;
typedef __attribute__((ext_vector_type(4))) float f32x4;

__device__ __forceinline__ ushortT f2bf(float f){
  uint32 u = __float_as_uint(f);
  u = (u + 0x7fffu + ((u >> 16) & 1u)) >> 16;   // RNE
  return (ushortT)u;
}
__device__ __forceinline__ float bf2f(ushortT u){
  return __uint_as_float(((uint32)u) << 16);
}
__device__ __forceinline__ void split2(float v, ushortT& h, ushortT& lo){
  h = f2bf(v);
  lo = f2bf(v - bf2f(h));
}
__device__ __forceinline__ uint32 packu(ushortT a, ushortT b){
  return (uint32)a | ((uint32)b << 16);
}

// async global->LDS, 16B per lane; dest = wave-uniform base + lane*16
typedef __attribute__((address_space(1))) const void g_void;
typedef __attribute__((address_space(3))) void l_void;
__device__ __forceinline__ void glds16(const ushortT* g, ushortT* l){
  __builtin_amdgcn_global_load_lds((g_void*)g, (l_void*)l, 16, 0, 0);
}
__device__ __forceinline__ void waitcnt_vm8(){ asm volatile("s_waitcnt vmcnt(8)" ::: "memory"); }
__device__ __forceinline__ void waitcnt_vm0(){ asm volatile("s_waitcnt vmcnt(0)" ::: "memory"); }

// ============ weight prep (round-7 layout) ============
__device__ __forceinline__ void wsplit(float v, ushortT* dh, ushortT* dl, size_t i){
  ushortT h, lo; split2(v, h, lo); dh[i] = h; dl[i] = lo;
}

__global__ __launch_bounds__(256) void prep_w(
  const float* __restrict__ b_w1, const float* __restrict__ b_g1,
  const float* __restrict__ b_w2, const float* __restrict__ b_g2,
  const float* __restrict__ b_w3, const float* __restrict__ b_g3,
  const float* __restrict__ b_dw, const float* __restrict__ b_dg,
  const float* __restrict__ r_w1, const float* __restrict__ r_g1,
  const float* __restrict__ r_w2, const float* __restrict__ r_g2,
  const float* __restrict__ r_w3, const float* __restrict__ r_g3,
  const float* __restrict__ r_dw, const float* __restrict__ r_dg,
  const float* __restrict__ f_w1, const float* __restrict__ f_g1,
  const float* __restrict__ f_w2, const float* __restrict__ f_g2,
  const float* __restrict__ f_w3, const float* __restrict__ f_g3,
  const float* __restrict__ b_b1, const float* __restrict__ r_b1,
  ushortT* __restrict__ dh, ushortT* __restrict__ dl,
  ushortT* __restrict__ zp, float* __restrict__ biasC)
{
  const int idx = blockIdx.x*256 + threadIdx.x;
  switch (blockIdx.y){
    case 0: { // b1 rows 0-127 of merged
      if (idx >= 32768) return; int m = idx >> 8;
      wsplit(b_w1[idx]*b_g1[m], dh, dl, (size_t)0 + idx); } break;
    case 3: { // r1 rows 128-255 of merged
      if (idx >= 32768) return; int m = idx >> 8;
      wsplit(r_w1[idx]*r_g1[m], dh, dl, 32768 + (size_t)idx); } break;
    case 1: { // b2 [128][1152] k = tap*128+c
      if (idx >= 147456) return; int m = idx / 1152; int k = idx - m*1152;
      int tap = k >> 7, c = k & 127;
      wsplit(b_w2[((size_t)(m*128 + c))*9 + tap]*b_g2[m], dh, dl, 65536 + (size_t)idx); } break;
    case 2: { // xbase dual [512][384]
      if (idx >= 196608) return; int m = idx / 384; int k = idx - m*384;
      float v = (k < 128) ? b_w3[m*128 + k]*b_g3[m] : b_dw[m*256 + (k-128)]*b_dg[m];
      wsplit(v, dh, dl, 212992 + (size_t)idx); } break;
    case 4: { // r2 [128][1152]
      if (idx >= 147456) return; int m = idx / 1152; int k = idx - m*1152;
      int tap = k >> 7, c = k & 127;
      wsplit(r_w2[((size_t)(m*128 + c))*9 + tap]*r_g2[m], dh, dl, 409600 + (size_t)idx); } break;
    case 5: { // fuse dual [512][384]
      if (idx >= 196608) return; int m = idx / 384; int k = idx - m*384;
      float v = (k < 128) ? r_w3[m*128 + k]*r_g3[m] : r_dw[m*256 + (k-128)]*r_dg[m];
      wsplit(v, dh, dl, 557056 + (size_t)idx); } break;
    case 6: { // f1 [128][512]
      if (idx >= 65536) return; int m = idx >> 9;
      wsplit(f_w1[idx]*f_g1[m], dh, dl, 753664 + (size_t)idx); } break;
    case 7: { // f2 [128][1152]
      if (idx >= 147456) return; int m = idx / 1152; int k = idx - m*1152;
      int tap = k >> 7, c = k & 127;
      wsplit(f_w2[((size_t)(m*128 + c))*9 + tap]*f_g2[m], dh, dl, 819200 + (size_t)idx); } break;
    case 8: { // final [512][128]
      if (idx >= 65536) return; int m = idx >> 7;
      wsplit(f_w3[idx]*f_g3[m], dh, dl, 966656 + (size_t)idx); } break;
    case 9: { // zero page + concat bias
      if (idx < 64) zp[idx] = 0;
      if (idx < 128) biasC[idx] = b_b1[idx];
      else if (idx < 256) biasC[idx] = r_b1[idx-128];
    } break;
  }
}

// ============ pooled: avgpool3s2(x) NCHW f32 -> NHWC hi/lo, fused transpose ============
__global__ __launch_bounds__(256) void k_pool2(const float* __restrict__ x,
    ushortT* __restrict__ ph_, ushortT* __restrict__ pl_){
  __shared__ float s[16][17];
  const int p0 = blockIdx.x*16, c0 = blockIdx.y*16, bz = blockIdx.z;
  const int ci = threadIdx.x >> 4, pi = threadIdx.x & 15;
  {
    const int p = p0 + pi;
    const int oy = p / WP, ox = p - oy*WP;
    const float* src = x + ((size_t)bz*CINX + c0 + ci)*HWX;
    float sum = 0.f;
    #pragma unroll
    for (int dy=0; dy<3; dy++){
      int yy = 2*oy-1+dy;
      if ((unsigned)yy >= HH) continue;
      #pragma unroll
      for (int dx=0; dx<3; dx++){
        int xx = 2*ox-1+dx;
        if ((unsigned)xx >= WW) continue;
        sum += src[yy*WW + xx];
      }
    }
    s[ci][pi] = sum * (1.f/9.f);
  }
  __syncthreads();
  const int pr = threadIdx.x >> 4, cj = threadIdx.x & 15;
  float v = s[cj][pr];
  ushortT h, lo; split2(v, h, lo);
  size_t o = ((size_t)bz*HWP + p0 + pr)*CINX + c0 + cj;
  ph_[o] = h; pl_[o] = lo;
}

// ============ x f32 NCHW -> NHWC hi/lo (16x16 LDS transpose) ============
__global__ __launch_bounds__(256) void prep_x2(const float* __restrict__ x,
    ushortT* __restrict__ xh, ushortT* __restrict__ xl){
  __shared__ float s[16][17];
  const int p0 = blockIdx.x*16, c0 = blockIdx.y*16, bz = blockIdx.z;
  const int ci = threadIdx.x >> 4, pi = threadIdx.x & 15;
  s[ci][pi] = x[((size_t)bz*CINX + c0 + ci)*HWX + p0 + pi];
  __syncthreads();
  const int pr = threadIdx.x >> 4, cj = threadIdx.x & 15;
  float v = s[cj][pr];
  ushortT h, lo; split2(v, h, lo);
  size_t o = ((size_t)bz*HWX + p0 + pr)*CINX + c0 + cj;
  xh[o] = h; xl[o] = lo;
}

// ============ avgpool 3x3 s2 p1 on fused (NHWC hi/lo) -> f32 NHWC [bz][p][512] ============
__global__ __launch_bounds__(256) void k_poolf(const ushortT* __restrict__ fzh,
    const ushortT* __restrict__ fzl, float* __restrict__ pf){
  const int p = blockIdx.x, bz = blockIdx.y;
  const int oy = p / WP, ox = p - oy*WP;
  const int c = threadIdx.x*2;
  float s0 = 0.f, s1 = 0.f;
  #pragma unroll
  for (int dy=0; dy<3; dy++){
    const int iy = 2*oy - 1 + dy;
    if ((unsigned)iy >= (unsigned)HH) continue;
    #pragma unroll
    for (int dx=0; dx<3; dx++){
      const int ix = 2*ox - 1 + dx;
      if ((unsigned)ix >= (unsigned)WW) continue;
      const size_t fi = ((size_t)bz*HWX + (size_t)(iy*WW + ix))*CO + c;
      uint32 hh = *(const uint32*)(fzh + fi);
      uint32 ll = *(const uint32*)(fzl + fi);
      s0 += bf2f((ushortT)(hh & 0xffff)) + bf2f((ushortT)(ll & 0xffff));
      s1 += bf2f((ushortT)(hh >> 16))    + bf2f((ushortT)(ll >> 16));
    }
  }
  const size_t o = ((size_t)bz*HWP + p)*CO + c;
  pf[o]   = s0 * (1.f/9.f);
  pf[o+1] = s1 * (1.f/9.f);
}

// ============ unified bf16x3-split MFMA implicit-GEMM (v6: counted-vmcnt pipeline) ============
// KIND: 0=1x1, 1=3x3, 2=dual K-concat, 3=dual K-concat w/ mask on src1 (MT must be 128)
// S1F: 1 = f32 NCHW gather (x) split on the fly
// DBUF: 1 = double-buffered LDS with counted s_waitcnt vmcnt(8) — prefetch stays in
//        flight across barriers and the MFMA phase (T4; m218)
// SWAP: 1 = x-coord is mt (else x-coord is nt); XCD-chunked bijective remap on 1D grid
// EPI: 0=bias+relu->hi/lo NHWC, 1=bias1+bias2->f32 NCHW, 2=fuse, 3=final(+pooledF)
template<int KIND,int EPI,int S1F,int MT,int DBUF,int SWAP,int GX,int GY,int STRIDE,int PAD,
         int HIN,int WIN,int WOUT,int NOUT,int C1,int C2,int BSTR1,int MTOT,int KTOT>
__global__ __launch_bounds__(MT*2)
void gemm_bf3(const ushortT* __restrict__ wph, const ushortT* __restrict__ wpl,
              const ushortT* __restrict__ s1h, const ushortT* __restrict__ s1l,
              const ushortT* __restrict__ s2h, const ushortT* __restrict__ s2l,
              const float* __restrict__ xf32,
              const float* __restrict__ bias1, const float* __restrict__ bias2,
              const float* __restrict__ maskf, const float* __restrict__ xbase,
              const ushortT* __restrict__ zp,
              ushortT* __restrict__ oh, ushortT* __restrict__ ol,
              float* __restrict__ of32)
{
  constexpr int NW = MT/32;        // waves: 4 (MT=128) or 8 (MT=256)
  constexpr int BCALLS = 8/NW;     // B glds calls/wave: 2 or 1
  constexpr bool GATHER1 = (KIND==0 && S1F==1);
  constexpr int BUFSZ = MT*64 + 8192;   // ushorts per buffer
  constexpr int T = GX*GY*BB;
  static_assert(T % 8 == 0, "grid not divisible by 8 XCDs");
  constexpr int QX = T/8;
  __shared__ ushortT smem[BUFSZ*(DBUF+1)];

  const int tid = threadIdx.x;
  const int lin = blockIdx.x;
  const int virt = (lin & 7)*QX + (lin >> 3);        // bijective XCD-chunked remap
  const int vx = virt % GX;
  const int vrest = virt / GX;
  const int vy = vrest % GY;
  const int bz = vrest / GY;
  const int nt = SWAP ? vy : vx;
  const int mt = SWAP ? vx : vy;
  const int l  = tid & 63, w = tid >> 6;
  const int wm = w >> 1, wn = w & 1;

  // ---- A glds precompute: 2 calls/wave/plane ----
  size_t a_src[2]; int a_dst[2];
  #pragma unroll
  for (int c=0;c<2;c++){
    int s = (w*2 + c)*64 + l;
    int row = s >> 2, slotm = s & 3;
    int logical = slotm ^ ((row >> 1) & 3);
    a_src[c] = (size_t)(mt*MT + row)*KTOT + logical*8;
    a_dst[c] = (w*2 + c)*512;
  }

  // ---- B glds precompute ----
  int b_dst[2]; size_t b_base1[2], b_base2[2]; int b_klane[2];
  int b_oy[2], b_ox[2]; bool b_ok[2]; float b_mv[2];
  #pragma unroll
  for (int c=0;c<BCALLS;c++){
    int s = (w*BCALLS + c)*64 + l;
    int row = s >> 2, slotm = s & 3;
    int logical = slotm ^ ((row >> 1) & 3);
    b_klane[c] = logical*8;
    b_dst[c] = (w*BCALLS + c)*512;
    int ngr = nt*128 + row;
    b_ok[c] = (ngr < NOUT);
    int oyv = ngr / WOUT, oxv = ngr - (ngr / WOUT)*WOUT;
    b_oy[c] = oyv; b_ox[c] = oxv;
    b_base1[c] = ((size_t)bz*NOUT + ngr)*BSTR1 + b_klane[c];
    b_base2[c] = ((size_t)bz*NOUT + ngr)*C2 + b_klane[c];
    b_mv[c] = 1.f;
    if (KIND == 3)
      b_mv[c] = b_ok[c] ? maskf[((size_t)(bz*NG + mt)*MSZ + (oyv>>3))*MSZ + (oxv>>3)] : 0.f;
  }

  // ---- gather-path (VGPR) ids ----
  const int sr = tid >> 1;
  const int hp = tid & 1;
  const int swz = (sr >> 1) & 3;
  const int lws0 = sr*32 + ((2*hp) ^ swz)*8;
  const int lws1 = sr*32 + ((2*hp + 1) ^ swz)*8;
  const int ng = nt*128 + sr;

  f32x4 acc[4][4];
  f32x4 zf = {0.f,0.f,0.f,0.f};
  #pragma unroll
  for (int i=0;i<4;i++)
    #pragma unroll
    for (int j=0;j<4;j++) acc[i][j] = zf;

  auto stagef = [&](int ks, ushortT* AHb, ushortT* ALb, ushortT* BHb, ushortT* BLb){
    const int k0 = ks*32;
    #pragma unroll
    for (int c=0;c<2;c++){
      glds16(wph + a_src[c] + k0, AHb + a_dst[c]);
      glds16(wpl + a_src[c] + k0, ALb + a_dst[c]);
    }
    if constexpr (GATHER1){
      if (tid < 256){
        uint4 b0 = make_uint4(0,0,0,0), b1v = b0, b2v = b0, b3v = b0;
        if (ng < NOUT){
          size_t fbase = ((size_t)bz*C1 + k0 + hp*16)*(size_t)NOUT + ng;
          ushortT h[16], lo[16];
          #pragma unroll
          for (int e=0;e<16;e++){ split2(xf32[fbase + (size_t)e*NOUT], h[e], lo[e]); }
          b0  = make_uint4(packu(h[0],h[1]),  packu(h[2],h[3]),  packu(h[4],h[5]),  packu(h[6],h[7]));
          b1v = make_uint4(packu(h[8],h[9]),  packu(h[10],h[11]),packu(h[12],h[13]),packu(h[14],h[15]));
          b2v = make_uint4(packu(lo[0],lo[1]),packu(lo[2],lo[3]),packu(lo[4],lo[5]),packu(lo[6],lo[7]));
          b3v = make_uint4(packu(lo[8],lo[9]),packu(lo[10],lo[11]),packu(lo[12],lo[13]),packu(lo[14],lo[15]));
        }
        *(uint4*)(BHb + lws0) = b0;  *(uint4*)(BHb + lws1) = b1v;
        *(uint4*)(BLb + lws0) = b2v; *(uint4*)(BLb + lws1) = b3v;
      }
    } else {
      #pragma unroll
      for (int c=0;c<BCALLS;c++){
        const ushortT *sh, *sl;
        if constexpr (KIND == 0){
          bool ok = b_ok[c];
          size_t off = b_base1[c] + k0;
          sh = ok ? s1h + off : zp;  sl = ok ? s1l + off : zp;
        } else if constexpr (KIND == 1){
          const int tap = k0 >> 7;             // C1 == 128
          const int cb  = (k0 & 127);
          const int dy = tap/3, dx = tap - 3*(tap/3);
          int iy = b_oy[c]*STRIDE + dy - PAD;
          int ix = b_ox[c]*STRIDE + dx - PAD;
          bool ok = b_ok[c] && (unsigned)iy < (unsigned)HIN && (unsigned)ix < (unsigned)WIN;
          size_t off = ((size_t)bz*(HIN*WIN) + (size_t)(iy*WIN + ix))*BSTR1 + cb + b_klane[c];
          sh = ok ? s1h + off : zp;  sl = ok ? s1l + off : zp;
        } else {
          if (k0 < C1){
            bool ok = b_ok[c] && (KIND != 3 || b_mv[c] != 0.f);
            size_t off = b_base1[c] + k0;
            sh = ok ? s1h + off : zp;  sl = ok ? s1l + off : zp;
          } else {
            bool ok = b_ok[c];
            size_t off = b_base2[c] + (k0 - C1);
            sh = ok ? s2h + off : zp;  sl = ok ? s2l + off : zp;
          }
        }
        glds16(sh, BHb + b_dst[c]);
        glds16(sl, BLb + b_dst[c]);
      }
    }
  };

  auto computef = [&](const ushortT* AHb, const ushortT* ALb,
                      const ushortT* BHb, const ushortT* BLb){
    short8 bh[4], bl[4];
    #pragma unroll
    for (int nf=0; nf<4; nf++){
      const int rr = wn*64 + nf*16 + (l & 15);
      const int ph = (l >> 4) ^ ((rr >> 1) & 3);
      bh[nf] = *(const short8*)(BHb + rr*32 + ph*8);
      bl[nf] = *(const short8*)(BLb + rr*32 + ph*8);
    }
    #pragma unroll
    for (int mf=0; mf<4; mf++){
      const int rr = wm*64 + mf*16 + (l & 15);
      const int ph = (l >> 4) ^ ((rr >> 1) & 3);
      short8 ah = *(const short8*)(AHb + rr*32 + ph*8);
      short8 al = *(const short8*)(ALb + rr*32 + ph*8);
      #pragma unroll
      for (int nf=0; nf<4; nf++)
        acc[mf][nf] = __builtin_amdgcn_mfma_f32_16x16x32_bf16(ah, bh[nf], acc[mf][nf], 0,0,0);
      #pragma unroll
      for (int nf=0; nf<4; nf++)
        acc[mf][nf] = __builtin_amdgcn_mfma_f32_16x16x32_bf16(ah, bl[nf], acc[mf][nf], 0,0,0);
      #pragma unroll
      for (int nf=0; nf<4; nf++)
        acc[mf][nf] = __builtin_amdgcn_mfma_f32_16x16x32_bf16(al, bh[nf], acc[mf][nf], 0,0,0);
    }
  };

  const int NK = KTOT / 32;
  if constexpr (DBUF == 0){
    ushortT* AH  = smem;
    ushortT* AL  = smem + MT*32;
    ushortT* BHs = smem + MT*64;
    ushortT* BLs = smem + MT*64 + 4096;
    for (int ks=0; ks<NK; ks++){
      stagef(ks, AH, AL, BHs, BLs);
      __syncthreads();
      computef(AH, AL, BHs, BLs);
      __syncthreads();
    }
  } else {
    // counted-vmcnt pipeline: stage(k+1)'s 8 glds/wave stay in flight across both
    // barriers and the compute phase; vmcnt(8) waits only for stage(k)'s glds.
    stagef(0, smem, smem + MT*32, smem + MT*64, smem + MT*64 + 4096);
    waitcnt_vm0();
    __builtin_amdgcn_s_barrier();
    for (int ks=0; ks<NK; ks++){
      ushortT* cb = smem + (ks & 1)*BUFSZ;
      ushortT* nb = smem + ((ks & 1) ^ 1)*BUFSZ;
      if (ks + 1 < NK){
        stagef(ks + 1, nb, nb + MT*32, nb + MT*64, nb + MT*64 + 4096);
        waitcnt_vm8();                      // previous stage complete; new 8 in flight
      } else {
        waitcnt_vm0();
      }
      __builtin_amdgcn_sched_barrier(0);
      __builtin_amdgcn_s_barrier();         // cb ready for all waves
      computef(cb, cb + MT*32, cb + MT*64, cb + MT*64 + 4096);
      __builtin_amdgcn_s_barrier();         // all waves done reading cb
    }
  }

  // epilogue: C/D frag: col n = l&15, row m = (l>>4)*4 + r
  const int mb0 = mt*MT + wm*64;
  const int nb0 = nt*128 + wn*64;

  #pragma unroll
  for (int nf=0; nf<4; nf++){
    const int n = nb0 + nf*16 + (l & 15);
    if (n >= NOUT) continue;
    if constexpr (EPI == 0){
      const size_t ob = ((size_t)bz*NOUT + n)*MTOT;
      #pragma unroll
      for (int mf=0; mf<4; mf++){
        const int m0 = mb0 + mf*16 + (l>>4)*4;
        ushort4 hq, lq; ushortT h0, l0; float v;
        v = fmaxf(acc[mf][nf][0] + bias1[m0+0], 0.f); split2(v,h0,l0); hq.x=h0; lq.x=l0;
        v = fmaxf(acc[mf][nf][1] + bias1[m0+1], 0.f); split2(v,h0,l0); hq.y=h0; lq.y=l0;
        v = fmaxf(acc[mf][nf][2] + bias1[m0+2], 0.f); split2(v,h0,l0); hq.z=h0; lq.z=l0;
        v = fmaxf(acc[mf][nf][3] + bias1[m0+3], 0.f); split2(v,h0,l0); hq.w=h0; lq.w=l0;
        *(ushort4*)(oh + ob + m0) = hq;
        *(ushort4*)(ol + ob + m0) = lq;
      }
    } else if constexpr (EPI == 1){
      #pragma unroll
      for (int mf=0; mf<4; mf++){
        const int m0 = mb0 + mf*16 + (l>>4)*4;
        #pragma unroll
        for (int r=0;r<4;r++){
          const int m = m0 + r;
          of32[((size_t)bz*MTOT + m)*NOUT + n] = acc[mf][nf][r] + bias1[m] + bias2[m];
        }
      }
    } else if constexpr (EPI == 2){
      const int y = n / WOUT, x = n - (n / WOUT)*WOUT;
      const int grpw = (mt*MT + wm*64) >> 7;
      const float mvv = maskf[((size_t)(bz*NG + grpw)*MSZ + (y>>3))*MSZ + (x>>3)];
      const int iy = y >> 1, ix = x >> 1;
      int yA,yB,xA,xB; float wyA,wyB,wxA,wxB;
      if (y & 1){ yA=iy; wyA=0.75f; yB=(iy+1<HP)?iy+1:HP-1; wyB=0.25f; }
      else      { yA=(iy>0)?iy-1:0; wyA=0.25f; yB=iy; wyB=0.75f; }
      if (x & 1){ xA=ix; wxA=0.75f; xB=(ix+1<WP)?ix+1:WP-1; wxB=0.25f; }
      else      { xA=(ix>0)?ix-1:0; wxA=0.25f; xB=ix; wxB=0.75f; }
      const size_t ob = ((size_t)bz*NOUT + n)*MTOT;
      #pragma unroll
      for (int mf=0; mf<4; mf++){
        const int m0 = mb0 + mf*16 + (l>>4)*4;
        ushort4 hq, lq;
        #pragma unroll
        for (int r=0;r<4;r++){
          const int m = m0 + r;
          const float* xb = xbase + ((size_t)bz*MTOT + m)*HWP;
          float up = wyA*(wxA*xb[yA*WP+xA] + wxB*xb[yA*WP+xB])
                   + wyB*(wxA*xb[yB*WP+xA] + wxB*xb[yB*WP+xB]);
          float v = fmaxf(acc[mf][nf][r] + up + mvv*bias1[m] + bias2[m], 0.f);
          ushortT h0, l0; split2(v, h0, l0);
          if      (r==0){hq.x=h0;lq.x=l0;}
          else if (r==1){hq.y=h0;lq.y=l0;}
          else if (r==2){hq.z=h0;lq.z=l0;}
          else          {hq.w=h0;lq.w=l0;}
        }
        *(ushort4*)(oh + ob + m0) = hq;
        *(ushort4*)(ol + ob + m0) = lq;
      }
    } else { // EPI == 3: out = relu(acc + bias1 + pooledF[bz][n][m])
      const float* pfrow = xbase + ((size_t)bz*NOUT + n)*MTOT;
      #pragma unroll
      for (int mf=0; mf<4; mf++){
        const int m0 = mb0 + mf*16 + (l>>4)*4;
        const float4 pv = *(const float4*)(pfrow + m0);
        of32[((size_t)bz*MTOT + m0+0)*NOUT + n] = fmaxf(acc[mf][nf][0] + bias1[m0+0] + pv.x, 0.f);
        of32[((size_t)bz*MTOT + m0+1)*NOUT + n] = fmaxf(acc[mf][nf][1] + bias1[m0+1] + pv.y, 0.f);
        of32[((size_t)bz*MTOT + m0+2)*NOUT + n] = fmaxf(acc[mf][nf][2] + bias1[m0+2] + pv.z, 0.f);
        of32[((size_t)bz*MTOT + m0+3)*NOUT + n] = fmaxf(acc[mf][nf][3] + bias1[m0+3] + pv.w, 0.f);
      }
    }
  }
}

// ============ gmap v2 (round-6 proven) ============
#define GM_LDSW 9216
__global__ __launch_bounds__(256) void k_gmap2(const float* __restrict__ xbase,
    const float* __restrict__ mw, const float* __restrict__ mg, const float* __restrict__ mb,
    float* __restrict__ gmap){
  __shared__ float wsh[GM_LDSW];
  __shared__ float red[16][2][4][16];
  const int tile = blockIdx.x, b = blockIdx.y;
  const int tid = threadIdx.x;
  const int pl = tid & 15, cs = tid >> 4;
  const int p = tile*16 + pl;
  const int oy = p / WP, ox = p - oy*WP;
  int toff[9];
  #pragma unroll
  for (int tap=0; tap<9; tap++){
    int dy = tap/3, dx = tap - 3*dy;
    int yy = oy + dy - 1, xx = ox + dx - 1;
    toff[tap] = ((unsigned)yy < (unsigned)HP && (unsigned)xx < (unsigned)WP) ? (yy*WP + xx) : -1;
  }
  float acc[2][4] = {{0.f,0.f,0.f,0.f},{0.f,0.f,0.f,0.f}};
  for (int pass=0; pass<2; pass++){
    __syncthreads();
    for (int i = tid; i < GM_LDSW; i += 256){
      int ocl = i & 3, tap = (i >> 2) % 9, c_rel = i / 36;
      int cg = pass*256 + c_rel;
      int g = cg >> 7;
      int oc = g*4 + ocl;
      wsh[i] = mw[((size_t)(oc*128 + (cg & 127)))*9 + tap] * mg[oc];
    }
    __syncthreads();
    const float* xb = xbase + ((size_t)b*CO + pass*256 + cs*16)*HWP;
    for (int cl=0; cl<16; cl++){
      const float* xc = xb + (size_t)cl*HWP;
      const float* wr = &wsh[(cs*16 + cl)*36];
      #pragma unroll
      for (int tap=0; tap<9; tap++){
        if (toff[tap] < 0) continue;
        float v = xc[toff[tap]];
        f32x4 w4 = *(const f32x4*)(wr + tap*4);
        acc[pass][0] += v*w4[0];
        acc[pass][1] += v*w4[1];
        acc[pass][2] += v*w4[2];
        acc[pass][3] += v*w4[3];
      }
    }
  }
  #pragma unroll
  for (int pp=0; pp<2; pp++)
    #pragma unroll
    for (int o=0; o<4; o++)
      red[cs][pp][o][pl] = acc[pp][o];
  __syncthreads();
  const int oc = tid >> 4;
  const int g = oc >> 2, ocl = oc & 3, pg = g >> 1, cs0 = (g & 1)*8;
  float s = 0.f;
  #pragma unroll
  for (int t=0; t<8; t++) s += red[cs0 + t][pg][ocl][pl];
  s = fmaxf(s + mb[oc], 0.f);
  gmap[((size_t)b*16 + oc)*HWP + p] = s;
}

__global__ __launch_bounds__(256) void k_gpool(const float* __restrict__ gmap, float* __restrict__ gpool){
  int idx = blockIdx.x*256 + threadIdx.x;
  if (idx >= BB*16*49) return;
  int q = idx % 49; int t = idx / 49; int ch = t % 16; int b = t / 16;
  int my = q/7, mx = q%7;
  const float* src = gmap + ((size_t)b*16 + ch)*HWP;
  float s = 0.f;
  #pragma unroll
  for (int yb=0;yb<4;yb++)
    #pragma unroll
    for (int xb=0;xb<4;xb++)
      s += src[(my*4+yb)*WP + (mx*4+xb)];
  gpool[idx] = s * (1.f/16.f);
}

__global__ __launch_bounds__(256) void k_mask(const float* __restrict__ gpool, const float* __restrict__ fcw,
    const float* __restrict__ fcb, const float* __restrict__ gum,
    float* __restrict__ maskf, float* __restrict__ mout){
  int idx = blockIdx.x*256 + threadIdx.x;
  if (idx >= BB*NG*49) return;
  int q = idx % 49; int t = idx / 49; int g = t % NG; int b = t / NG;
  float lgt[2];
  #pragma unroll
  for (int cls=0; cls<2; cls++){
    int c = cls*NG + g;
    int gc = c >> 1;
    float s = fcb[c];
    #pragma unroll
    for (int k=0;k<4;k++)
      s += fcw[c*4+k] * gpool[((size_t)b*16 + gc*4 + k)*49 + q];
    s += gum[(((size_t)b*2 + cls)*NG + g)*49 + q];
    lgt[cls] = s;
  }
  float m = (lgt[1] > lgt[0]) ? 1.f : 0.f;
  maskf[idx] = m;
  mout[idx] = m;
}

extern "C" void kernel_launch(void* const* d_in, const int* in_sizes, int n_in,
                              void* d_out, int out_size, void* d_ws, size_t ws_size,
                              hipStream_t stream){
  const float* x    = (const float*)d_in[0];
  const float* gum  = (const float*)d_in[1];
  const float* b_w1 = (const float*)d_in[2];
  const float* b_g1 = (const float*)d_in[3];
  const float* b_b1 = (const float*)d_in[4];
  const float* b_w2 = (const float*)d_in[5];
  const float* b_g2 = (const float*)d_in[6];
  const float* b_b2 = (const float*)d_in[7];
  const float* b_w3 = (const float*)d_in[8];
  const float* b_g3 = (const float*)d_in[9];
  const float* b_b3 = (const float*)d_in[10];
  const float* b_dw = (const float*)d_in[11];
  const float* b_dg = (const float*)d_in[12];
  const float* b_db = (const float*)d_in[13];
  const float* r_w1 = (const float*)d_in[14];
  const float* r_g1 = (const float*)d_in[15];
  const float* r_b1 = (const float*)d_in[16];
  const float* r_w2 = (const float*)d_in[17];
  const float* r_g2 = (const float*)d_in[18];
  const float* r_b2 = (const float*)d_in[19];
  const float* r_w3 = (const float*)d_in[20];
  const float* r_g3 = (const float*)d_in[21];
  const float* r_b3 = (const float*)d_in[22];
  const float* r_dw = (const float*)d_in[23];
  const float* r_dg = (const float*)d_in[24];
  const float* r_db = (const float*)d_in[25];
  const float* m_w  = (const float*)d_in[26];
  const float* m_g  = (const float*)d_in[27];
  const float* m_b  = (const float*)d_in[28];
  const float* m_fcw= (const float*)d_in[29];
  const float* m_fcb= (const float*)d_in[30];
  const float* f_w1 = (const float*)d_in[31];
  const float* f_g1 = (const float*)d_in[32];
  const float* f_b1 = (const float*)d_in[33];
  const float* f_w2 = (const float*)d_in[34];
  const float* f_g2 = (const float*)d_in[35];
  const float* f_b2 = (const float*)d_in[36];
  const float* f_w3 = (const float*)d_in[37];
  const float* f_g3 = (const float*)d_in[38];
  const float* f_b3 = (const float*)d_in[39];

  char* ws = (char*)d_ws;
  // ws layout v5 — total 378,367,616 B
  constexpr size_t O_WPH  = 0;            //  2,064,384
  constexpr size_t O_WPL  = 2064384;      //  2,064,384  -> 4,128,768
  constexpr size_t O_CH   = 4128768;      // 51,380,224  merged hi; then XH (x hi NHWC); then f1 hi+lo
  constexpr size_t O_DH   = 55508992;     //  6,422,528  t2/f2 hi
  constexpr size_t O_DL   = 61931520;     //  6,422,528  -> 68,354,048
  constexpr size_t O_EH   = 68354048;     // 25,690,112  r2 hi
  constexpr size_t O_EL   = 94044160;     // 25,690,112  -> 119,734,272
  constexpr size_t O_PF   = O_EH;         // 51,380,224  pooledF f32 NHWC (r2 dead after fuse)
  constexpr size_t O_XB   = 119734272;    // 51,380,224  xbase f32 NCHW
  constexpr size_t O_GMAP = 171114496;    //  1,605,632
  constexpr size_t O_GPOOL= 172720128;    //    100,352
  constexpr size_t O_MASK = 172820480;    //     25,088
  constexpr size_t O_FH   = 172845568;    // 102,760,448 fused hi (overlaps PH/PL)
  constexpr size_t O_PH   = 172845568;    // 12,845,056  pooled hi (dead after xbase GEMM)
  constexpr size_t O_PL   = 185690624;    // 12,845,056
  constexpr size_t O_FL   = 275606016;    // 102,760,448 -> 378,366,464
  constexpr size_t O_ZP   = 378366464;    //        128  zero page
  constexpr size_t O_BIASC= 378366592;    //      1,024  concat bias -> 378,367,616

  ushortT* WPH = (ushortT*)(ws + O_WPH);
  ushortT* WPL = (ushortT*)(ws + O_WPL);
  ushortT* MGH = (ushortT*)(ws + O_CH);          // merged hi plane, stride 256 (b2/r2 input)
  ushortT* XH  = (ushortT*)(ws + O_CH);          // x hi NHWC (after r2; fuse input)
  ushortT* F1H = (ushortT*)(ws + O_CH);          // f1 hi (after fuse)
  ushortT* F1L = (ushortT*)(ws + O_CH + 25690112);
  ushortT* DHp = (ushortT*)(ws + O_DH);
  ushortT* DLp = (ushortT*)(ws + O_DL);
  ushortT* EHp = (ushortT*)(ws + O_EH);
  ushortT* ELp = (ushortT*)(ws + O_EL);
  float*   PF  = (float*)(ws + O_PF);
  float*   XB  = (float*)(ws + O_XB);
  ushortT* PHp = (ushortT*)(ws + O_PH);
  ushortT* PLp = (ushortT*)(ws + O_PL);
  ushortT* FHp = (ushortT*)(ws + O_FH);
  ushortT* FLp = (ushortT*)(ws + O_FL);
  float*   GMAP = (float*)(ws + O_GMAP);
  float*   GPOOL= (float*)(ws + O_GPOOL);
  float*   MASKF= (float*)(ws + O_MASK);
  ushortT* ZP  = (ushortT*)(ws + O_ZP);
  float*   BIASC = (float*)(ws + O_BIASC);
  (void)ws_size;

  float* outp = (float*)d_out;
  float* mout = outp + (size_t)BB*CO*HWP;
  ushortT* dout_u = (ushortT*)d_out;             // merged lo plane, then XL (x lo NHWC)

  dim3 blk(256), blk2(512);
  const ushortT* nu = nullptr; const float* nf_ = nullptr;
  ushortT* nuo = nullptr; float* nfo = nullptr;

  // prep
  prep_w<<<dim3(768, 10), blk, 0, stream>>>(b_w1,b_g1,b_w2,b_g2,b_w3,b_g3,b_dw,b_dg,
      r_w1,r_g1,r_w2,r_g2,r_w3,r_g3,r_dw,r_dg,f_w1,f_g1,f_w2,f_g2,f_w3,f_g3,
      b_b1, r_b1, WPH, WPL, ZP, BIASC);
  k_pool2<<<dim3(49, 16, BB), blk, 0, stream>>>(x, PHp, PLp);

  // merged b1|r1: one x-gather pass, MT=256 (single-buffer, gather path)  T=800
  gemm_bf3<0,0,1,256,0,0, 25,1, 1,0,56,56,56,3136, 256,0,256, 256,256><<<dim3(800), blk2, 0, stream>>>(
      WPH+0, WPL+0, nu, nu, nu, nu, x, BIASC, nf_, nf_, nf_, ZP, MGH, dout_u, nfo);
  // b2 (reads t1 = merged rows 0-127, stride 256) — counted-vmcnt dbuf  T=224
  gemm_bf3<1,0,0,128,1,0, 7,1, 2,1,56,56,28,784, 128,0,256, 128,1152><<<dim3(224), blk, 0, stream>>>(
      WPH+65536, WPL+65536, MGH, dout_u, nu, nu, nf_, b_b2, nf_, nf_, nf_, ZP, DHp, DLp, nfo);
  // xbase dual (MT=256, single-buffer)  T=448
  gemm_bf3<2,1,0,256,0,0, 7,2, 1,0,28,28,28,784, 128,256,128, 512,384><<<dim3(448), blk2, 0, stream>>>(
      WPH+212992, WPL+212992, DHp, DLp, PHp, PLp, nf_, b_b3, b_db, nf_, nf_, ZP, nuo, nuo, XB);

  // mask path
  k_gmap2<<<dim3(49, BB), blk, 0, stream>>>(XB, m_w, m_g, m_b, GMAP);
  k_gpool<<<dim3(98), blk, 0, stream>>>(GMAP, GPOOL);
  k_mask<<<dim3(25), blk, 0, stream>>>(GPOOL, m_fcw, m_fcb, gum, MASKF, mout);

  // r2 (reads r1 = merged rows 128-255) — counted-vmcnt dbuf  T=800
  gemm_bf3<1,0,0,128,1,0, 25,1, 1,1,56,56,56,3136, 128,0,256, 128,1152><<<dim3(800), blk, 0, stream>>>(
      WPH+409600, WPL+409600, MGH+128, dout_u+128, nu, nu, nf_, r_b2, nf_, nf_, nf_, ZP, EHp, ELp, nfo);

  // pre-split x -> XH (CH region, merged dead) + XL (d_out, merged-lo dead)
  prep_x2<<<dim3(196, 16, BB), blk, 0, stream>>>(x, XH, dout_u);

  // fused = relu(up(xbase) + mask*(conv(r2)+b3) + conv(x)+db) — counted-vmcnt dbuf, mt-fastest  T=3200
  gemm_bf3<3,2,0,128,1,1, 4,25, 1,0,56,56,56,3136, 128,256,128, 512,384><<<dim3(3200), blk, 0, stream>>>(
      WPH+557056, WPL+557056, EHp, ELp, XH, dout_u, nf_, r_b3, r_db, MASKF, XB, ZP, FHp, FLp, nfo);

  // pooledF = avgpool3s2(fused)
  k_poolf<<<dim3(HWP, BB), blk, 0, stream>>>(FHp, FLp, PF);

  // fuse branch
  gemm_bf3<0,0,0,128,1,0, 25,1, 1,0,56,56,56,3136, 512,0,512, 128,512><<<dim3(800), blk, 0, stream>>>(
      WPH+753664, WPL+753664, FHp, FLp, nu, nu, nf_, f_b1, nf_, nf_, nf_, ZP, F1H, F1L, nfo);
  gemm_bf3<1,0,0,128,1,0, 7,1, 2,1,56,56,28,784, 128,0,128, 128,1152><<<dim3(224), blk, 0, stream>>>(
      WPH+819200, WPL+819200, F1H, F1L, nu, nu, nf_, f_b2, nf_, nf_, nf_, ZP, DHp, DLp, nfo);
  // out = relu(conv(f2)+b3 + pooledF)   (MT=256, single-buffer)  T=448
  gemm_bf3<0,3,0,256,0,0, 7,2, 1,0,28,28,28,784, 128,0,128, 512,128><<<dim3(448), blk2, 0, stream>>>(
      WPH+966656, WPL+966656, DHp, DLp, nu, nu, nf_, f_b3, nf_, nf_, PF, ZP, nuo, nuo, outp);
}